// Round 1
// baseline (618.539 us; speedup 1.0000x reference)
//
#include <hip/hip_runtime.h>
#include <math.h>

#define EPSV 1e-5f

// ---------------------------------------------------------------- hist
__global__ __launch_bounds__(256) void k_hist(const int* __restrict__ dst,
                                              int* __restrict__ hist, int e) {
  int i = blockIdx.x * 256 + threadIdx.x;
  if (i < e) atomicAdd(&hist[dst[i]], 1);
}

// ---------------------------------------------------------------- scan (single block, hierarchical shuffle scan)
__global__ __launch_bounds__(1024) void k_scan(const int* __restrict__ hist,
                                               int* __restrict__ row_start,
                                               int* __restrict__ cursor,
                                               float* __restrict__ invs, int n) {
  __shared__ int wtot[16];
  int tid = threadIdx.x, lane = tid & 63, w = tid >> 6;
  int running = 0;
  int nch = (n + 1023) >> 10;
  for (int ch = 0; ch < nch; ++ch) {
    int i = (ch << 10) + tid;
    int v = (i < n) ? hist[i] : 0;
    int x = v;
    #pragma unroll
    for (int off = 1; off < 64; off <<= 1) {
      int y = __shfl_up(x, off);
      if (lane >= off) x += y;
    }
    if (lane == 63) wtot[w] = x;
    __syncthreads();
    if (w == 0) {
      int t = (lane < 16) ? wtot[lane] : 0;
      #pragma unroll
      for (int off = 1; off < 16; off <<= 1) {
        int y = __shfl_up(t, off);
        if (lane >= off) t += y;
      }
      if (lane < 16) wtot[lane] = t;
    }
    __syncthreads();
    int base = running + ((w > 0) ? wtot[w - 1] : 0);
    if (i < n) {
      int excl = base + x - v;
      row_start[i] = excl;
      cursor[i] = excl;
      invs[i] = rsqrtf((float)(v + 1));  // deg = in-degree + self loop, always >= 1
    }
    running += wtot[15];
    __syncthreads();
  }
  if (tid == 0) row_start[n] = running;
}

// ---------------------------------------------------------------- scatter edges into CSR
__global__ __launch_bounds__(256) void k_scatter(const int* __restrict__ src,
                                                 const int* __restrict__ dst,
                                                 int* __restrict__ cursor,
                                                 int* __restrict__ csr, int e) {
  int i = blockIdx.x * 256 + threadIdx.x;
  if (i < e) {
    int d = dst[i];
    int pos = atomicAdd(&cursor[d], 1);
    csr[pos] = src[i];
  }
}

// ---------------------------------------------------------------- GEMM: out[r][c] = transform(in)[r] @ W * invs[r]
// transform = identity (layer1) or BN+ReLU using stats_red (layer2)
template <bool BN>
__global__ __launch_bounds__(256) void k_gemm(const float* __restrict__ in,
                                              const float* __restrict__ W,
                                              const float* __restrict__ invs,
                                              const float* __restrict__ stats_red,
                                              float* __restrict__ out, int n) {
  __shared__ float xs[64][36];
  __shared__ float wsT[128][36];
  __shared__ float muL[128], sclL[128];
  const int tid = threadIdx.x;
  const int tx = tid & 31, ty = tid >> 5;
  const int br0 = blockIdx.x * 64;

  if (BN) {
    if (tid < 128) {
      float s = stats_red[tid], q = stats_red[128 + tid];
      float m = s * (1.0f / 50000.0f);
      muL[tid] = m;
      sclL[tid] = rsqrtf(q * (1.0f / 50000.0f) - m * m + EPSV);
    }
    __syncthreads();
  }

  float acc[8][4];
  #pragma unroll
  for (int r = 0; r < 8; ++r)
    #pragma unroll
    for (int c = 0; c < 4; ++c) acc[r][c] = 0.0f;

  for (int kt = 0; kt < 4; ++kt) {
    #pragma unroll
    for (int i = 0; i < 16; ++i) {  // W tile 32x128, stored transposed
      int idx = tid + i * 256;
      int kk = idx >> 7, col = idx & 127;
      wsT[col][kk] = W[(kt * 32 + kk) * 128 + col];
    }
    #pragma unroll
    for (int i = 0; i < 8; ++i) {  // x tile 64x32
      int idx = tid + i * 256;
      int kk = idx & 31, row = idx >> 5;
      int gr = br0 + row;
      float v = 0.0f;
      if (gr < n) v = in[gr * 128 + kt * 32 + kk];
      if (BN) {
        int k = kt * 32 + kk;
        v = (v - muL[k]) * sclL[k];
        v = v > 0.0f ? v : 0.0f;
      }
      xs[row][kk] = v;
    }
    __syncthreads();
    #pragma unroll
    for (int kk = 0; kk < 32; kk += 4) {
      float4 wv[4], xv[8];
      #pragma unroll
      for (int c = 0; c < 4; ++c) wv[c] = *(const float4*)&wsT[c * 32 + tx][kk];
      #pragma unroll
      for (int r = 0; r < 8; ++r) xv[r] = *(const float4*)&xs[ty * 8 + r][kk];
      #pragma unroll
      for (int r = 0; r < 8; ++r)
        #pragma unroll
        for (int c = 0; c < 4; ++c)
          acc[r][c] += xv[r].x * wv[c].x + xv[r].y * wv[c].y +
                       xv[r].z * wv[c].z + xv[r].w * wv[c].w;
    }
    __syncthreads();
  }

  #pragma unroll
  for (int r = 0; r < 8; ++r) {
    int gr = br0 + ty * 8 + r;
    if (gr >= n) continue;
    float iv = invs[gr];
    #pragma unroll
    for (int c = 0; c < 4; ++c) out[gr * 128 + c * 32 + tx] = acc[r][c] * iv;
  }
}

// ---------------------------------------------------------------- gather: h[d] = invs[d]*(hs[d]+sum hs[src]) + b; fused col-stats partials
__global__ __launch_bounds__(256) void k_gather(const float* __restrict__ hs,
                                                const int* __restrict__ row_start,
                                                const int* __restrict__ csr,
                                                const float* __restrict__ invs,
                                                const float* __restrict__ bias,
                                                float* __restrict__ out,
                                                float* __restrict__ statsP, int n) {
  const int tid = threadIdx.x;
  const int lane = tid & 63, w = tid >> 6;
  const int c0 = lane * 2;
  float s0 = 0.f, s1 = 0.f, q0 = 0.f, q1 = 0.f;
  const float bv0 = bias[c0], bv1 = bias[c0 + 1];
  const int stride = gridDim.x * 4;
  for (int node = blockIdx.x * 4 + w; node < n; node += stride) {
    float2 acc = *(const float2*)&hs[(size_t)node * 128 + c0];  // self loop
    int beg = row_start[node], end = row_start[node + 1];
    int e = beg;
    for (; e + 1 < end; e += 2) {
      int sA = csr[e], sB = csr[e + 1];
      float2 vA = *(const float2*)&hs[(size_t)sA * 128 + c0];
      float2 vB = *(const float2*)&hs[(size_t)sB * 128 + c0];
      acc.x += vA.x + vB.x;
      acc.y += vA.y + vB.y;
    }
    if (e < end) {
      int sA = csr[e];
      float2 vA = *(const float2*)&hs[(size_t)sA * 128 + c0];
      acc.x += vA.x;
      acc.y += vA.y;
    }
    float iv = invs[node];
    float o0 = acc.x * iv + bv0, o1 = acc.y * iv + bv1;
    float2 o = make_float2(o0, o1);
    *(float2*)&out[(size_t)node * 128 + c0] = o;
    s0 += o0; s1 += o1; q0 += o0 * o0; q1 += o1 * o1;
  }
  __shared__ float redS[4][128], redQ[4][128];
  redS[w][c0] = s0; redS[w][c0 + 1] = s1;
  redQ[w][c0] = q0; redQ[w][c0 + 1] = q1;
  __syncthreads();
  if (tid < 128) {
    float s = redS[0][tid] + redS[1][tid] + redS[2][tid] + redS[3][tid];
    statsP[blockIdx.x * 256 + tid] = s;
  } else {
    int t = tid - 128;
    float q = redQ[0][t] + redQ[1][t] + redQ[2][t] + redQ[3][t];
    statsP[blockIdx.x * 256 + tid] = q;
  }
}

// ---------------------------------------------------------------- reduce stats partials -> stats_red[256] (sum[128]|sumsq[128])
__global__ __launch_bounds__(1024) void k_finstats(const float* __restrict__ statsP,
                                                   float* __restrict__ stats_red,
                                                   int nb) {
  int t = threadIdx.x;
  int c = blockIdx.x * 16 + (t & 15);
  int b0 = t >> 4;  // 64 slices
  int per = nb >> 6;
  float s = 0.f;
  for (int j = 0; j < per; ++j) s += statsP[(b0 * per + j) * 256 + c];
  __shared__ float red[1024];
  red[t] = s;
  __syncthreads();
  for (int st = 512; st >= 16; st >>= 1) {
    if (t < st) red[t] += red[t + st];
    __syncthreads();
  }
  if (t < 16) stats_red[blockIdx.x * 16 + t] = red[t];
}

// ---------------------------------------------------------------- pool: LDS bins per block -> per-block partials
__global__ __launch_bounds__(256) void k_pool(const float* __restrict__ h,
                                              const float* __restrict__ stats_red,
                                              const float* __restrict__ cv,
                                              const int* __restrict__ part,
                                              float* __restrict__ poolP, int n) {
  __shared__ float bins[16384];  // [2][64][128] = 64 KB
  const int tid = threadIdx.x;
  const int lane = tid & 63, w = tid >> 6;
  const int c0 = lane * 2;
  for (int i = tid; i < 16384; i += 256) bins[i] = 0.f;
  float s0 = stats_red[c0], s1 = stats_red[c0 + 1];
  float qq0 = stats_red[128 + c0], qq1 = stats_red[128 + c0 + 1];
  float mu0 = s0 * (1.0f / 50000.0f), mu1 = s1 * (1.0f / 50000.0f);
  float scl0 = rsqrtf(qq0 * (1.0f / 50000.0f) - mu0 * mu0 + EPSV);
  float scl1 = rsqrtf(qq1 * (1.0f / 50000.0f) - mu1 * mu1 + EPSV);
  __syncthreads();
  const int stride = gridDim.x * 4;
  for (int row = blockIdx.x * 4 + w; row < n; row += stride) {
    float2 v = *(const float2*)&h[(size_t)row * 128 + c0];
    float x0 = (v.x - mu0) * scl0; x0 = x0 > 0.f ? x0 : 0.f;
    float x1 = (v.y - mu1) * scl1; x1 = x1 > 0.f ? x1 : 0.f;
    float cvv = cv[row];
    int p = part[row];
    atomicAdd(&bins[p * 128 + c0], x0 * cvv);
    atomicAdd(&bins[p * 128 + c0 + 1], x1 * cvv);
    atomicAdd(&bins[8192 + p * 128 + c0], x0 * (1.f - cvv));
    atomicAdd(&bins[8192 + p * 128 + c0 + 1], x1 * (1.f - cvv));
  }
  __syncthreads();
  for (int i = tid; i < 16384; i += 256) poolP[blockIdx.x * 16384 + i] = bins[i];
}

// ---------------------------------------------------------------- final MLP: one block per partition
__global__ __launch_bounds__(128) void k_mlp(const float* __restrict__ h,
                                             const float* __restrict__ stats_red,
                                             const float* __restrict__ poolP, int nbp,
                                             const float* __restrict__ l1W,
                                             const float* __restrict__ l1b,
                                             const float* __restrict__ l2W,
                                             const float* __restrict__ l2b,
                                             const int* __restrict__ curr_ptr,
                                             float* __restrict__ out, int n) {
  const int p = blockIdx.x;
  const int t = threadIdx.x;  // 128 threads
  __shared__ float z[384];
  int curr = *curr_ptr;
  float s = stats_red[t], q = stats_red[128 + t];
  float mu = s / (float)n;
  float scl = rsqrtf(q / (float)n - mu * mu + EPSV);
  float v = h[(size_t)curr * 128 + t];
  v = (v - mu) * scl;
  z[t] = v > 0.f ? v : 0.f;
  float ccore = 0.f, cnon = 0.f;
  for (int b = 0; b < nbp; ++b) {
    ccore += poolP[b * 16384 + p * 128 + t];
    cnon += poolP[b * 16384 + 8192 + p * 128 + t];
  }
  z[128 + t] = ccore;
  z[256 + t] = cnon;
  __syncthreads();
  float a = l1b[t];
  for (int k = 0; k < 384; ++k) a += z[k] * l1W[k * 128 + t];
  a = a > 0.f ? a : 0.f;
  float pr = a * l2W[t];
  #pragma unroll
  for (int off = 32; off; off >>= 1) pr += __shfl_down(pr, off);
  __shared__ float rr[2];
  if ((t & 63) == 0) rr[t >> 6] = pr;
  __syncthreads();
  if (t == 0) out[p] = rr[0] + rr[1] + l2b[0];
}

// ================================================================ host
extern "C" void kernel_launch(void* const* d_in, const int* in_sizes, int n_in,
                              void* d_out, int out_size, void* d_ws, size_t ws_size,
                              hipStream_t stream) {
  const float* x    = (const float*)d_in[0];
  const float* cv   = (const float*)d_in[1];
  const float* W0   = (const float*)d_in[2];
  const float* b0   = (const float*)d_in[3];
  const float* W1   = (const float*)d_in[4];
  const float* b1   = (const float*)d_in[5];
  const float* l1W  = (const float*)d_in[6];
  const float* l1b  = (const float*)d_in[7];
  const float* l2W  = (const float*)d_in[8];
  const float* l2b  = (const float*)d_in[9];
  const int*   ei   = (const int*)d_in[10];
  const int*   part = (const int*)d_in[11];
  const int*   curr = (const int*)d_in[12];

  const int N = in_sizes[1];          // 50000
  const int E = in_sizes[10] / 2;     // 640000
  const int* src = ei;
  const int* dst = ei + E;

  const int GATHER_BLOCKS = 2048;
  const int POOL_BLOCKS = 128;

  char* w = (char*)d_ws;
  size_t off = 0;
  auto alloc = [&](size_t bytes) -> void* {
    void* p = (void*)(w + off);
    off = (off + bytes + 255) & ~(size_t)255;
    return p;
  };
  int*   hist      = (int*)alloc((size_t)N * 4);
  int*   cursor    = (int*)alloc((size_t)N * 4);
  int*   row_start = (int*)alloc((size_t)(N + 1) * 4);
  int*   csr       = (int*)alloc((size_t)E * 4);
  float* invs      = (float*)alloc((size_t)N * 4);
  float* stats_red0 = (float*)alloc(256 * 4);
  float* stats_red1 = (float*)alloc(256 * 4);
  float* statsP    = (float*)alloc((size_t)GATHER_BLOCKS * 256 * 4);
  float* poolP     = (float*)alloc((size_t)POOL_BLOCKS * 16384 * 4);
  float* hs        = (float*)alloc((size_t)N * 128 * 4);
  float* h         = (float*)alloc((size_t)N * 128 * 4);
  (void)ws_size;

  hipMemsetAsync(hist, 0, (size_t)N * 4, stream);

  int eb = (E + 255) / 256;
  k_hist<<<eb, 256, 0, stream>>>(dst, hist, E);
  k_scan<<<1, 1024, 0, stream>>>(hist, row_start, cursor, invs, N);
  k_scatter<<<eb, 256, 0, stream>>>(src, dst, cursor, csr, E);

  int gb = (N + 63) / 64;
  // layer 1
  k_gemm<false><<<gb, 256, 0, stream>>>(x, W0, invs, nullptr, hs, N);
  k_gather<<<GATHER_BLOCKS, 256, 0, stream>>>(hs, row_start, csr, invs, b0, h, statsP, N);
  k_finstats<<<16, 1024, 0, stream>>>(statsP, stats_red0, GATHER_BLOCKS);
  // layer 2 (BN+ReLU of layer1 fused into GEMM input transform)
  k_gemm<true><<<gb, 256, 0, stream>>>(h, W1, invs, stats_red0, hs, N);
  k_gather<<<GATHER_BLOCKS, 256, 0, stream>>>(hs, row_start, csr, invs, b1, h, statsP, N);
  k_finstats<<<16, 1024, 0, stream>>>(statsP, stats_red1, GATHER_BLOCKS);
  // pooling + head (BN+ReLU of layer2 fused into loads)
  k_pool<<<POOL_BLOCKS, 256, 0, stream>>>(h, stats_red1, cv, part, poolP, N);
  k_mlp<<<64, 128, 0, stream>>>(h, stats_red1, poolP, POOL_BLOCKS, l1W, l1b, l2W, l2b, curr, (float*)d_out, N);
}

// Round 2
// 551.719 us; speedup vs baseline: 1.1211x; 1.1211x over previous
//
#include <hip/hip_runtime.h>
#include <math.h>

#define EPSV 1e-5f

// ---------------------------------------------------------------- hist (edge in-degree)
__global__ __launch_bounds__(256) void k_hist(const int* __restrict__ dst,
                                              int* __restrict__ hist, int e) {
  int i = blockIdx.x * 256 + threadIdx.x;
  if (i < e) atomicAdd(&hist[dst[i]], 1);
}

// ---------------------------------------------------------------- scan (single block, hierarchical shuffle scan)
__global__ __launch_bounds__(1024) void k_scan(const int* __restrict__ hist,
                                               int* __restrict__ row_start,
                                               int* __restrict__ cursor,
                                               float* __restrict__ invs, int n) {
  __shared__ int wtot[16];
  int tid = threadIdx.x, lane = tid & 63, w = tid >> 6;
  int running = 0;
  int nch = (n + 1023) >> 10;
  for (int ch = 0; ch < nch; ++ch) {
    int i = (ch << 10) + tid;
    int v = (i < n) ? hist[i] : 0;
    int x = v;
    #pragma unroll
    for (int off = 1; off < 64; off <<= 1) {
      int y = __shfl_up(x, off);
      if (lane >= off) x += y;
    }
    if (lane == 63) wtot[w] = x;
    __syncthreads();
    if (w == 0) {
      int t = (lane < 16) ? wtot[lane] : 0;
      #pragma unroll
      for (int off = 1; off < 16; off <<= 1) {
        int y = __shfl_up(t, off);
        if (lane >= off) t += y;
      }
      if (lane < 16) wtot[lane] = t;
    }
    __syncthreads();
    int base = running + ((w > 0) ? wtot[w - 1] : 0);
    if (i < n) {
      int excl = base + x - v;
      row_start[i] = excl;
      cursor[i] = excl;
      invs[i] = rsqrtf((float)(v + 1));  // deg = in-degree + self loop, always >= 1
    }
    running += wtot[15];
    __syncthreads();
  }
  if (tid == 0) row_start[n] = running;
}

// ---------------------------------------------------------------- scatter edges into CSR
__global__ __launch_bounds__(256) void k_scatter(const int* __restrict__ src,
                                                 const int* __restrict__ dst,
                                                 int* __restrict__ cursor,
                                                 int* __restrict__ csr, int e) {
  int i = blockIdx.x * 256 + threadIdx.x;
  if (i < e) {
    int d = dst[i];
    int pos = atomicAdd(&cursor[d], 1);
    csr[pos] = src[i];
  }
}

// ---------------------------------------------------------------- partition histogram (LDS-reduced)
__global__ __launch_bounds__(256) void k_phist(const int* __restrict__ part,
                                               int* __restrict__ ph, int n) {
  __shared__ int lh[64];
  int tid = threadIdx.x;
  if (tid < 64) lh[tid] = 0;
  __syncthreads();
  for (int i = blockIdx.x * 256 + tid; i < n; i += gridDim.x * 256)
    atomicAdd(&lh[part[i]], 1);
  __syncthreads();
  if (tid < 64) atomicAdd(&ph[tid], lh[tid]);
}

// ---------------------------------------------------------------- partition scan (1 wave, 64 bins)
__global__ __launch_bounds__(64) void k_pscan(const int* __restrict__ ph,
                                              int* __restrict__ pstart,
                                              int* __restrict__ pcur) {
  int lane = threadIdx.x;
  int v = ph[lane];
  int x = v;
  #pragma unroll
  for (int off = 1; off < 64; off <<= 1) {
    int y = __shfl_up(x, off);
    if (lane >= off) x += y;
  }
  pstart[lane] = x - v;
  pcur[lane] = x - v;
  if (lane == 63) pstart[64] = x;
}

// ---------------------------------------------------------------- scatter node ids into partition-sorted perm
__global__ __launch_bounds__(256) void k_pscatter(const int* __restrict__ part,
                                                  int* __restrict__ pcur,
                                                  int* __restrict__ perm, int n) {
  int i = blockIdx.x * 256 + threadIdx.x;
  if (i < n) {
    int p = part[i];
    int pos = atomicAdd(&pcur[p], 1);
    perm[pos] = i;
  }
}

// ---------------------------------------------------------------- GEMM: out[r][c] = transform(in)[r] @ W * invs[r]
template <bool BN>
__global__ __launch_bounds__(256) void k_gemm(const float* __restrict__ in,
                                              const float* __restrict__ W,
                                              const float* __restrict__ invs,
                                              const float* __restrict__ stats_red,
                                              float* __restrict__ out, int n) {
  __shared__ float xs[64][36];
  __shared__ float wsT[128][36];
  __shared__ float muL[128], sclL[128];
  const int tid = threadIdx.x;
  const int tx = tid & 31, ty = tid >> 5;
  const int br0 = blockIdx.x * 64;

  if (BN) {
    if (tid < 128) {
      float s = stats_red[tid], q = stats_red[128 + tid];
      float m = s * (1.0f / 50000.0f);
      muL[tid] = m;
      sclL[tid] = rsqrtf(q * (1.0f / 50000.0f) - m * m + EPSV);
    }
    __syncthreads();
  }

  float acc[8][4];
  #pragma unroll
  for (int r = 0; r < 8; ++r)
    #pragma unroll
    for (int c = 0; c < 4; ++c) acc[r][c] = 0.0f;

  for (int kt = 0; kt < 4; ++kt) {
    #pragma unroll
    for (int i = 0; i < 16; ++i) {  // W tile 32x128, stored transposed
      int idx = tid + i * 256;
      int kk = idx >> 7, col = idx & 127;
      wsT[col][kk] = W[(kt * 32 + kk) * 128 + col];
    }
    #pragma unroll
    for (int i = 0; i < 8; ++i) {  // x tile 64x32
      int idx = tid + i * 256;
      int kk = idx & 31, row = idx >> 5;
      int gr = br0 + row;
      float v = 0.0f;
      if (gr < n) v = in[gr * 128 + kt * 32 + kk];
      if (BN) {
        int k = kt * 32 + kk;
        v = (v - muL[k]) * sclL[k];
        v = v > 0.0f ? v : 0.0f;
      }
      xs[row][kk] = v;
    }
    __syncthreads();
    #pragma unroll
    for (int kk = 0; kk < 32; kk += 4) {
      float4 wv[4], xv[8];
      #pragma unroll
      for (int c = 0; c < 4; ++c) wv[c] = *(const float4*)&wsT[c * 32 + tx][kk];
      #pragma unroll
      for (int r = 0; r < 8; ++r) xv[r] = *(const float4*)&xs[ty * 8 + r][kk];
      #pragma unroll
      for (int r = 0; r < 8; ++r)
        #pragma unroll
        for (int c = 0; c < 4; ++c)
          acc[r][c] += xv[r].x * wv[c].x + xv[r].y * wv[c].y +
                       xv[r].z * wv[c].z + xv[r].w * wv[c].w;
    }
    __syncthreads();
  }

  #pragma unroll
  for (int r = 0; r < 8; ++r) {
    int gr = br0 + ty * 8 + r;
    if (gr >= n) continue;
    float iv = invs[gr];
    #pragma unroll
    for (int c = 0; c < 4; ++c) out[gr * 128 + c * 32 + tx] = acc[r][c] * iv;
  }
}

// ---------------------------------------------------------------- gather: h[d] = invs[d]*(hs[d]+sum hs[src]) + b; fused col-stats partials
__global__ __launch_bounds__(256) void k_gather(const float* __restrict__ hs,
                                                const int* __restrict__ row_start,
                                                const int* __restrict__ csr,
                                                const float* __restrict__ invs,
                                                const float* __restrict__ bias,
                                                float* __restrict__ out,
                                                float* __restrict__ statsP, int n) {
  const int tid = threadIdx.x;
  const int lane = tid & 63, w = tid >> 6;
  const int c0 = lane * 2;
  float s0 = 0.f, s1 = 0.f, q0 = 0.f, q1 = 0.f;
  const float bv0 = bias[c0], bv1 = bias[c0 + 1];
  const int stride = gridDim.x * 4;
  for (int node = blockIdx.x * 4 + w; node < n; node += stride) {
    float2 acc = *(const float2*)&hs[(size_t)node * 128 + c0];  // self loop
    int beg = row_start[node], end = row_start[node + 1];
    int e = beg;
    for (; e + 3 < end; e += 4) {
      int sA = csr[e], sB = csr[e + 1], sC = csr[e + 2], sD = csr[e + 3];
      float2 vA = *(const float2*)&hs[(size_t)sA * 128 + c0];
      float2 vB = *(const float2*)&hs[(size_t)sB * 128 + c0];
      float2 vC = *(const float2*)&hs[(size_t)sC * 128 + c0];
      float2 vD = *(const float2*)&hs[(size_t)sD * 128 + c0];
      acc.x += (vA.x + vB.x) + (vC.x + vD.x);
      acc.y += (vA.y + vB.y) + (vC.y + vD.y);
    }
    for (; e < end; ++e) {
      int sA = csr[e];
      float2 vA = *(const float2*)&hs[(size_t)sA * 128 + c0];
      acc.x += vA.x;
      acc.y += vA.y;
    }
    float iv = invs[node];
    float o0 = acc.x * iv + bv0, o1 = acc.y * iv + bv1;
    float2 o = make_float2(o0, o1);
    *(float2*)&out[(size_t)node * 128 + c0] = o;
    s0 += o0; s1 += o1; q0 += o0 * o0; q1 += o1 * o1;
  }
  __shared__ float redS[4][128], redQ[4][128];
  redS[w][c0] = s0; redS[w][c0 + 1] = s1;
  redQ[w][c0] = q0; redQ[w][c0 + 1] = q1;
  __syncthreads();
  if (tid < 128) {
    float s = redS[0][tid] + redS[1][tid] + redS[2][tid] + redS[3][tid];
    statsP[blockIdx.x * 256 + tid] = s;
  } else {
    int t = tid - 128;
    float q = redQ[0][t] + redQ[1][t] + redQ[2][t] + redQ[3][t];
    statsP[blockIdx.x * 256 + tid] = q;
  }
}

// ---------------------------------------------------------------- reduce stats partials -> stats_red[256]
__global__ __launch_bounds__(1024) void k_finstats(const float* __restrict__ statsP,
                                                   float* __restrict__ stats_red,
                                                   int nb) {
  int t = threadIdx.x;
  int c = blockIdx.x * 16 + (t & 15);
  int b0 = t >> 4;
  int per = nb >> 6;
  float s = 0.f;
  for (int j = 0; j < per; ++j) s += statsP[(b0 * per + j) * 256 + c];
  __shared__ float red[1024];
  red[t] = s;
  __syncthreads();
  for (int st = 512; st >= 16; st >>= 1) {
    if (t < st) red[t] += red[t + st];
    __syncthreads();
  }
  if (t < 16) stats_red[blockIdx.x * 16 + t] = red[t];
}

// ---------------------------------------------------------------- pool over partition-sorted rows (no atomics)
// grid = 64 partitions * 4 sub-blocks; 512 threads (8 waves)
__global__ __launch_bounds__(512) void k_pool2(const float* __restrict__ h,
                                               const float* __restrict__ stats_red,
                                               const float* __restrict__ cv,
                                               const int* __restrict__ perm,
                                               const int* __restrict__ pstart,
                                               float* __restrict__ poolP, int n) {
  const int tid = threadIdx.x;
  const int lane = tid & 63, w = tid >> 6;
  const int p = blockIdx.x >> 2, s = blockIdx.x & 3;
  const int g = s * 8 + w;  // 0..31 wave slot within partition
  const int c0 = lane * 2;

  float s0 = stats_red[c0], s1 = stats_red[c0 + 1];
  float qq0 = stats_red[128 + c0], qq1 = stats_red[128 + c0 + 1];
  float mu0 = s0 * (1.0f / 50000.0f), mu1 = s1 * (1.0f / 50000.0f);
  float scl0 = rsqrtf(qq0 * (1.0f / 50000.0f) - mu0 * mu0 + EPSV);
  float scl1 = rsqrtf(qq1 * (1.0f / 50000.0f) - mu1 * mu1 + EPSV);

  const int beg = pstart[p], end = pstart[p + 1];
  float cc0 = 0.f, cc1 = 0.f, cn0 = 0.f, cn1 = 0.f;

  int j = beg + g;
  for (; j + 32 < end; j += 64) {
    int rA = perm[j], rB = perm[j + 32];
    float2 vA = *(const float2*)&h[(size_t)rA * 128 + c0];
    float2 vB = *(const float2*)&h[(size_t)rB * 128 + c0];
    float cvA = cv[rA], cvB = cv[rB];
    float xA0 = (vA.x - mu0) * scl0; xA0 = xA0 > 0.f ? xA0 : 0.f;
    float xA1 = (vA.y - mu1) * scl1; xA1 = xA1 > 0.f ? xA1 : 0.f;
    float xB0 = (vB.x - mu0) * scl0; xB0 = xB0 > 0.f ? xB0 : 0.f;
    float xB1 = (vB.y - mu1) * scl1; xB1 = xB1 > 0.f ? xB1 : 0.f;
    cc0 += xA0 * cvA + xB0 * cvB;
    cc1 += xA1 * cvA + xB1 * cvB;
    cn0 += xA0 * (1.f - cvA) + xB0 * (1.f - cvB);
    cn1 += xA1 * (1.f - cvA) + xB1 * (1.f - cvB);
  }
  if (j < end) {
    int rA = perm[j];
    float2 vA = *(const float2*)&h[(size_t)rA * 128 + c0];
    float cvA = cv[rA];
    float xA0 = (vA.x - mu0) * scl0; xA0 = xA0 > 0.f ? xA0 : 0.f;
    float xA1 = (vA.y - mu1) * scl1; xA1 = xA1 > 0.f ? xA1 : 0.f;
    cc0 += xA0 * cvA;
    cc1 += xA1 * cvA;
    cn0 += xA0 * (1.f - cvA);
    cn1 += xA1 * (1.f - cvA);
  }

  __shared__ float redC[8][128], redN[8][128];
  redC[w][c0] = cc0; redC[w][c0 + 1] = cc1;
  redN[w][c0] = cn0; redN[w][c0 + 1] = cn1;
  __syncthreads();
  if (tid < 128) {
    float a = 0.f;
    #pragma unroll
    for (int ww = 0; ww < 8; ++ww) a += redC[ww][tid];
    poolP[blockIdx.x * 256 + tid] = a;
  } else if (tid < 256) {
    int t = tid - 128;
    float a = 0.f;
    #pragma unroll
    for (int ww = 0; ww < 8; ++ww) a += redN[ww][t];
    poolP[blockIdx.x * 256 + tid] = a;
  }
}

// ---------------------------------------------------------------- final MLP: one block per partition
__global__ __launch_bounds__(128) void k_mlp(const float* __restrict__ h,
                                             const float* __restrict__ stats_red,
                                             const float* __restrict__ poolP,
                                             const float* __restrict__ l1W,
                                             const float* __restrict__ l1b,
                                             const float* __restrict__ l2W,
                                             const float* __restrict__ l2b,
                                             const int* __restrict__ curr_ptr,
                                             float* __restrict__ out, int n) {
  const int p = blockIdx.x;
  const int t = threadIdx.x;  // 128 threads
  __shared__ float z[384];
  int curr = *curr_ptr;
  float s = stats_red[t], q = stats_red[128 + t];
  float mu = s / (float)n;
  float scl = rsqrtf(q / (float)n - mu * mu + EPSV);
  float v = h[(size_t)curr * 128 + t];
  v = (v - mu) * scl;
  z[t] = v > 0.f ? v : 0.f;
  float ccore = 0.f, cnon = 0.f;
  #pragma unroll
  for (int sb = 0; sb < 4; ++sb) {
    ccore += poolP[(p * 4 + sb) * 256 + t];
    cnon  += poolP[(p * 4 + sb) * 256 + 128 + t];
  }
  z[128 + t] = ccore;
  z[256 + t] = cnon;
  __syncthreads();
  float a = l1b[t];
  for (int k = 0; k < 384; ++k) a += z[k] * l1W[k * 128 + t];
  a = a > 0.f ? a : 0.f;
  float pr = a * l2W[t];
  #pragma unroll
  for (int off = 32; off; off >>= 1) pr += __shfl_down(pr, off);
  __shared__ float rr[2];
  if ((t & 63) == 0) rr[t >> 6] = pr;
  __syncthreads();
  if (t == 0) out[p] = rr[0] + rr[1] + l2b[0];
}

// ================================================================ host
extern "C" void kernel_launch(void* const* d_in, const int* in_sizes, int n_in,
                              void* d_out, int out_size, void* d_ws, size_t ws_size,
                              hipStream_t stream) {
  const float* x    = (const float*)d_in[0];
  const float* cv   = (const float*)d_in[1];
  const float* W0   = (const float*)d_in[2];
  const float* b0   = (const float*)d_in[3];
  const float* W1   = (const float*)d_in[4];
  const float* b1   = (const float*)d_in[5];
  const float* l1W  = (const float*)d_in[6];
  const float* l1b  = (const float*)d_in[7];
  const float* l2W  = (const float*)d_in[8];
  const float* l2b  = (const float*)d_in[9];
  const int*   ei   = (const int*)d_in[10];
  const int*   part = (const int*)d_in[11];
  const int*   curr = (const int*)d_in[12];

  const int N = in_sizes[1];          // 50000
  const int E = in_sizes[10] / 2;     // 640000
  const int* src = ei;
  const int* dst = ei + E;

  const int GATHER_BLOCKS = 2048;

  char* w = (char*)d_ws;
  size_t off = 0;
  auto alloc = [&](size_t bytes) -> void* {
    void* p = (void*)(w + off);
    off = (off + bytes + 255) & ~(size_t)255;
    return p;
  };
  int*   hist      = (int*)alloc((size_t)N * 4);
  int*   cursor    = (int*)alloc((size_t)N * 4);
  int*   row_start = (int*)alloc((size_t)(N + 1) * 4);
  int*   csr       = (int*)alloc((size_t)E * 4);
  float* invs      = (float*)alloc((size_t)N * 4);
  int*   ph        = (int*)alloc(64 * 4);
  int*   pcur      = (int*)alloc(64 * 4);
  int*   pstart    = (int*)alloc(65 * 4);
  int*   perm      = (int*)alloc((size_t)N * 4);
  float* stats_red0 = (float*)alloc(256 * 4);
  float* stats_red1 = (float*)alloc(256 * 4);
  float* statsP    = (float*)alloc((size_t)GATHER_BLOCKS * 256 * 4);
  float* poolP     = (float*)alloc((size_t)256 * 256 * 4);
  float* hs        = (float*)alloc((size_t)N * 128 * 4);
  float* h         = (float*)alloc((size_t)N * 128 * 4);
  (void)ws_size;

  hipMemsetAsync(hist, 0, (size_t)N * 4, stream);
  hipMemsetAsync(ph, 0, 64 * 4, stream);

  int eb = (E + 255) / 256;
  int nb = (N + 255) / 256;
  // CSR build (edges)
  k_hist<<<eb, 256, 0, stream>>>(dst, hist, E);
  k_scan<<<1, 1024, 0, stream>>>(hist, row_start, cursor, invs, N);
  k_scatter<<<eb, 256, 0, stream>>>(src, dst, cursor, csr, E);
  // partition counting sort (nodes)
  k_phist<<<128, 256, 0, stream>>>(part, ph, N);
  k_pscan<<<1, 64, 0, stream>>>(ph, pstart, pcur);
  k_pscatter<<<nb, 256, 0, stream>>>(part, pcur, perm, N);

  int gb = (N + 63) / 64;
  // layer 1
  k_gemm<false><<<gb, 256, 0, stream>>>(x, W0, invs, nullptr, hs, N);
  k_gather<<<GATHER_BLOCKS, 256, 0, stream>>>(hs, row_start, csr, invs, b0, h, statsP, N);
  k_finstats<<<16, 1024, 0, stream>>>(statsP, stats_red0, GATHER_BLOCKS);
  // layer 2 (BN+ReLU of layer1 fused into GEMM input transform)
  k_gemm<true><<<gb, 256, 0, stream>>>(h, W1, invs, stats_red0, hs, N);
  k_gather<<<GATHER_BLOCKS, 256, 0, stream>>>(hs, row_start, csr, invs, b1, h, statsP, N);
  k_finstats<<<16, 1024, 0, stream>>>(statsP, stats_red1, GATHER_BLOCKS);
  // pooling + head (BN+ReLU of layer2 fused into loads)
  k_pool2<<<256, 512, 0, stream>>>(h, stats_red1, cv, perm, pstart, poolP, N);
  k_mlp<<<64, 128, 0, stream>>>(h, stats_red1, poolP, l1W, l1b, l2W, l2b, curr, (float*)d_out, N);
}

// Round 3
// 347.689 us; speedup vs baseline: 1.7790x; 1.5868x over previous
//
#include <hip/hip_runtime.h>
#include <math.h>

#define EPSV 1e-5f

typedef __attribute__((ext_vector_type(8))) short bf16x8;
typedef __attribute__((ext_vector_type(4))) float f32x4;

__device__ __forceinline__ uint f2b(float f) {  // fp32 -> bf16 bits (RNE)
  uint u = __builtin_bit_cast(uint, f);
  return (u + 0x7FFFu + ((u >> 16) & 1u)) >> 16;
}
__device__ __forceinline__ float blo(uint v) { return __builtin_bit_cast(float, v << 16); }
__device__ __forceinline__ float bhi(uint v) { return __builtin_bit_cast(float, v & 0xFFFF0000u); }

// ---------------------------------------------------------------- hist (edge in-degree)
__global__ __launch_bounds__(256) void k_hist(const int* __restrict__ dst,
                                              int* __restrict__ hist, int e) {
  int i = blockIdx.x * 256 + threadIdx.x;
  if (i < e) atomicAdd(&hist[dst[i]], 1);
}

// ---------------------------------------------------------------- scan (single block)
__global__ __launch_bounds__(1024) void k_scan(const int* __restrict__ hist,
                                               int* __restrict__ row_start,
                                               int* __restrict__ cursor,
                                               float* __restrict__ invs, int n) {
  __shared__ int wtot[16];
  int tid = threadIdx.x, lane = tid & 63, w = tid >> 6;
  int running = 0;
  int nch = (n + 1023) >> 10;
  for (int ch = 0; ch < nch; ++ch) {
    int i = (ch << 10) + tid;
    int v = (i < n) ? hist[i] : 0;
    int x = v;
    #pragma unroll
    for (int off = 1; off < 64; off <<= 1) {
      int y = __shfl_up(x, off);
      if (lane >= off) x += y;
    }
    if (lane == 63) wtot[w] = x;
    __syncthreads();
    if (w == 0) {
      int t = (lane < 16) ? wtot[lane] : 0;
      #pragma unroll
      for (int off = 1; off < 16; off <<= 1) {
        int y = __shfl_up(t, off);
        if (lane >= off) t += y;
      }
      if (lane < 16) wtot[lane] = t;
    }
    __syncthreads();
    int base = running + ((w > 0) ? wtot[w - 1] : 0);
    if (i < n) {
      int excl = base + x - v;
      row_start[i] = excl;
      cursor[i] = excl;
      invs[i] = rsqrtf((float)(v + 1));
    }
    running += wtot[15];
    __syncthreads();
  }
  if (tid == 0) row_start[n] = running;
}

// ---------------------------------------------------------------- scatter edges into CSR
__global__ __launch_bounds__(256) void k_scatter(const int* __restrict__ src,
                                                 const int* __restrict__ dst,
                                                 int* __restrict__ cursor,
                                                 int* __restrict__ csr, int e) {
  int i = blockIdx.x * 256 + threadIdx.x;
  if (i < e) {
    int d = dst[i];
    int pos = atomicAdd(&cursor[d], 1);
    csr[pos] = src[i];
  }
}

// ---------------------------------------------------------------- partition histogram
__global__ __launch_bounds__(256) void k_phist(const int* __restrict__ part,
                                               int* __restrict__ ph, int n) {
  __shared__ int lh[64];
  int tid = threadIdx.x;
  if (tid < 64) lh[tid] = 0;
  __syncthreads();
  for (int i = blockIdx.x * 256 + tid; i < n; i += gridDim.x * 256)
    atomicAdd(&lh[part[i]], 1);
  __syncthreads();
  if (tid < 64) atomicAdd(&ph[tid], lh[tid]);
}

// ---------------------------------------------------------------- partition scan (1 wave)
__global__ __launch_bounds__(64) void k_pscan(const int* __restrict__ ph,
                                              int* __restrict__ pstart,
                                              int* __restrict__ pcur) {
  int lane = threadIdx.x;
  int v = ph[lane];
  int x = v;
  #pragma unroll
  for (int off = 1; off < 64; off <<= 1) {
    int y = __shfl_up(x, off);
    if (lane >= off) x += y;
  }
  pstart[lane] = x - v;
  pcur[lane] = x - v;
  if (lane == 63) pstart[64] = x;
}

// ---------------------------------------------------------------- node counting-sort scatter
__global__ __launch_bounds__(256) void k_pscatter(const int* __restrict__ part,
                                                  int* __restrict__ pcur,
                                                  int* __restrict__ perm, int n) {
  int i = blockIdx.x * 256 + threadIdx.x;
  if (i < n) {
    int p = part[i];
    int pos = atomicAdd(&pcur[p], 1);
    perm[pos] = i;
  }
}

// ---------------------------------------------------------------- W cast+transpose: WT[c][k] = bf16(W[k][c])
__global__ __launch_bounds__(256) void k_castW(const float* __restrict__ W0,
                                               const float* __restrict__ W1,
                                               ushort* __restrict__ WT0,
                                               ushort* __restrict__ WT1) {
  int idx = blockIdx.x * 256 + threadIdx.x;  // 32768 total
  const float* W = (idx < 16384) ? W0 : W1;
  ushort* WT = (idx < 16384) ? WT0 : WT1;
  int j = idx & 16383;
  int c = j >> 7, k = j & 127;
  WT[j] = (ushort)f2b(W[k * 128 + c]);
}

// ---------------------------------------------------------------- MFMA GEMM:
// outb[r][c] = bf16( (transform(in)[r] @ W)[c] * invs[r] )
// transform = identity (layer1) or BN+ReLU via stats_red (layer2)
template <bool BN>
__global__ __launch_bounds__(256) void k_gemm(const float* __restrict__ in,
                                              const ushort* __restrict__ WT,
                                              const float* __restrict__ invs,
                                              const float* __restrict__ stats_red,
                                              ushort* __restrict__ outb, int n) {
  __shared__ ushort As[16384];  // [row][k], XOR-swizzled
  __shared__ ushort Bs[16384];  // [col][k], XOR-swizzled
  __shared__ float muL[128], sclL[128];
  const int tid = threadIdx.x;
  const int l = tid & 63, w = tid >> 6;
  const int br0 = blockIdx.x * 128;

  if (BN) {
    if (tid < 128) {
      float s = stats_red[tid], q = stats_red[128 + tid];
      float m = s * (1.0f / 50000.0f);
      muL[tid] = m;
      sclL[tid] = rsqrtf(q * (1.0f / 50000.0f) - m * m + EPSV);
    }
    __syncthreads();
  }

  // stage B (already bf16, [c][k] contiguous)
  #pragma unroll
  for (int i = 0; i < 8; ++i) {
    int flat = i * 2048 + tid * 8;
    int c = flat >> 7;
    uint4 v = *(const uint4*)&WT[flat];
    *(uint4*)&Bs[flat ^ ((c & 7) << 3)] = v;
  }
  // stage A (fp32 -> optional BN+ReLU -> bf16)
  #pragma unroll
  for (int i = 0; i < 8; ++i) {
    int flat = i * 2048 + tid * 8;
    int row = flat >> 7, k0 = flat & 127;
    int grow = br0 + row;
    uint4 u;
    if (grow < n) {
      float4 v0 = *(const float4*)&in[(size_t)grow * 128 + k0];
      float4 v1 = *(const float4*)&in[(size_t)grow * 128 + k0 + 4];
      if (BN) {
        float4 m0 = *(const float4*)&muL[k0], m1 = *(const float4*)&muL[k0 + 4];
        float4 s0 = *(const float4*)&sclL[k0], s1 = *(const float4*)&sclL[k0 + 4];
        v0.x = (v0.x - m0.x) * s0.x; v0.x = v0.x > 0.f ? v0.x : 0.f;
        v0.y = (v0.y - m0.y) * s0.y; v0.y = v0.y > 0.f ? v0.y : 0.f;
        v0.z = (v0.z - m0.z) * s0.z; v0.z = v0.z > 0.f ? v0.z : 0.f;
        v0.w = (v0.w - m0.w) * s0.w; v0.w = v0.w > 0.f ? v0.w : 0.f;
        v1.x = (v1.x - m1.x) * s1.x; v1.x = v1.x > 0.f ? v1.x : 0.f;
        v1.y = (v1.y - m1.y) * s1.y; v1.y = v1.y > 0.f ? v1.y : 0.f;
        v1.z = (v1.z - m1.z) * s1.z; v1.z = v1.z > 0.f ? v1.z : 0.f;
        v1.w = (v1.w - m1.w) * s1.w; v1.w = v1.w > 0.f ? v1.w : 0.f;
      }
      u.x = f2b(v0.x) | (f2b(v0.y) << 16);
      u.y = f2b(v0.z) | (f2b(v0.w) << 16);
      u.z = f2b(v1.x) | (f2b(v1.y) << 16);
      u.w = f2b(v1.z) | (f2b(v1.w) << 16);
    } else {
      u.x = u.y = u.z = u.w = 0u;
    }
    *(uint4*)&As[flat ^ ((row & 7) << 3)] = u;
  }
  __syncthreads();

  const int wr = w >> 1, wc = w & 1;
  const int lr = l & 15, lk = (l >> 4) * 8;
  f32x4 acc[4][4];
  #pragma unroll
  for (int m = 0; m < 4; ++m)
    #pragma unroll
    for (int nn = 0; nn < 4; ++nn) acc[m][nn] = (f32x4){0.f, 0.f, 0.f, 0.f};

  #pragma unroll
  for (int ks = 0; ks < 4; ++ks) {
    bf16x8 af[4], bfr[4];
    #pragma unroll
    for (int m = 0; m < 4; ++m) {
      int row = wr * 64 + m * 16 + lr;
      af[m] = *(const bf16x8*)&As[(row * 128 + ks * 32 + lk) ^ ((row & 7) << 3)];
    }
    #pragma unroll
    for (int nn = 0; nn < 4; ++nn) {
      int c = wc * 64 + nn * 16 + lr;
      bfr[nn] = *(const bf16x8*)&Bs[(c * 128 + ks * 32 + lk) ^ ((c & 7) << 3)];
    }
    #pragma unroll
    for (int m = 0; m < 4; ++m)
      #pragma unroll
      for (int nn = 0; nn < 4; ++nn)
        acc[m][nn] = __builtin_amdgcn_mfma_f32_16x16x32_bf16(af[m], bfr[nn], acc[m][nn], 0, 0, 0);
  }

  #pragma unroll
  for (int m = 0; m < 4; ++m) {
    #pragma unroll
    for (int r = 0; r < 4; ++r) {
      int row = br0 + wr * 64 + m * 16 + (l >> 4) * 4 + r;
      if (row >= n) continue;
      float iv = invs[row];
      #pragma unroll
      for (int nn = 0; nn < 4; ++nn) {
        int col = wc * 64 + nn * 16 + lr;
        outb[(size_t)row * 128 + col] = (ushort)f2b(acc[m][nn][r] * iv);
      }
    }
  }
}

// ---------------------------------------------------------------- gather (bf16 hs): h[d] = invs[d]*(hs[d]+sum hs[src]) + b
__global__ __launch_bounds__(256) void k_gather(const ushort* __restrict__ hsb,
                                                const int* __restrict__ row_start,
                                                const int* __restrict__ csr,
                                                const float* __restrict__ invs,
                                                const float* __restrict__ bias,
                                                float* __restrict__ out,
                                                float* __restrict__ statsP, int n) {
  const int tid = threadIdx.x;
  const int lane = tid & 63, w = tid >> 6;
  const int c0 = lane * 2;
  float s0 = 0.f, s1 = 0.f, q0 = 0.f, q1 = 0.f;
  const float bv0 = bias[c0], bv1 = bias[c0 + 1];
  const int stride = gridDim.x * 4;
  for (int node = blockIdx.x * 4 + w; node < n; node += stride) {
    uint vs = *(const uint*)&hsb[(size_t)node * 128 + c0];  // self loop
    float accx = blo(vs), accy = bhi(vs);
    int beg = row_start[node], end = row_start[node + 1];
    int e = beg;
    for (; e + 3 < end; e += 4) {
      int sA = csr[e], sB = csr[e + 1], sC = csr[e + 2], sD = csr[e + 3];
      uint vA = *(const uint*)&hsb[(size_t)sA * 128 + c0];
      uint vB = *(const uint*)&hsb[(size_t)sB * 128 + c0];
      uint vC = *(const uint*)&hsb[(size_t)sC * 128 + c0];
      uint vD = *(const uint*)&hsb[(size_t)sD * 128 + c0];
      accx += (blo(vA) + blo(vB)) + (blo(vC) + blo(vD));
      accy += (bhi(vA) + bhi(vB)) + (bhi(vC) + bhi(vD));
    }
    for (; e < end; ++e) {
      uint vA = *(const uint*)&hsb[(size_t)csr[e] * 128 + c0];
      accx += blo(vA);
      accy += bhi(vA);
    }
    float iv = invs[node];
    float o0 = accx * iv + bv0, o1 = accy * iv + bv1;
    *(float2*)&out[(size_t)node * 128 + c0] = make_float2(o0, o1);
    s0 += o0; s1 += o1; q0 += o0 * o0; q1 += o1 * o1;
  }
  __shared__ float redS[4][128], redQ[4][128];
  redS[w][c0] = s0; redS[w][c0 + 1] = s1;
  redQ[w][c0] = q0; redQ[w][c0 + 1] = q1;
  __syncthreads();
  if (tid < 128) {
    float s = redS[0][tid] + redS[1][tid] + redS[2][tid] + redS[3][tid];
    statsP[blockIdx.x * 256 + tid] = s;
  } else {
    int t = tid - 128;
    float q = redQ[0][t] + redQ[1][t] + redQ[2][t] + redQ[3][t];
    statsP[blockIdx.x * 256 + tid] = q;
  }
}

// ---------------------------------------------------------------- reduce stats partials -> stats_red[256]
__global__ __launch_bounds__(1024) void k_finstats(const float* __restrict__ statsP,
                                                   float* __restrict__ stats_red,
                                                   int nb) {
  int t = threadIdx.x;
  int c = blockIdx.x * 16 + (t & 15);
  int b0 = t >> 4;
  int per = nb >> 6;
  float s = 0.f;
  for (int j = 0; j < per; ++j) s += statsP[(b0 * per + j) * 256 + c];
  __shared__ float red[1024];
  red[t] = s;
  __syncthreads();
  for (int st = 512; st >= 16; st >>= 1) {
    if (t < st) red[t] += red[t + st];
    __syncthreads();
  }
  if (t < 16) stats_red[blockIdx.x * 16 + t] = red[t];
}

// ---------------------------------------------------------------- pool over partition-sorted rows (no atomics)
__global__ __launch_bounds__(512) void k_pool2(const float* __restrict__ h,
                                               const float* __restrict__ stats_red,
                                               const float* __restrict__ cv,
                                               const int* __restrict__ perm,
                                               const int* __restrict__ pstart,
                                               float* __restrict__ poolP, int n) {
  const int tid = threadIdx.x;
  const int lane = tid & 63, w = tid >> 6;
  const int p = blockIdx.x >> 2, s = blockIdx.x & 3;
  const int g = s * 8 + w;
  const int c0 = lane * 2;

  float s0 = stats_red[c0], s1 = stats_red[c0 + 1];
  float qq0 = stats_red[128 + c0], qq1 = stats_red[128 + c0 + 1];
  float mu0 = s0 * (1.0f / 50000.0f), mu1 = s1 * (1.0f / 50000.0f);
  float scl0 = rsqrtf(qq0 * (1.0f / 50000.0f) - mu0 * mu0 + EPSV);
  float scl1 = rsqrtf(qq1 * (1.0f / 50000.0f) - mu1 * mu1 + EPSV);

  const int beg = pstart[p], end = pstart[p + 1];
  float cc0 = 0.f, cc1 = 0.f, cn0 = 0.f, cn1 = 0.f;

  int j = beg + g;
  for (; j + 32 < end; j += 64) {
    int rA = perm[j], rB = perm[j + 32];
    float2 vA = *(const float2*)&h[(size_t)rA * 128 + c0];
    float2 vB = *(const float2*)&h[(size_t)rB * 128 + c0];
    float cvA = cv[rA], cvB = cv[rB];
    float xA0 = (vA.x - mu0) * scl0; xA0 = xA0 > 0.f ? xA0 : 0.f;
    float xA1 = (vA.y - mu1) * scl1; xA1 = xA1 > 0.f ? xA1 : 0.f;
    float xB0 = (vB.x - mu0) * scl0; xB0 = xB0 > 0.f ? xB0 : 0.f;
    float xB1 = (vB.y - mu1) * scl1; xB1 = xB1 > 0.f ? xB1 : 0.f;
    cc0 += xA0 * cvA + xB0 * cvB;
    cc1 += xA1 * cvA + xB1 * cvB;
    cn0 += xA0 * (1.f - cvA) + xB0 * (1.f - cvB);
    cn1 += xA1 * (1.f - cvA) + xB1 * (1.f - cvB);
  }
  if (j < end) {
    int rA = perm[j];
    float2 vA = *(const float2*)&h[(size_t)rA * 128 + c0];
    float cvA = cv[rA];
    float xA0 = (vA.x - mu0) * scl0; xA0 = xA0 > 0.f ? xA0 : 0.f;
    float xA1 = (vA.y - mu1) * scl1; xA1 = xA1 > 0.f ? xA1 : 0.f;
    cc0 += xA0 * cvA;
    cc1 += xA1 * cvA;
    cn0 += xA0 * (1.f - cvA);
    cn1 += xA1 * (1.f - cvA);
  }

  __shared__ float redC[8][128], redN[8][128];
  redC[w][c0] = cc0; redC[w][c0 + 1] = cc1;
  redN[w][c0] = cn0; redN[w][c0 + 1] = cn1;
  __syncthreads();
  if (tid < 128) {
    float a = 0.f;
    #pragma unroll
    for (int ww = 0; ww < 8; ++ww) a += redC[ww][tid];
    poolP[blockIdx.x * 256 + tid] = a;
  } else if (tid < 256) {
    int t = tid - 128;
    float a = 0.f;
    #pragma unroll
    for (int ww = 0; ww < 8; ++ww) a += redN[ww][t];
    poolP[blockIdx.x * 256 + tid] = a;
  }
}

// ---------------------------------------------------------------- final MLP: one block per partition
__global__ __launch_bounds__(128) void k_mlp(const float* __restrict__ h,
                                             const float* __restrict__ stats_red,
                                             const float* __restrict__ poolP,
                                             const float* __restrict__ l1W,
                                             const float* __restrict__ l1b,
                                             const float* __restrict__ l2W,
                                             const float* __restrict__ l2b,
                                             const int* __restrict__ curr_ptr,
                                             float* __restrict__ out, int n) {
  const int p = blockIdx.x;
  const int t = threadIdx.x;
  __shared__ float z[384];
  int curr = *curr_ptr;
  float s = stats_red[t], q = stats_red[128 + t];
  float mu = s / (float)n;
  float scl = rsqrtf(q / (float)n - mu * mu + EPSV);
  float v = h[(size_t)curr * 128 + t];
  v = (v - mu) * scl;
  z[t] = v > 0.f ? v : 0.f;
  float ccore = 0.f, cnon = 0.f;
  #pragma unroll
  for (int sb = 0; sb < 4; ++sb) {
    ccore += poolP[(p * 4 + sb) * 256 + t];
    cnon  += poolP[(p * 4 + sb) * 256 + 128 + t];
  }
  z[128 + t] = ccore;
  z[256 + t] = cnon;
  __syncthreads();
  float a = l1b[t];
  for (int k = 0; k < 384; ++k) a += z[k] * l1W[k * 128 + t];
  a = a > 0.f ? a : 0.f;
  float pr = a * l2W[t];
  #pragma unroll
  for (int off = 32; off; off >>= 1) pr += __shfl_down(pr, off);
  __shared__ float rr[2];
  if ((t & 63) == 0) rr[t >> 6] = pr;
  __syncthreads();
  if (t == 0) out[p] = rr[0] + rr[1] + l2b[0];
}

// ================================================================ host
extern "C" void kernel_launch(void* const* d_in, const int* in_sizes, int n_in,
                              void* d_out, int out_size, void* d_ws, size_t ws_size,
                              hipStream_t stream) {
  const float* x    = (const float*)d_in[0];
  const float* cv   = (const float*)d_in[1];
  const float* W0   = (const float*)d_in[2];
  const float* b0   = (const float*)d_in[3];
  const float* W1   = (const float*)d_in[4];
  const float* b1   = (const float*)d_in[5];
  const float* l1W  = (const float*)d_in[6];
  const float* l1b  = (const float*)d_in[7];
  const float* l2W  = (const float*)d_in[8];
  const float* l2b  = (const float*)d_in[9];
  const int*   ei   = (const int*)d_in[10];
  const int*   part = (const int*)d_in[11];
  const int*   curr = (const int*)d_in[12];

  const int N = in_sizes[1];          // 50000
  const int E = in_sizes[10] / 2;     // 640000
  const int* src = ei;
  const int* dst = ei + E;

  const int GATHER_BLOCKS = 2048;

  char* w = (char*)d_ws;
  size_t off = 0;
  auto alloc = [&](size_t bytes) -> void* {
    void* p = (void*)(w + off);
    off = (off + bytes + 255) & ~(size_t)255;
    return p;
  };
  int*   hist      = (int*)alloc((size_t)N * 4);
  int*   cursor    = (int*)alloc((size_t)N * 4);
  int*   row_start = (int*)alloc((size_t)(N + 1) * 4);
  int*   csr       = (int*)alloc((size_t)E * 4);
  float* invs      = (float*)alloc((size_t)N * 4);
  int*   ph        = (int*)alloc(64 * 4);
  int*   pcur      = (int*)alloc(64 * 4);
  int*   pstart    = (int*)alloc(65 * 4);
  int*   perm      = (int*)alloc((size_t)N * 4);
  float* stats_red0 = (float*)alloc(256 * 4);
  float* stats_red1 = (float*)alloc(256 * 4);
  float* statsP    = (float*)alloc((size_t)GATHER_BLOCKS * 256 * 4);
  float* poolP     = (float*)alloc((size_t)256 * 256 * 4);
  ushort* WT0      = (ushort*)alloc((size_t)16384 * 2);
  ushort* WT1      = (ushort*)alloc((size_t)16384 * 2);
  ushort* hsb      = (ushort*)alloc((size_t)N * 128 * 2);
  float* h         = (float*)alloc((size_t)N * 128 * 4);
  (void)ws_size;

  hipMemsetAsync(hist, 0, (size_t)N * 4, stream);
  hipMemsetAsync(ph, 0, 64 * 4, stream);

  int eb = (E + 255) / 256;
  int nb = (N + 255) / 256;
  // CSR build (edges)
  k_hist<<<eb, 256, 0, stream>>>(dst, hist, E);
  k_scan<<<1, 1024, 0, stream>>>(hist, row_start, cursor, invs, N);
  k_scatter<<<eb, 256, 0, stream>>>(src, dst, cursor, csr, E);
  // partition counting sort (nodes)
  k_phist<<<128, 256, 0, stream>>>(part, ph, N);
  k_pscan<<<1, 64, 0, stream>>>(ph, pstart, pcur);
  k_pscatter<<<nb, 256, 0, stream>>>(part, pcur, perm, N);
  // weights -> bf16 transposed
  k_castW<<<128, 256, 0, stream>>>(W0, W1, WT0, WT1);

  int gb = (N + 127) / 128;
  // layer 1
  k_gemm<false><<<gb, 256, 0, stream>>>(x, WT0, invs, nullptr, hsb, N);
  k_gather<<<GATHER_BLOCKS, 256, 0, stream>>>(hsb, row_start, csr, invs, b0, h, statsP, N);
  k_finstats<<<16, 1024, 0, stream>>>(statsP, stats_red0, GATHER_BLOCKS);
  // layer 2 (BN+ReLU of layer1 fused into GEMM staging)
  k_gemm<true><<<gb, 256, 0, stream>>>(h, WT1, invs, stats_red0, hsb, N);
  k_gather<<<GATHER_BLOCKS, 256, 0, stream>>>(hsb, row_start, csr, invs, b1, h, statsP, N);
  k_finstats<<<16, 1024, 0, stream>>>(statsP, stats_red1, GATHER_BLOCKS);
  // pooling + head (BN+ReLU of layer2 fused into loads)
  k_pool2<<<256, 512, 0, stream>>>(h, stats_red1, cv, perm, pstart, poolP, N);
  k_mlp<<<64, 128, 0, stream>>>(h, stats_red1, poolP, l1W, l1b, l2W, l2b, curr, (float*)d_out, N);
}

// Round 4
// 303.169 us; speedup vs baseline: 2.0402x; 1.1469x over previous
//
#include <hip/hip_runtime.h>
#include <math.h>

#define EPSV 1e-5f
#define PSORT_NB 256

typedef __attribute__((ext_vector_type(8))) short bf16x8;
typedef __attribute__((ext_vector_type(4))) float f32x4;

__device__ __forceinline__ uint f2b(float f) {  // fp32 -> bf16 bits (RNE)
  uint u = __builtin_bit_cast(uint, f);
  return (u + 0x7FFFu + ((u >> 16) & 1u)) >> 16;
}
__device__ __forceinline__ float blo(uint v) { return __builtin_bit_cast(float, v << 16); }
__device__ __forceinline__ float bhi(uint v) { return __builtin_bit_cast(float, v & 0xFFFF0000u); }
__device__ __forceinline__ float b2f(ushort u) { return __builtin_bit_cast(float, ((uint)u) << 16); }

// ---------------------------------------------------------------- hist (edge in-degree)
__global__ __launch_bounds__(256) void k_hist(const int* __restrict__ dst,
                                              int* __restrict__ hist, int e) {
  int i = blockIdx.x * 256 + threadIdx.x;
  if (i < e) atomicAdd(&hist[dst[i]], 1);
}

// ---------------------------------------------------------------- scan (single block)
__global__ __launch_bounds__(1024) void k_scan(const int* __restrict__ hist,
                                               int* __restrict__ row_start,
                                               int* __restrict__ cursor,
                                               float* __restrict__ invs, int n) {
  __shared__ int wtot[16];
  int tid = threadIdx.x, lane = tid & 63, w = tid >> 6;
  int running = 0;
  int nch = (n + 1023) >> 10;
  for (int ch = 0; ch < nch; ++ch) {
    int i = (ch << 10) + tid;
    int v = (i < n) ? hist[i] : 0;
    int x = v;
    #pragma unroll
    for (int off = 1; off < 64; off <<= 1) {
      int y = __shfl_up(x, off);
      if (lane >= off) x += y;
    }
    if (lane == 63) wtot[w] = x;
    __syncthreads();
    if (w == 0) {
      int t = (lane < 16) ? wtot[lane] : 0;
      #pragma unroll
      for (int off = 1; off < 16; off <<= 1) {
        int y = __shfl_up(t, off);
        if (lane >= off) t += y;
      }
      if (lane < 16) wtot[lane] = t;
    }
    __syncthreads();
    int base = running + ((w > 0) ? wtot[w - 1] : 0);
    if (i < n) {
      int excl = base + x - v;
      row_start[i] = excl;
      cursor[i] = excl;
      invs[i] = rsqrtf((float)(v + 1));
    }
    running += wtot[15];
    __syncthreads();
  }
  if (tid == 0) row_start[n] = running;
}

// ---------------------------------------------------------------- scatter edges into CSR
__global__ __launch_bounds__(256) void k_scatter(const int* __restrict__ src,
                                                 const int* __restrict__ dst,
                                                 int* __restrict__ cursor,
                                                 int* __restrict__ csr, int e) {
  int i = blockIdx.x * 256 + threadIdx.x;
  if (i < e) {
    int d = dst[i];
    int pos = atomicAdd(&cursor[d], 1);
    csr[pos] = src[i];
  }
}

// ---------------------------------------------------------------- partition sort: per-block hist (no global atomics)
__global__ __launch_bounds__(256) void k_phist2(const int* __restrict__ part,
                                                int* __restrict__ blockHist, int n) {
  __shared__ int lh[64];
  int b = blockIdx.x, tid = threadIdx.x;
  if (tid < 64) lh[tid] = 0;
  __syncthreads();
  int chunk = (n + PSORT_NB - 1) / PSORT_NB;
  int beg = b * chunk, end = min(n, beg + chunk);
  for (int i = beg + tid; i < end; i += 256) atomicAdd(&lh[part[i]], 1);
  __syncthreads();
  if (tid < 64) blockHist[b * 64 + tid] = lh[tid];
}

// ---------------------------------------------------------------- partition sort: base offsets (1 wave)
__global__ __launch_bounds__(64) void k_pbase(const int* __restrict__ blockHist,
                                              int* __restrict__ base,
                                              int* __restrict__ pstart) {
  int p = threadIdx.x;  // one thread per partition
  int running = 0;
  for (int b = 0; b < PSORT_NB; ++b) {
    base[b * 64 + p] = running;
    running += blockHist[b * 64 + p];
  }
  int x = running;
  #pragma unroll
  for (int off = 1; off < 64; off <<= 1) {
    int y = __shfl_up(x, off);
    if (p >= off) x += y;
  }
  int excl = x - running;
  pstart[p] = excl;
  if (p == 63) pstart[64] = x;
  for (int b = 0; b < PSORT_NB; ++b) base[b * 64 + p] += excl;
}

// ---------------------------------------------------------------- partition sort: scatter (LDS cursors only)
__global__ __launch_bounds__(256) void k_pscatter2(const int* __restrict__ part,
                                                   const int* __restrict__ base,
                                                   int* __restrict__ perm, int n) {
  __shared__ int cur[64];
  int b = blockIdx.x, tid = threadIdx.x;
  if (tid < 64) cur[tid] = base[b * 64 + tid];
  __syncthreads();
  int chunk = (n + PSORT_NB - 1) / PSORT_NB;
  int beg = b * chunk, end = min(n, beg + chunk);
  for (int i = beg + tid; i < end; i += 256) {
    int pos = atomicAdd(&cur[part[i]], 1);
    perm[pos] = i;
  }
}

// ---------------------------------------------------------------- W cast+transpose: WT[c][k] = bf16(W[k][c])
__global__ __launch_bounds__(256) void k_castW(const float* __restrict__ W0,
                                               const float* __restrict__ W1,
                                               ushort* __restrict__ WT0,
                                               ushort* __restrict__ WT1) {
  int idx = blockIdx.x * 256 + threadIdx.x;  // 32768 total
  const float* W = (idx < 16384) ? W0 : W1;
  ushort* WT = (idx < 16384) ? WT0 : WT1;
  int j = idx & 16383;
  int c = j >> 7, k = j & 127;
  WT[j] = (ushort)f2b(W[k * 128 + c]);
}

// ---------------------------------------------------------------- MFMA GEMM:
// outb[r][c] = bf16( (transform(in)[r] @ W)[c] * invs[r] )
// BN=false: in = fp32 x;  BN=true: in = bf16 h, BN+ReLU fused via stats_red
template <bool BN>
__global__ __launch_bounds__(256) void k_gemm(const void* __restrict__ inp,
                                              const ushort* __restrict__ WT,
                                              const float* __restrict__ invs,
                                              const float* __restrict__ stats_red,
                                              ushort* __restrict__ outb, int n) {
  __shared__ ushort As[16384];  // [row][k], XOR-swizzled
  __shared__ ushort Bs[16384];  // [col][k], XOR-swizzled
  __shared__ float muL[128], sclL[128];
  const int tid = threadIdx.x;
  const int l = tid & 63, w = tid >> 6;
  const int br0 = blockIdx.x * 128;

  if (BN) {
    if (tid < 128) {
      float s = stats_red[tid], q = stats_red[128 + tid];
      float m = s * (1.0f / 50000.0f);
      muL[tid] = m;
      sclL[tid] = rsqrtf(q * (1.0f / 50000.0f) - m * m + EPSV);
    }
    __syncthreads();
  }

  // stage B (already bf16, [c][k] contiguous)
  #pragma unroll
  for (int i = 0; i < 8; ++i) {
    int flat = i * 2048 + tid * 8;
    int c = flat >> 7;
    uint4 v = *(const uint4*)&WT[flat];
    *(uint4*)&Bs[flat ^ ((c & 7) << 3)] = v;
  }
  // stage A
  #pragma unroll
  for (int i = 0; i < 8; ++i) {
    int flat = i * 2048 + tid * 8;
    int row = flat >> 7, k0 = flat & 127;
    int grow = br0 + row;
    uint4 u;
    if (grow < n) {
      if (BN) {
        const ushort* inb = (const ushort*)inp;
        uint4 raw = *(const uint4*)&inb[(size_t)grow * 128 + k0];
        float f[8] = {blo(raw.x), bhi(raw.x), blo(raw.y), bhi(raw.y),
                      blo(raw.z), bhi(raw.z), blo(raw.w), bhi(raw.w)};
        #pragma unroll
        for (int j = 0; j < 8; ++j) {
          float v = (f[j] - muL[k0 + j]) * sclL[k0 + j];
          f[j] = v > 0.f ? v : 0.f;
        }
        u.x = f2b(f[0]) | (f2b(f[1]) << 16);
        u.y = f2b(f[2]) | (f2b(f[3]) << 16);
        u.z = f2b(f[4]) | (f2b(f[5]) << 16);
        u.w = f2b(f[6]) | (f2b(f[7]) << 16);
      } else {
        const float* inf = (const float*)inp;
        float4 v0 = *(const float4*)&inf[(size_t)grow * 128 + k0];
        float4 v1 = *(const float4*)&inf[(size_t)grow * 128 + k0 + 4];
        u.x = f2b(v0.x) | (f2b(v0.y) << 16);
        u.y = f2b(v0.z) | (f2b(v0.w) << 16);
        u.z = f2b(v1.x) | (f2b(v1.y) << 16);
        u.w = f2b(v1.z) | (f2b(v1.w) << 16);
      }
    } else {
      u.x = u.y = u.z = u.w = 0u;
    }
    *(uint4*)&As[flat ^ ((row & 7) << 3)] = u;
  }
  __syncthreads();

  const int wr = w >> 1, wc = w & 1;
  const int lr = l & 15, lk = (l >> 4) * 8;
  f32x4 acc[4][4];
  #pragma unroll
  for (int m = 0; m < 4; ++m)
    #pragma unroll
    for (int nn = 0; nn < 4; ++nn) acc[m][nn] = (f32x4){0.f, 0.f, 0.f, 0.f};

  #pragma unroll
  for (int ks = 0; ks < 4; ++ks) {
    bf16x8 af[4], bfr[4];
    #pragma unroll
    for (int m = 0; m < 4; ++m) {
      int row = wr * 64 + m * 16 + lr;
      af[m] = *(const bf16x8*)&As[(row * 128 + ks * 32 + lk) ^ ((row & 7) << 3)];
    }
    #pragma unroll
    for (int nn = 0; nn < 4; ++nn) {
      int c = wc * 64 + nn * 16 + lr;
      bfr[nn] = *(const bf16x8*)&Bs[(c * 128 + ks * 32 + lk) ^ ((c & 7) << 3)];
    }
    #pragma unroll
    for (int m = 0; m < 4; ++m)
      #pragma unroll
      for (int nn = 0; nn < 4; ++nn)
        acc[m][nn] = __builtin_amdgcn_mfma_f32_16x16x32_bf16(af[m], bfr[nn], acc[m][nn], 0, 0, 0);
  }

  #pragma unroll
  for (int m = 0; m < 4; ++m) {
    #pragma unroll
    for (int r = 0; r < 4; ++r) {
      int row = br0 + wr * 64 + m * 16 + (l >> 4) * 4 + r;
      if (row >= n) continue;
      float iv = invs[row];
      #pragma unroll
      for (int nn = 0; nn < 4; ++nn) {
        int col = wc * 64 + nn * 16 + lr;
        outb[(size_t)row * 128 + col] = (ushort)f2b(acc[m][nn][r] * iv);
      }
    }
  }
}

// ---------------------------------------------------------------- gather: h[d]=bf16(invs[d]*(hs[d]+sum hs[src])+b); fp32 stats
__global__ __launch_bounds__(256) void k_gather(const ushort* __restrict__ hsb,
                                                const int* __restrict__ row_start,
                                                const int* __restrict__ csr,
                                                const float* __restrict__ invs,
                                                const float* __restrict__ bias,
                                                ushort* __restrict__ outb,
                                                float* __restrict__ statsP, int n) {
  const int tid = threadIdx.x;
  const int lane = tid & 63, w = tid >> 6;
  const int c0 = lane * 2;
  float s0 = 0.f, s1 = 0.f, q0 = 0.f, q1 = 0.f;
  const float bv0 = bias[c0], bv1 = bias[c0 + 1];
  const int stride = gridDim.x * 4;
  for (int node = blockIdx.x * 4 + w; node < n; node += stride) {
    uint vs = *(const uint*)&hsb[(size_t)node * 128 + c0];  // self loop
    float accx = blo(vs), accy = bhi(vs);
    int beg = row_start[node], end = row_start[node + 1];
    int e = beg;
    for (; e + 3 < end; e += 4) {
      int sA = csr[e], sB = csr[e + 1], sC = csr[e + 2], sD = csr[e + 3];
      uint vA = *(const uint*)&hsb[(size_t)sA * 128 + c0];
      uint vB = *(const uint*)&hsb[(size_t)sB * 128 + c0];
      uint vC = *(const uint*)&hsb[(size_t)sC * 128 + c0];
      uint vD = *(const uint*)&hsb[(size_t)sD * 128 + c0];
      accx += (blo(vA) + blo(vB)) + (blo(vC) + blo(vD));
      accy += (bhi(vA) + bhi(vB)) + (bhi(vC) + bhi(vD));
    }
    for (; e < end; ++e) {
      uint vA = *(const uint*)&hsb[(size_t)csr[e] * 128 + c0];
      accx += blo(vA);
      accy += bhi(vA);
    }
    float iv = invs[node];
    float o0 = accx * iv + bv0, o1 = accy * iv + bv1;
    *(uint*)&outb[(size_t)node * 128 + c0] = f2b(o0) | (f2b(o1) << 16);
    s0 += o0; s1 += o1; q0 += o0 * o0; q1 += o1 * o1;
  }
  __shared__ float redS[4][128], redQ[4][128];
  redS[w][c0] = s0; redS[w][c0 + 1] = s1;
  redQ[w][c0] = q0; redQ[w][c0 + 1] = q1;
  __syncthreads();
  if (tid < 128) {
    float s = redS[0][tid] + redS[1][tid] + redS[2][tid] + redS[3][tid];
    statsP[blockIdx.x * 256 + tid] = s;
  } else {
    int t = tid - 128;
    float q = redQ[0][t] + redQ[1][t] + redQ[2][t] + redQ[3][t];
    statsP[blockIdx.x * 256 + tid] = q;
  }
}

// ---------------------------------------------------------------- reduce stats partials -> stats_red[256]
__global__ __launch_bounds__(1024) void k_finstats(const float* __restrict__ statsP,
                                                   float* __restrict__ stats_red,
                                                   int nb) {
  int t = threadIdx.x;
  int c = blockIdx.x * 16 + (t & 15);
  int b0 = t >> 4;
  int per = nb >> 6;
  float s = 0.f;
  for (int j = 0; j < per; ++j) s += statsP[(b0 * per + j) * 256 + c];
  __shared__ float red[1024];
  red[t] = s;
  __syncthreads();
  for (int st = 512; st >= 16; st >>= 1) {
    if (t < st) red[t] += red[t + st];
    __syncthreads();
  }
  if (t < 16) stats_red[blockIdx.x * 16 + t] = red[t];
}

// ---------------------------------------------------------------- pool over partition-sorted rows (no atomics)
__global__ __launch_bounds__(512) void k_pool2(const ushort* __restrict__ hb,
                                               const float* __restrict__ stats_red,
                                               const float* __restrict__ cv,
                                               const int* __restrict__ perm,
                                               const int* __restrict__ pstart,
                                               float* __restrict__ poolP, int n) {
  const int tid = threadIdx.x;
  const int lane = tid & 63, w = tid >> 6;
  const int p = blockIdx.x >> 2, s = blockIdx.x & 3;
  const int g = s * 8 + w;
  const int c0 = lane * 2;

  float s0 = stats_red[c0], s1 = stats_red[c0 + 1];
  float qq0 = stats_red[128 + c0], qq1 = stats_red[128 + c0 + 1];
  float mu0 = s0 * (1.0f / 50000.0f), mu1 = s1 * (1.0f / 50000.0f);
  float scl0 = rsqrtf(qq0 * (1.0f / 50000.0f) - mu0 * mu0 + EPSV);
  float scl1 = rsqrtf(qq1 * (1.0f / 50000.0f) - mu1 * mu1 + EPSV);

  const int beg = pstart[p], end = pstart[p + 1];
  float cc0 = 0.f, cc1 = 0.f, cn0 = 0.f, cn1 = 0.f;

  int j = beg + g;
  for (; j + 32 < end; j += 64) {
    int rA = perm[j], rB = perm[j + 32];
    uint vA = *(const uint*)&hb[(size_t)rA * 128 + c0];
    uint vB = *(const uint*)&hb[(size_t)rB * 128 + c0];
    float cvA = cv[rA], cvB = cv[rB];
    float xA0 = (blo(vA) - mu0) * scl0; xA0 = xA0 > 0.f ? xA0 : 0.f;
    float xA1 = (bhi(vA) - mu1) * scl1; xA1 = xA1 > 0.f ? xA1 : 0.f;
    float xB0 = (blo(vB) - mu0) * scl0; xB0 = xB0 > 0.f ? xB0 : 0.f;
    float xB1 = (bhi(vB) - mu1) * scl1; xB1 = xB1 > 0.f ? xB1 : 0.f;
    cc0 += xA0 * cvA + xB0 * cvB;
    cc1 += xA1 * cvA + xB1 * cvB;
    cn0 += xA0 * (1.f - cvA) + xB0 * (1.f - cvB);
    cn1 += xA1 * (1.f - cvA) + xB1 * (1.f - cvB);
  }
  if (j < end) {
    int rA = perm[j];
    uint vA = *(const uint*)&hb[(size_t)rA * 128 + c0];
    float cvA = cv[rA];
    float xA0 = (blo(vA) - mu0) * scl0; xA0 = xA0 > 0.f ? xA0 : 0.f;
    float xA1 = (bhi(vA) - mu1) * scl1; xA1 = xA1 > 0.f ? xA1 : 0.f;
    cc0 += xA0 * cvA;
    cc1 += xA1 * cvA;
    cn0 += xA0 * (1.f - cvA);
    cn1 += xA1 * (1.f - cvA);
  }

  __shared__ float redC[8][128], redN[8][128];
  redC[w][c0] = cc0; redC[w][c0 + 1] = cc1;
  redN[w][c0] = cn0; redN[w][c0 + 1] = cn1;
  __syncthreads();
  if (tid < 128) {
    float a = 0.f;
    #pragma unroll
    for (int ww = 0; ww < 8; ++ww) a += redC[ww][tid];
    poolP[blockIdx.x * 256 + tid] = a;
  } else if (tid < 256) {
    int t = tid - 128;
    float a = 0.f;
    #pragma unroll
    for (int ww = 0; ww < 8; ++ww) a += redN[ww][t];
    poolP[blockIdx.x * 256 + tid] = a;
  }
}

// ---------------------------------------------------------------- final MLP: one block per partition
__global__ __launch_bounds__(128) void k_mlp(const ushort* __restrict__ hb,
                                             const float* __restrict__ stats_red,
                                             const float* __restrict__ poolP,
                                             const float* __restrict__ l1W,
                                             const float* __restrict__ l1b,
                                             const float* __restrict__ l2W,
                                             const float* __restrict__ l2b,
                                             const int* __restrict__ curr_ptr,
                                             float* __restrict__ out, int n) {
  const int p = blockIdx.x;
  const int t = threadIdx.x;
  __shared__ float z[384];
  int curr = *curr_ptr;
  float s = stats_red[t], q = stats_red[128 + t];
  float mu = s / (float)n;
  float scl = rsqrtf(q / (float)n - mu * mu + EPSV);
  float v = b2f(hb[(size_t)curr * 128 + t]);
  v = (v - mu) * scl;
  z[t] = v > 0.f ? v : 0.f;
  float ccore = 0.f, cnon = 0.f;
  #pragma unroll
  for (int sb = 0; sb < 4; ++sb) {
    ccore += poolP[(p * 4 + sb) * 256 + t];
    cnon  += poolP[(p * 4 + sb) * 256 + 128 + t];
  }
  z[128 + t] = ccore;
  z[256 + t] = cnon;
  __syncthreads();
  float a = l1b[t];
  for (int k = 0; k < 384; ++k) a += z[k] * l1W[k * 128 + t];
  a = a > 0.f ? a : 0.f;
  float pr = a * l2W[t];
  #pragma unroll
  for (int off = 32; off; off >>= 1) pr += __shfl_down(pr, off);
  __shared__ float rr[2];
  if ((t & 63) == 0) rr[t >> 6] = pr;
  __syncthreads();
  if (t == 0) out[p] = rr[0] + rr[1] + l2b[0];
}

// ================================================================ host
extern "C" void kernel_launch(void* const* d_in, const int* in_sizes, int n_in,
                              void* d_out, int out_size, void* d_ws, size_t ws_size,
                              hipStream_t stream) {
  const float* x    = (const float*)d_in[0];
  const float* cv   = (const float*)d_in[1];
  const float* W0   = (const float*)d_in[2];
  const float* b0   = (const float*)d_in[3];
  const float* W1   = (const float*)d_in[4];
  const float* b1   = (const float*)d_in[5];
  const float* l1W  = (const float*)d_in[6];
  const float* l1b  = (const float*)d_in[7];
  const float* l2W  = (const float*)d_in[8];
  const float* l2b  = (const float*)d_in[9];
  const int*   ei   = (const int*)d_in[10];
  const int*   part = (const int*)d_in[11];
  const int*   curr = (const int*)d_in[12];

  const int N = in_sizes[1];          // 50000
  const int E = in_sizes[10] / 2;     // 640000
  const int* src = ei;
  const int* dst = ei + E;

  const int GATHER_BLOCKS = 2048;

  char* w = (char*)d_ws;
  size_t off = 0;
  auto alloc = [&](size_t bytes) -> void* {
    void* p = (void*)(w + off);
    off = (off + bytes + 255) & ~(size_t)255;
    return p;
  };
  int*   hist      = (int*)alloc((size_t)N * 4);
  int*   cursor    = (int*)alloc((size_t)N * 4);
  int*   row_start = (int*)alloc((size_t)(N + 1) * 4);
  int*   csr       = (int*)alloc((size_t)E * 4);
  float* invs      = (float*)alloc((size_t)N * 4);
  int*   blockHist = (int*)alloc((size_t)PSORT_NB * 64 * 4);
  int*   pbase     = (int*)alloc((size_t)PSORT_NB * 64 * 4);
  int*   pstart    = (int*)alloc(65 * 4);
  int*   perm      = (int*)alloc((size_t)N * 4);
  float* stats_red0 = (float*)alloc(256 * 4);
  float* stats_red1 = (float*)alloc(256 * 4);
  float* statsP    = (float*)alloc((size_t)GATHER_BLOCKS * 256 * 4);
  float* poolP     = (float*)alloc((size_t)256 * 256 * 4);
  ushort* WT0      = (ushort*)alloc((size_t)16384 * 2);
  ushort* WT1      = (ushort*)alloc((size_t)16384 * 2);
  ushort* hsb      = (ushort*)alloc((size_t)N * 128 * 2);
  ushort* hb       = (ushort*)alloc((size_t)N * 128 * 2);
  (void)ws_size;

  hipMemsetAsync(hist, 0, (size_t)N * 4, stream);

  int eb = (E + 255) / 256;
  // CSR build (edges)
  k_hist<<<eb, 256, 0, stream>>>(dst, hist, E);
  k_scan<<<1, 1024, 0, stream>>>(hist, row_start, cursor, invs, N);
  k_scatter<<<eb, 256, 0, stream>>>(src, dst, cursor, csr, E);
  // partition counting sort (nodes) — no global atomics
  k_phist2<<<PSORT_NB, 256, 0, stream>>>(part, blockHist, N);
  k_pbase<<<1, 64, 0, stream>>>(blockHist, pbase, pstart);
  k_pscatter2<<<PSORT_NB, 256, 0, stream>>>(part, pbase, perm, N);
  // weights -> bf16 transposed
  k_castW<<<128, 256, 0, stream>>>(W0, W1, WT0, WT1);

  int gb = (N + 127) / 128;
  // layer 1
  k_gemm<false><<<gb, 256, 0, stream>>>(x, WT0, invs, nullptr, hsb, N);
  k_gather<<<GATHER_BLOCKS, 256, 0, stream>>>(hsb, row_start, csr, invs, b0, hb, statsP, N);
  k_finstats<<<16, 1024, 0, stream>>>(statsP, stats_red0, GATHER_BLOCKS);
  // layer 2 (BN+ReLU of layer1 fused into GEMM staging)
  k_gemm<true><<<gb, 256, 0, stream>>>(hb, WT1, invs, stats_red0, hsb, N);
  k_gather<<<GATHER_BLOCKS, 256, 0, stream>>>(hsb, row_start, csr, invs, b1, hb, statsP, N);
  k_finstats<<<16, 1024, 0, stream>>>(statsP, stats_red1, GATHER_BLOCKS);
  // pooling + head (BN+ReLU of layer2 fused into loads)
  k_pool2<<<256, 512, 0, stream>>>(hb, stats_red1, cv, perm, pstart, poolP, N);
  k_mlp<<<64, 128, 0, stream>>>(hb, stats_red1, poolP, l1W, l1b, l2W, l2b, curr, (float*)d_out, N);
}

// Round 5
// 260.949 us; speedup vs baseline: 2.3703x; 1.1618x over previous
//
#include <hip/hip_runtime.h>
#include <math.h>

#define EPSV 1e-5f
#define PSORT_NB 256
#define SCAN_NB 256

typedef __attribute__((ext_vector_type(8))) short bf16x8;
typedef __attribute__((ext_vector_type(4))) float f32x4;

__device__ __forceinline__ uint f2b(float f) {  // fp32 -> bf16 bits (RNE)
  uint u = __builtin_bit_cast(uint, f);
  return (u + 0x7FFFu + ((u >> 16) & 1u)) >> 16;
}
__device__ __forceinline__ float blo(uint v) { return __builtin_bit_cast(float, v << 16); }
__device__ __forceinline__ float bhi(uint v) { return __builtin_bit_cast(float, v & 0xFFFF0000u); }
__device__ __forceinline__ float b2f(ushort u) { return __builtin_bit_cast(float, ((uint)u) << 16); }

// ---------------------------------------------------------------- hist (edge in-degree)
__global__ __launch_bounds__(256) void k_hist(const int* __restrict__ dst,
                                              int* __restrict__ hist, int e) {
  int i = blockIdx.x * 256 + threadIdx.x;
  if (i < e) atomicAdd(&hist[dst[i]], 1);
}

// ---------------------------------------------------------------- scan phase 1: chunk-local exclusive scan + block sums
__global__ __launch_bounds__(256) void k_scan1(const int* __restrict__ hist,
                                               int* __restrict__ row_start,
                                               float* __restrict__ invs,
                                               int* __restrict__ bsum, int n) {
  __shared__ int wtot[4];
  __shared__ int tot;
  const int b = blockIdx.x, tid = threadIdx.x, lane = tid & 63, w = tid >> 6;
  const int nb = gridDim.x;
  const int chunk = (n + nb - 1) / nb;
  const int beg = b * chunk, end = min(n, beg + chunk);
  int running = 0;
  for (int t0 = beg; t0 < end; t0 += 256) {
    int i = t0 + tid;
    int v = (i < end) ? hist[i] : 0;
    int x = v;
    #pragma unroll
    for (int off = 1; off < 64; off <<= 1) {
      int y = __shfl_up(x, off);
      if (lane >= off) x += y;
    }
    if (lane == 63) wtot[w] = x;
    __syncthreads();
    if (tid == 0) {
      int a0 = wtot[0], a1 = wtot[1], a2 = wtot[2], a3 = wtot[3];
      wtot[0] = 0; wtot[1] = a0; wtot[2] = a0 + a1; wtot[3] = a0 + a1 + a2;
      tot = a0 + a1 + a2 + a3;
    }
    __syncthreads();
    if (i < end) {
      row_start[i] = running + wtot[w] + x - v;  // chunk-local exclusive
      invs[i] = rsqrtf((float)(v + 1));
    }
    running += tot;
    __syncthreads();
  }
  if (tid == 0) bsum[b] = running;
}

// ---------------------------------------------------------------- scan phase 2: scan block sums (1 wave, 4/lane)
__global__ __launch_bounds__(64) void k_scan2(const int* __restrict__ bsum,
                                              int* __restrict__ boff,
                                              int* __restrict__ row_start, int n) {
  int lane = threadIdx.x;
  int v0 = bsum[lane * 4], v1 = bsum[lane * 4 + 1], v2 = bsum[lane * 4 + 2], v3 = bsum[lane * 4 + 3];
  int s = v0 + v1 + v2 + v3;
  int x = s;
  #pragma unroll
  for (int off = 1; off < 64; off <<= 1) {
    int y = __shfl_up(x, off);
    if (lane >= off) x += y;
  }
  int run = x - s;
  boff[lane * 4] = run; run += v0;
  boff[lane * 4 + 1] = run; run += v1;
  boff[lane * 4 + 2] = run; run += v2;
  boff[lane * 4 + 3] = run;
  if (lane == 63) row_start[n] = x;
}

// ---------------------------------------------------------------- scan phase 3: add block offsets, fill cursor
__global__ __launch_bounds__(256) void k_scan3(int* __restrict__ row_start,
                                               int* __restrict__ cursor,
                                               const int* __restrict__ boff, int n) {
  const int b = blockIdx.x, tid = threadIdx.x;
  const int nb = gridDim.x;
  const int chunk = (n + nb - 1) / nb;
  const int beg = b * chunk, end = min(n, beg + chunk);
  const int off = boff[b];
  for (int i = beg + tid; i < end; i += 256) {
    int r = row_start[i] + off;
    row_start[i] = r;
    cursor[i] = r;
  }
}

// ---------------------------------------------------------------- scatter edges into CSR
__global__ __launch_bounds__(256) void k_scatter(const int* __restrict__ src,
                                                 const int* __restrict__ dst,
                                                 int* __restrict__ cursor,
                                                 int* __restrict__ csr, int e) {
  int i = blockIdx.x * 256 + threadIdx.x;
  if (i < e) {
    int d = dst[i];
    int pos = atomicAdd(&cursor[d], 1);
    csr[pos] = src[i];
  }
}

// ---------------------------------------------------------------- partition sort: per-block hist (no global atomics)
__global__ __launch_bounds__(256) void k_phist2(const int* __restrict__ part,
                                                int* __restrict__ blockHist, int n) {
  __shared__ int lh[64];
  int b = blockIdx.x, tid = threadIdx.x;
  if (tid < 64) lh[tid] = 0;
  __syncthreads();
  int chunk = (n + PSORT_NB - 1) / PSORT_NB;
  int beg = b * chunk, end = min(n, beg + chunk);
  for (int i = beg + tid; i < end; i += 256) atomicAdd(&lh[part[i]], 1);
  __syncthreads();
  if (tid < 64) blockHist[b * 64 + tid] = lh[tid];
}

// ---------------------------------------------------------------- partition sort: base offsets (1 wave)
__global__ __launch_bounds__(64) void k_pbase(const int* __restrict__ blockHist,
                                              int* __restrict__ base,
                                              int* __restrict__ pstart) {
  int p = threadIdx.x;  // one thread per partition
  int running = 0;
  for (int b = 0; b < PSORT_NB; ++b) {
    base[b * 64 + p] = running;
    running += blockHist[b * 64 + p];
  }
  int x = running;
  #pragma unroll
  for (int off = 1; off < 64; off <<= 1) {
    int y = __shfl_up(x, off);
    if (p >= off) x += y;
  }
  int excl = x - running;
  pstart[p] = excl;
  if (p == 63) pstart[64] = x;
  for (int b = 0; b < PSORT_NB; ++b) base[b * 64 + p] += excl;
}

// ---------------------------------------------------------------- partition sort: scatter (LDS cursors only)
__global__ __launch_bounds__(256) void k_pscatter2(const int* __restrict__ part,
                                                   const int* __restrict__ base,
                                                   int* __restrict__ perm, int n) {
  __shared__ int cur[64];
  int b = blockIdx.x, tid = threadIdx.x;
  if (tid < 64) cur[tid] = base[b * 64 + tid];
  __syncthreads();
  int chunk = (n + PSORT_NB - 1) / PSORT_NB;
  int beg = b * chunk, end = min(n, beg + chunk);
  for (int i = beg + tid; i < end; i += 256) {
    int pos = atomicAdd(&cur[part[i]], 1);
    perm[pos] = i;
  }
}

// ---------------------------------------------------------------- W cast+transpose: WT[c][k] = bf16(W[k][c])
__global__ __launch_bounds__(256) void k_castW(const float* __restrict__ W0,
                                               const float* __restrict__ W1,
                                               ushort* __restrict__ WT0,
                                               ushort* __restrict__ WT1) {
  int idx = blockIdx.x * 256 + threadIdx.x;  // 32768 total
  const float* W = (idx < 16384) ? W0 : W1;
  ushort* WT = (idx < 16384) ? WT0 : WT1;
  int j = idx & 16383;
  int c = j >> 7, k = j & 127;
  WT[j] = (ushort)f2b(W[k * 128 + c]);
}

// ---------------------------------------------------------------- MFMA GEMM:
// outb[r][c] = bf16( (transform(in)[r] @ W)[c] * invs[r] )
// BN=false: in = fp32 x;  BN=true: in = bf16 h, BN+ReLU fused via stats_red
template <bool BN>
__global__ __launch_bounds__(256) void k_gemm(const void* __restrict__ inp,
                                              const ushort* __restrict__ WT,
                                              const float* __restrict__ invs,
                                              const float* __restrict__ stats_red,
                                              ushort* __restrict__ outb, int n) {
  __shared__ ushort As[16384];  // [row][k], XOR-swizzled
  __shared__ ushort Bs[16384];  // [col][k], XOR-swizzled
  __shared__ float muL[128], sclL[128];
  const int tid = threadIdx.x;
  const int l = tid & 63, w = tid >> 6;
  const int br0 = blockIdx.x * 128;

  if (BN) {
    if (tid < 128) {
      float s = stats_red[tid], q = stats_red[128 + tid];
      float m = s * (1.0f / 50000.0f);
      muL[tid] = m;
      sclL[tid] = rsqrtf(q * (1.0f / 50000.0f) - m * m + EPSV);
    }
    __syncthreads();
  }

  // stage B (already bf16, [c][k] contiguous)
  #pragma unroll
  for (int i = 0; i < 8; ++i) {
    int flat = i * 2048 + tid * 8;
    int c = flat >> 7;
    uint4 v = *(const uint4*)&WT[flat];
    *(uint4*)&Bs[flat ^ ((c & 7) << 3)] = v;
  }
  // stage A
  #pragma unroll
  for (int i = 0; i < 8; ++i) {
    int flat = i * 2048 + tid * 8;
    int row = flat >> 7, k0 = flat & 127;
    int grow = br0 + row;
    uint4 u;
    if (grow < n) {
      if (BN) {
        const ushort* inb = (const ushort*)inp;
        uint4 raw = *(const uint4*)&inb[(size_t)grow * 128 + k0];
        float f[8] = {blo(raw.x), bhi(raw.x), blo(raw.y), bhi(raw.y),
                      blo(raw.z), bhi(raw.z), blo(raw.w), bhi(raw.w)};
        #pragma unroll
        for (int j = 0; j < 8; ++j) {
          float v = (f[j] - muL[k0 + j]) * sclL[k0 + j];
          f[j] = v > 0.f ? v : 0.f;
        }
        u.x = f2b(f[0]) | (f2b(f[1]) << 16);
        u.y = f2b(f[2]) | (f2b(f[3]) << 16);
        u.z = f2b(f[4]) | (f2b(f[5]) << 16);
        u.w = f2b(f[6]) | (f2b(f[7]) << 16);
      } else {
        const float* inf = (const float*)inp;
        float4 v0 = *(const float4*)&inf[(size_t)grow * 128 + k0];
        float4 v1 = *(const float4*)&inf[(size_t)grow * 128 + k0 + 4];
        u.x = f2b(v0.x) | (f2b(v0.y) << 16);
        u.y = f2b(v0.z) | (f2b(v0.w) << 16);
        u.z = f2b(v1.x) | (f2b(v1.y) << 16);
        u.w = f2b(v1.z) | (f2b(v1.w) << 16);
      }
    } else {
      u.x = u.y = u.z = u.w = 0u;
    }
    *(uint4*)&As[flat ^ ((row & 7) << 3)] = u;
  }
  __syncthreads();

  const int wr = w >> 1, wc = w & 1;
  const int lr = l & 15, lk = (l >> 4) * 8;
  f32x4 acc[4][4];
  #pragma unroll
  for (int m = 0; m < 4; ++m)
    #pragma unroll
    for (int nn = 0; nn < 4; ++nn) acc[m][nn] = (f32x4){0.f, 0.f, 0.f, 0.f};

  #pragma unroll
  for (int ks = 0; ks < 4; ++ks) {
    bf16x8 af[4], bfr[4];
    #pragma unroll
    for (int m = 0; m < 4; ++m) {
      int row = wr * 64 + m * 16 + lr;
      af[m] = *(const bf16x8*)&As[(row * 128 + ks * 32 + lk) ^ ((row & 7) << 3)];
    }
    #pragma unroll
    for (int nn = 0; nn < 4; ++nn) {
      int c = wc * 64 + nn * 16 + lr;
      bfr[nn] = *(const bf16x8*)&Bs[(c * 128 + ks * 32 + lk) ^ ((c & 7) << 3)];
    }
    #pragma unroll
    for (int m = 0; m < 4; ++m)
      #pragma unroll
      for (int nn = 0; nn < 4; ++nn)
        acc[m][nn] = __builtin_amdgcn_mfma_f32_16x16x32_bf16(af[m], bfr[nn], acc[m][nn], 0, 0, 0);
  }

  #pragma unroll
  for (int m = 0; m < 4; ++m) {
    #pragma unroll
    for (int r = 0; r < 4; ++r) {
      int row = br0 + wr * 64 + m * 16 + (l >> 4) * 4 + r;
      if (row >= n) continue;
      float iv = invs[row];
      #pragma unroll
      for (int nn = 0; nn < 4; ++nn) {
        int col = wc * 64 + nn * 16 + lr;
        outb[(size_t)row * 128 + col] = (ushort)f2b(acc[m][nn][r] * iv);
      }
    }
  }
}

// ---------------------------------------------------------------- gather: h[d]=bf16(invs[d]*(hs[d]+sum hs[src])+b); fp32 stats
__global__ __launch_bounds__(256) void k_gather(const ushort* __restrict__ hsb,
                                                const int* __restrict__ row_start,
                                                const int* __restrict__ csr,
                                                const float* __restrict__ invs,
                                                const float* __restrict__ bias,
                                                ushort* __restrict__ outb,
                                                float* __restrict__ statsP, int n) {
  const int tid = threadIdx.x;
  const int lane = tid & 63, w = tid >> 6;
  const int c0 = lane * 2;
  float s0 = 0.f, s1 = 0.f, q0 = 0.f, q1 = 0.f;
  const float bv0 = bias[c0], bv1 = bias[c0 + 1];
  const int stride = gridDim.x * 4;
  for (int node = blockIdx.x * 4 + w; node < n; node += stride) {
    uint vs = *(const uint*)&hsb[(size_t)node * 128 + c0];  // self loop
    float accx = blo(vs), accy = bhi(vs);
    int beg = row_start[node], end = row_start[node + 1];
    int e = beg;
    for (; e + 3 < end; e += 4) {
      int sA = csr[e], sB = csr[e + 1], sC = csr[e + 2], sD = csr[e + 3];
      uint vA = *(const uint*)&hsb[(size_t)sA * 128 + c0];
      uint vB = *(const uint*)&hsb[(size_t)sB * 128 + c0];
      uint vC = *(const uint*)&hsb[(size_t)sC * 128 + c0];
      uint vD = *(const uint*)&hsb[(size_t)sD * 128 + c0];
      accx += (blo(vA) + blo(vB)) + (blo(vC) + blo(vD));
      accy += (bhi(vA) + bhi(vB)) + (bhi(vC) + bhi(vD));
    }
    for (; e < end; ++e) {
      uint vA = *(const uint*)&hsb[(size_t)csr[e] * 128 + c0];
      accx += blo(vA);
      accy += bhi(vA);
    }
    float iv = invs[node];
    float o0 = accx * iv + bv0, o1 = accy * iv + bv1;
    *(uint*)&outb[(size_t)node * 128 + c0] = f2b(o0) | (f2b(o1) << 16);
    s0 += o0; s1 += o1; q0 += o0 * o0; q1 += o1 * o1;
  }
  __shared__ float redS[4][128], redQ[4][128];
  redS[w][c0] = s0; redS[w][c0 + 1] = s1;
  redQ[w][c0] = q0; redQ[w][c0 + 1] = q1;
  __syncthreads();
  if (tid < 128) {
    float s = redS[0][tid] + redS[1][tid] + redS[2][tid] + redS[3][tid];
    statsP[blockIdx.x * 256 + tid] = s;
  } else {
    int t = tid - 128;
    float q = redQ[0][t] + redQ[1][t] + redQ[2][t] + redQ[3][t];
    statsP[blockIdx.x * 256 + tid] = q;
  }
}

// ---------------------------------------------------------------- reduce stats partials -> stats_red[256]
__global__ __launch_bounds__(1024) void k_finstats(const float* __restrict__ statsP,
                                                   float* __restrict__ stats_red,
                                                   int nb) {
  int t = threadIdx.x;
  int c = blockIdx.x * 16 + (t & 15);
  int b0 = t >> 4;
  int per = nb >> 6;
  float s = 0.f;
  for (int j = 0; j < per; ++j) s += statsP[(b0 * per + j) * 256 + c];
  __shared__ float red[1024];
  red[t] = s;
  __syncthreads();
  for (int st = 512; st >= 16; st >>= 1) {
    if (t < st) red[t] += red[t + st];
    __syncthreads();
  }
  if (t < 16) stats_red[blockIdx.x * 16 + t] = red[t];
}

// ---------------------------------------------------------------- pool over partition-sorted rows (no atomics)
__global__ __launch_bounds__(512) void k_pool2(const ushort* __restrict__ hb,
                                               const float* __restrict__ stats_red,
                                               const float* __restrict__ cv,
                                               const int* __restrict__ perm,
                                               const int* __restrict__ pstart,
                                               float* __restrict__ poolP, int n) {
  const int tid = threadIdx.x;
  const int lane = tid & 63, w = tid >> 6;
  const int p = blockIdx.x >> 2, s = blockIdx.x & 3;
  const int g = s * 8 + w;
  const int c0 = lane * 2;

  float s0 = stats_red[c0], s1 = stats_red[c0 + 1];
  float qq0 = stats_red[128 + c0], qq1 = stats_red[128 + c0 + 1];
  float mu0 = s0 * (1.0f / 50000.0f), mu1 = s1 * (1.0f / 50000.0f);
  float scl0 = rsqrtf(qq0 * (1.0f / 50000.0f) - mu0 * mu0 + EPSV);
  float scl1 = rsqrtf(qq1 * (1.0f / 50000.0f) - mu1 * mu1 + EPSV);

  const int beg = pstart[p], end = pstart[p + 1];
  float cc0 = 0.f, cc1 = 0.f, cn0 = 0.f, cn1 = 0.f;

  int j = beg + g;
  for (; j + 32 < end; j += 64) {
    int rA = perm[j], rB = perm[j + 32];
    uint vA = *(const uint*)&hb[(size_t)rA * 128 + c0];
    uint vB = *(const uint*)&hb[(size_t)rB * 128 + c0];
    float cvA = cv[rA], cvB = cv[rB];
    float xA0 = (blo(vA) - mu0) * scl0; xA0 = xA0 > 0.f ? xA0 : 0.f;
    float xA1 = (bhi(vA) - mu1) * scl1; xA1 = xA1 > 0.f ? xA1 : 0.f;
    float xB0 = (blo(vB) - mu0) * scl0; xB0 = xB0 > 0.f ? xB0 : 0.f;
    float xB1 = (bhi(vB) - mu1) * scl1; xB1 = xB1 > 0.f ? xB1 : 0.f;
    cc0 += xA0 * cvA + xB0 * cvB;
    cc1 += xA1 * cvA + xB1 * cvB;
    cn0 += xA0 * (1.f - cvA) + xB0 * (1.f - cvB);
    cn1 += xA1 * (1.f - cvA) + xB1 * (1.f - cvB);
  }
  if (j < end) {
    int rA = perm[j];
    uint vA = *(const uint*)&hb[(size_t)rA * 128 + c0];
    float cvA = cv[rA];
    float xA0 = (blo(vA) - mu0) * scl0; xA0 = xA0 > 0.f ? xA0 : 0.f;
    float xA1 = (bhi(vA) - mu1) * scl1; xA1 = xA1 > 0.f ? xA1 : 0.f;
    cc0 += xA0 * cvA;
    cc1 += xA1 * cvA;
    cn0 += xA0 * (1.f - cvA);
    cn1 += xA1 * (1.f - cvA);
  }

  __shared__ float redC[8][128], redN[8][128];
  redC[w][c0] = cc0; redC[w][c0 + 1] = cc1;
  redN[w][c0] = cn0; redN[w][c0 + 1] = cn1;
  __syncthreads();
  if (tid < 128) {
    float a = 0.f;
    #pragma unroll
    for (int ww = 0; ww < 8; ++ww) a += redC[ww][tid];
    poolP[blockIdx.x * 256 + tid] = a;
  } else if (tid < 256) {
    int t = tid - 128;
    float a = 0.f;
    #pragma unroll
    for (int ww = 0; ww < 8; ++ww) a += redN[ww][t];
    poolP[blockIdx.x * 256 + tid] = a;
  }
}

// ---------------------------------------------------------------- final MLP: one block per partition
__global__ __launch_bounds__(128) void k_mlp(const ushort* __restrict__ hb,
                                             const float* __restrict__ stats_red,
                                             const float* __restrict__ poolP,
                                             const float* __restrict__ l1W,
                                             const float* __restrict__ l1b,
                                             const float* __restrict__ l2W,
                                             const float* __restrict__ l2b,
                                             const int* __restrict__ curr_ptr,
                                             float* __restrict__ out, int n) {
  const int p = blockIdx.x;
  const int t = threadIdx.x;
  __shared__ float z[384];
  int curr = *curr_ptr;
  float s = stats_red[t], q = stats_red[128 + t];
  float mu = s / (float)n;
  float scl = rsqrtf(q / (float)n - mu * mu + EPSV);
  float v = b2f(hb[(size_t)curr * 128 + t]);
  v = (v - mu) * scl;
  z[t] = v > 0.f ? v : 0.f;
  float ccore = 0.f, cnon = 0.f;
  #pragma unroll
  for (int sb = 0; sb < 4; ++sb) {
    ccore += poolP[(p * 4 + sb) * 256 + t];
    cnon  += poolP[(p * 4 + sb) * 256 + 128 + t];
  }
  z[128 + t] = ccore;
  z[256 + t] = cnon;
  __syncthreads();
  float a = l1b[t];
  for (int k = 0; k < 384; ++k) a += z[k] * l1W[k * 128 + t];
  a = a > 0.f ? a : 0.f;
  float pr = a * l2W[t];
  #pragma unroll
  for (int off = 32; off; off >>= 1) pr += __shfl_down(pr, off);
  __shared__ float rr[2];
  if ((t & 63) == 0) rr[t >> 6] = pr;
  __syncthreads();
  if (t == 0) out[p] = rr[0] + rr[1] + l2b[0];
}

// ================================================================ host
extern "C" void kernel_launch(void* const* d_in, const int* in_sizes, int n_in,
                              void* d_out, int out_size, void* d_ws, size_t ws_size,
                              hipStream_t stream) {
  const float* x    = (const float*)d_in[0];
  const float* cv   = (const float*)d_in[1];
  const float* W0   = (const float*)d_in[2];
  const float* b0   = (const float*)d_in[3];
  const float* W1   = (const float*)d_in[4];
  const float* b1   = (const float*)d_in[5];
  const float* l1W  = (const float*)d_in[6];
  const float* l1b  = (const float*)d_in[7];
  const float* l2W  = (const float*)d_in[8];
  const float* l2b  = (const float*)d_in[9];
  const int*   ei   = (const int*)d_in[10];
  const int*   part = (const int*)d_in[11];
  const int*   curr = (const int*)d_in[12];

  const int N = in_sizes[1];          // 50000
  const int E = in_sizes[10] / 2;     // 640000
  const int* src = ei;
  const int* dst = ei + E;

  const int GATHER_BLOCKS = 2048;

  char* w = (char*)d_ws;
  size_t off = 0;
  auto alloc = [&](size_t bytes) -> void* {
    void* p = (void*)(w + off);
    off = (off + bytes + 255) & ~(size_t)255;
    return p;
  };
  int*   hist      = (int*)alloc((size_t)N * 4);
  int*   cursor    = (int*)alloc((size_t)N * 4);
  int*   row_start = (int*)alloc((size_t)(N + 1) * 4);
  int*   csr       = (int*)alloc((size_t)E * 4);
  float* invs      = (float*)alloc((size_t)N * 4);
  int*   bsum      = (int*)alloc((size_t)SCAN_NB * 4);
  int*   boff      = (int*)alloc((size_t)SCAN_NB * 4);
  int*   blockHist = (int*)alloc((size_t)PSORT_NB * 64 * 4);
  int*   pbase     = (int*)alloc((size_t)PSORT_NB * 64 * 4);
  int*   pstart    = (int*)alloc(65 * 4);
  int*   perm      = (int*)alloc((size_t)N * 4);
  float* stats_red0 = (float*)alloc(256 * 4);
  float* stats_red1 = (float*)alloc(256 * 4);
  float* statsP    = (float*)alloc((size_t)GATHER_BLOCKS * 256 * 4);
  float* poolP     = (float*)alloc((size_t)256 * 256 * 4);
  ushort* WT0      = (ushort*)alloc((size_t)16384 * 2);
  ushort* WT1      = (ushort*)alloc((size_t)16384 * 2);
  ushort* hsb      = (ushort*)alloc((size_t)N * 128 * 2);
  ushort* hb       = (ushort*)alloc((size_t)N * 128 * 2);
  (void)ws_size;

  hipMemsetAsync(hist, 0, (size_t)N * 4, stream);

  int eb = (E + 255) / 256;
  // CSR build (edges) — multi-block scan
  k_hist<<<eb, 256, 0, stream>>>(dst, hist, E);
  k_scan1<<<SCAN_NB, 256, 0, stream>>>(hist, row_start, invs, bsum, N);
  k_scan2<<<1, 64, 0, stream>>>(bsum, boff, row_start, N);
  k_scan3<<<SCAN_NB, 256, 0, stream>>>(row_start, cursor, boff, N);
  k_scatter<<<eb, 256, 0, stream>>>(src, dst, cursor, csr, E);
  // partition counting sort (nodes) — no global atomics
  k_phist2<<<PSORT_NB, 256, 0, stream>>>(part, blockHist, N);
  k_pbase<<<1, 64, 0, stream>>>(blockHist, pbase, pstart);
  k_pscatter2<<<PSORT_NB, 256, 0, stream>>>(part, pbase, perm, N);
  // weights -> bf16 transposed
  k_castW<<<128, 256, 0, stream>>>(W0, W1, WT0, WT1);

  int gb = (N + 127) / 128;
  // layer 1
  k_gemm<false><<<gb, 256, 0, stream>>>(x, WT0, invs, nullptr, hsb, N);
  k_gather<<<GATHER_BLOCKS, 256, 0, stream>>>(hsb, row_start, csr, invs, b0, hb, statsP, N);
  k_finstats<<<16, 1024, 0, stream>>>(statsP, stats_red0, GATHER_BLOCKS);
  // layer 2 (BN+ReLU of layer1 fused into GEMM staging)
  k_gemm<true><<<gb, 256, 0, stream>>>(hb, WT1, invs, stats_red0, hsb, N);
  k_gather<<<GATHER_BLOCKS, 256, 0, stream>>>(hsb, row_start, csr, invs, b1, hb, statsP, N);
  k_finstats<<<16, 1024, 0, stream>>>(statsP, stats_red1, GATHER_BLOCKS);
  // pooling + head (BN+ReLU of layer2 fused into loads)
  k_pool2<<<256, 512, 0, stream>>>(hb, stats_red1, cv, perm, pstart, poolP, N);
  k_mlp<<<64, 128, 0, stream>>>(hb, stats_red1, poolP, l1W, l1b, l2W, l2b, curr, (float*)d_out, N);
}

// Round 6
// 227.670 us; speedup vs baseline: 2.7168x; 1.1462x over previous
//
#include <hip/hip_runtime.h>
#include <math.h>

#define EPSV 1e-5f
#define PSORT_NB 256
#define SCAN_NB 256

typedef __attribute__((ext_vector_type(8))) short bf16x8;
typedef __attribute__((ext_vector_type(4))) float f32x4;

__device__ __forceinline__ uint f2b(float f) {  // fp32 -> bf16 bits (RNE)
  uint u = __builtin_bit_cast(uint, f);
  return (u + 0x7FFFu + ((u >> 16) & 1u)) >> 16;
}
__device__ __forceinline__ float blo(uint v) { return __builtin_bit_cast(float, v << 16); }
__device__ __forceinline__ float bhi(uint v) { return __builtin_bit_cast(float, v & 0xFFFF0000u); }
__device__ __forceinline__ float b2f(ushort u) { return __builtin_bit_cast(float, ((uint)u) << 16); }

// ---------------------------------------------------------------- zero hist (replaces rocclr fillBuffer)
__global__ __launch_bounds__(256) void k_zero(int* __restrict__ p, int n) {
  int i = blockIdx.x * 256 + threadIdx.x;
  if (i < n) p[i] = 0;
}

// ---------------------------------------------------------------- hist (edge in-degree)
__global__ __launch_bounds__(256) void k_hist(const int* __restrict__ dst,
                                              int* __restrict__ hist, int e) {
  int i = blockIdx.x * 256 + threadIdx.x;
  if (i < e) atomicAdd(&hist[dst[i]], 1);
}

// ---------------------------------------------------------------- scan phase 1: chunk-local exclusive scan + block sums
__global__ __launch_bounds__(256) void k_scan1(const int* __restrict__ hist,
                                               int* __restrict__ row_start,
                                               float* __restrict__ invs,
                                               int* __restrict__ bsum, int n) {
  __shared__ int wtot[4];
  __shared__ int tot;
  const int b = blockIdx.x, tid = threadIdx.x, lane = tid & 63, w = tid >> 6;
  const int nb = gridDim.x;
  const int chunk = (n + nb - 1) / nb;
  const int beg = b * chunk, end = min(n, beg + chunk);
  int running = 0;
  for (int t0 = beg; t0 < end; t0 += 256) {
    int i = t0 + tid;
    int v = (i < end) ? hist[i] : 0;
    int x = v;
    #pragma unroll
    for (int off = 1; off < 64; off <<= 1) {
      int y = __shfl_up(x, off);
      if (lane >= off) x += y;
    }
    if (lane == 63) wtot[w] = x;
    __syncthreads();
    if (tid == 0) {
      int a0 = wtot[0], a1 = wtot[1], a2 = wtot[2], a3 = wtot[3];
      wtot[0] = 0; wtot[1] = a0; wtot[2] = a0 + a1; wtot[3] = a0 + a1 + a2;
      tot = a0 + a1 + a2 + a3;
    }
    __syncthreads();
    if (i < end) {
      row_start[i] = running + wtot[w] + x - v;  // chunk-local exclusive
      invs[i] = rsqrtf((float)(v + 1));
    }
    running += tot;
    __syncthreads();
  }
  if (tid == 0) bsum[b] = running;
}

// ---------------------------------------------------------------- scan phase 2: scan block sums (1 wave, 4/lane)
__global__ __launch_bounds__(64) void k_scan2(const int* __restrict__ bsum,
                                              int* __restrict__ boff,
                                              int* __restrict__ row_start, int n) {
  int lane = threadIdx.x;
  int v0 = bsum[lane * 4], v1 = bsum[lane * 4 + 1], v2 = bsum[lane * 4 + 2], v3 = bsum[lane * 4 + 3];
  int s = v0 + v1 + v2 + v3;
  int x = s;
  #pragma unroll
  for (int off = 1; off < 64; off <<= 1) {
    int y = __shfl_up(x, off);
    if (lane >= off) x += y;
  }
  int run = x - s;
  boff[lane * 4] = run; run += v0;
  boff[lane * 4 + 1] = run; run += v1;
  boff[lane * 4 + 2] = run; run += v2;
  boff[lane * 4 + 3] = run;
  if (lane == 63) row_start[n] = x;
}

// ---------------------------------------------------------------- scan phase 3: add block offsets, fill cursor
__global__ __launch_bounds__(256) void k_scan3(int* __restrict__ row_start,
                                               int* __restrict__ cursor,
                                               const int* __restrict__ boff, int n) {
  const int b = blockIdx.x, tid = threadIdx.x;
  const int nb = gridDim.x;
  const int chunk = (n + nb - 1) / nb;
  const int beg = b * chunk, end = min(n, beg + chunk);
  const int off = boff[b];
  for (int i = beg + tid; i < end; i += 256) {
    int r = row_start[i] + off;
    row_start[i] = r;
    cursor[i] = r;
  }
}

// ---------------------------------------------------------------- scatter edges into CSR
__global__ __launch_bounds__(256) void k_scatter(const int* __restrict__ src,
                                                 const int* __restrict__ dst,
                                                 int* __restrict__ cursor,
                                                 int* __restrict__ csr, int e) {
  int i = blockIdx.x * 256 + threadIdx.x;
  if (i < e) {
    int d = dst[i];
    int pos = atomicAdd(&cursor[d], 1);
    csr[pos] = src[i];
  }
}

// ---------------------------------------------------------------- partition sort: per-block hist (no global atomics)
__global__ __launch_bounds__(256) void k_phist2(const int* __restrict__ part,
                                                int* __restrict__ blockHist, int n) {
  __shared__ int lh[64];
  int b = blockIdx.x, tid = threadIdx.x;
  if (tid < 64) lh[tid] = 0;
  __syncthreads();
  int chunk = (n + PSORT_NB - 1) / PSORT_NB;
  int beg = b * chunk, end = min(n, beg + chunk);
  for (int i = beg + tid; i < end; i += 256) atomicAdd(&lh[part[i]], 1);
  __syncthreads();
  if (tid < 64) blockHist[b * 64 + tid] = lh[tid];
}

// ---------------------------------------------------------------- partition sort: per-partition block scan (64 blocks)
// base[b][p] = exclusive sum over blocks b' < b of blockHist[b'][p]; ptot[p] = total
__global__ __launch_bounds__(256) void k_pbaseA(const int* __restrict__ blockHist,
                                                int* __restrict__ base,
                                                int* __restrict__ ptot) {
  __shared__ int wtot[4];
  const int p = blockIdx.x, tid = threadIdx.x, lane = tid & 63, w = tid >> 6;
  int v = blockHist[tid * 64 + p];
  int x = v;
  #pragma unroll
  for (int off = 1; off < 64; off <<= 1) {
    int y = __shfl_up(x, off);
    if (lane >= off) x += y;
  }
  if (lane == 63) wtot[w] = x;
  __syncthreads();
  int woff = 0;
  if (w > 0) woff = wtot[0];
  if (w > 1) woff += wtot[1];
  if (w > 2) woff += wtot[2];
  base[tid * 64 + p] = woff + x - v;  // exclusive
  if (tid == 255) ptot[p] = woff + x;
}

// ---------------------------------------------------------------- partition sort: scan partition totals (1 wave)
__global__ __launch_bounds__(64) void k_pbaseB(const int* __restrict__ ptot,
                                               int* __restrict__ pexcl,
                                               int* __restrict__ pstart) {
  int lane = threadIdx.x;
  int v = ptot[lane];
  int x = v;
  #pragma unroll
  for (int off = 1; off < 64; off <<= 1) {
    int y = __shfl_up(x, off);
    if (lane >= off) x += y;
  }
  int excl = x - v;
  pexcl[lane] = excl;
  pstart[lane] = excl;
  if (lane == 63) pstart[64] = x;
}

// ---------------------------------------------------------------- partition sort: scatter (LDS cursors only)
__global__ __launch_bounds__(256) void k_pscatter2(const int* __restrict__ part,
                                                   const int* __restrict__ base,
                                                   const int* __restrict__ pexcl,
                                                   int* __restrict__ perm, int n) {
  __shared__ int cur[64];
  int b = blockIdx.x, tid = threadIdx.x;
  if (tid < 64) cur[tid] = base[b * 64 + tid] + pexcl[tid];
  __syncthreads();
  int chunk = (n + PSORT_NB - 1) / PSORT_NB;
  int beg = b * chunk, end = min(n, beg + chunk);
  for (int i = beg + tid; i < end; i += 256) {
    int pos = atomicAdd(&cur[part[i]], 1);
    perm[pos] = i;
  }
}

// ---------------------------------------------------------------- W cast+transpose: WT[c][k] = bf16(W[k][c])
__global__ __launch_bounds__(256) void k_castW(const float* __restrict__ W0,
                                               const float* __restrict__ W1,
                                               ushort* __restrict__ WT0,
                                               ushort* __restrict__ WT1) {
  int idx = blockIdx.x * 256 + threadIdx.x;  // 32768 total
  const float* W = (idx < 16384) ? W0 : W1;
  ushort* WT = (idx < 16384) ? WT0 : WT1;
  int j = idx & 16383;
  int c = j >> 7, k = j & 127;
  WT[j] = (ushort)f2b(W[k * 128 + c]);
}

// ---------------------------------------------------------------- MFMA GEMM:
// outb[r][c] = bf16( (transform(in)[r] @ W)[c] * invs[r] )
// BN=false: in = fp32 x;  BN=true: in = bf16 h, BN+ReLU fused via stats_red
template <bool BN>
__global__ __launch_bounds__(256) void k_gemm(const void* __restrict__ inp,
                                              const ushort* __restrict__ WT,
                                              const float* __restrict__ invs,
                                              const float* __restrict__ stats_red,
                                              ushort* __restrict__ outb, int n) {
  __shared__ ushort As[16384];  // [row][k], XOR-swizzled
  __shared__ ushort Bs[16384];  // [col][k], XOR-swizzled
  __shared__ float muL[128], sclL[128];
  const int tid = threadIdx.x;
  const int l = tid & 63, w = tid >> 6;
  const int br0 = blockIdx.x * 128;

  if (BN) {
    if (tid < 128) {
      float s = stats_red[tid], q = stats_red[128 + tid];
      float m = s * (1.0f / 50000.0f);
      muL[tid] = m;
      sclL[tid] = rsqrtf(q * (1.0f / 50000.0f) - m * m + EPSV);
    }
    __syncthreads();
  }

  // stage B (already bf16, [c][k] contiguous)
  #pragma unroll
  for (int i = 0; i < 8; ++i) {
    int flat = i * 2048 + tid * 8;
    int c = flat >> 7;
    uint4 v = *(const uint4*)&WT[flat];
    *(uint4*)&Bs[flat ^ ((c & 7) << 3)] = v;
  }
  // stage A
  #pragma unroll
  for (int i = 0; i < 8; ++i) {
    int flat = i * 2048 + tid * 8;
    int row = flat >> 7, k0 = flat & 127;
    int grow = br0 + row;
    uint4 u;
    if (grow < n) {
      if (BN) {
        const ushort* inb = (const ushort*)inp;
        uint4 raw = *(const uint4*)&inb[(size_t)grow * 128 + k0];
        float f[8] = {blo(raw.x), bhi(raw.x), blo(raw.y), bhi(raw.y),
                      blo(raw.z), bhi(raw.z), blo(raw.w), bhi(raw.w)};
        #pragma unroll
        for (int j = 0; j < 8; ++j) {
          float v = (f[j] - muL[k0 + j]) * sclL[k0 + j];
          f[j] = v > 0.f ? v : 0.f;
        }
        u.x = f2b(f[0]) | (f2b(f[1]) << 16);
        u.y = f2b(f[2]) | (f2b(f[3]) << 16);
        u.z = f2b(f[4]) | (f2b(f[5]) << 16);
        u.w = f2b(f[6]) | (f2b(f[7]) << 16);
      } else {
        const float* inf = (const float*)inp;
        float4 v0 = *(const float4*)&inf[(size_t)grow * 128 + k0];
        float4 v1 = *(const float4*)&inf[(size_t)grow * 128 + k0 + 4];
        u.x = f2b(v0.x) | (f2b(v0.y) << 16);
        u.y = f2b(v0.z) | (f2b(v0.w) << 16);
        u.z = f2b(v1.x) | (f2b(v1.y) << 16);
        u.w = f2b(v1.z) | (f2b(v1.w) << 16);
      }
    } else {
      u.x = u.y = u.z = u.w = 0u;
    }
    *(uint4*)&As[flat ^ ((row & 7) << 3)] = u;
  }
  __syncthreads();

  const int wr = w >> 1, wc = w & 1;
  const int lr = l & 15, lk = (l >> 4) * 8;
  f32x4 acc[4][4];
  #pragma unroll
  for (int m = 0; m < 4; ++m)
    #pragma unroll
    for (int nn = 0; nn < 4; ++nn) acc[m][nn] = (f32x4){0.f, 0.f, 0.f, 0.f};

  #pragma unroll
  for (int ks = 0; ks < 4; ++ks) {
    bf16x8 af[4], bfr[4];
    #pragma unroll
    for (int m = 0; m < 4; ++m) {
      int row = wr * 64 + m * 16 + lr;
      af[m] = *(const bf16x8*)&As[(row * 128 + ks * 32 + lk) ^ ((row & 7) << 3)];
    }
    #pragma unroll
    for (int nn = 0; nn < 4; ++nn) {
      int c = wc * 64 + nn * 16 + lr;
      bfr[nn] = *(const bf16x8*)&Bs[(c * 128 + ks * 32 + lk) ^ ((c & 7) << 3)];
    }
    #pragma unroll
    for (int m = 0; m < 4; ++m)
      #pragma unroll
      for (int nn = 0; nn < 4; ++nn)
        acc[m][nn] = __builtin_amdgcn_mfma_f32_16x16x32_bf16(af[m], bfr[nn], acc[m][nn], 0, 0, 0);
  }

  #pragma unroll
  for (int m = 0; m < 4; ++m) {
    #pragma unroll
    for (int r = 0; r < 4; ++r) {
      int row = br0 + wr * 64 + m * 16 + (l >> 4) * 4 + r;
      if (row >= n) continue;
      float iv = invs[row];
      #pragma unroll
      for (int nn = 0; nn < 4; ++nn) {
        int col = wc * 64 + nn * 16 + lr;
        outb[(size_t)row * 128 + col] = (ushort)f2b(acc[m][nn][r] * iv);
      }
    }
  }
}

// ---------------------------------------------------------------- gather: h[d]=bf16(invs[d]*(hs[d]+sum hs[src])+b); fp32 stats
__global__ __launch_bounds__(256) void k_gather(const ushort* __restrict__ hsb,
                                                const int* __restrict__ row_start,
                                                const int* __restrict__ csr,
                                                const float* __restrict__ invs,
                                                const float* __restrict__ bias,
                                                ushort* __restrict__ outb,
                                                float* __restrict__ statsP, int n) {
  const int tid = threadIdx.x;
  const int lane = tid & 63, w = tid >> 6;
  const int c0 = lane * 2;
  float s0 = 0.f, s1 = 0.f, q0 = 0.f, q1 = 0.f;
  const float bv0 = bias[c0], bv1 = bias[c0 + 1];
  const int stride = gridDim.x * 4;
  for (int node = blockIdx.x * 4 + w; node < n; node += stride) {
    uint vs = *(const uint*)&hsb[(size_t)node * 128 + c0];  // self loop
    float accx = blo(vs), accy = bhi(vs);
    int beg = row_start[node], end = row_start[node + 1];
    int e = beg;
    for (; e + 3 < end; e += 4) {
      int sA = csr[e], sB = csr[e + 1], sC = csr[e + 2], sD = csr[e + 3];
      uint vA = *(const uint*)&hsb[(size_t)sA * 128 + c0];
      uint vB = *(const uint*)&hsb[(size_t)sB * 128 + c0];
      uint vC = *(const uint*)&hsb[(size_t)sC * 128 + c0];
      uint vD = *(const uint*)&hsb[(size_t)sD * 128 + c0];
      accx += (blo(vA) + blo(vB)) + (blo(vC) + blo(vD));
      accy += (bhi(vA) + bhi(vB)) + (bhi(vC) + bhi(vD));
    }
    for (; e < end; ++e) {
      uint vA = *(const uint*)&hsb[(size_t)csr[e] * 128 + c0];
      accx += blo(vA);
      accy += bhi(vA);
    }
    float iv = invs[node];
    float o0 = accx * iv + bv0, o1 = accy * iv + bv1;
    *(uint*)&outb[(size_t)node * 128 + c0] = f2b(o0) | (f2b(o1) << 16);
    s0 += o0; s1 += o1; q0 += o0 * o0; q1 += o1 * o1;
  }
  __shared__ float redS[4][128], redQ[4][128];
  redS[w][c0] = s0; redS[w][c0 + 1] = s1;
  redQ[w][c0] = q0; redQ[w][c0 + 1] = q1;
  __syncthreads();
  if (tid < 128) {
    float s = redS[0][tid] + redS[1][tid] + redS[2][tid] + redS[3][tid];
    statsP[blockIdx.x * 256 + tid] = s;
  } else {
    int t = tid - 128;
    float q = redQ[0][t] + redQ[1][t] + redQ[2][t] + redQ[3][t];
    statsP[blockIdx.x * 256 + tid] = q;
  }
}

// ---------------------------------------------------------------- reduce stats partials -> stats_red[256]
__global__ __launch_bounds__(1024) void k_finstats(const float* __restrict__ statsP,
                                                   float* __restrict__ stats_red,
                                                   int nb) {
  int t = threadIdx.x;
  int c = blockIdx.x * 16 + (t & 15);
  int b0 = t >> 4;
  int per = nb >> 6;
  float s = 0.f;
  for (int j = 0; j < per; ++j) s += statsP[(b0 * per + j) * 256 + c];
  __shared__ float red[1024];
  red[t] = s;
  __syncthreads();
  for (int st = 512; st >= 16; st >>= 1) {
    if (t < st) red[t] += red[t + st];
    __syncthreads();
  }
  if (t < 16) stats_red[blockIdx.x * 16 + t] = red[t];
}

// ---------------------------------------------------------------- pool over partition-sorted rows (no atomics)
__global__ __launch_bounds__(512) void k_pool2(const ushort* __restrict__ hb,
                                               const float* __restrict__ stats_red,
                                               const float* __restrict__ cv,
                                               const int* __restrict__ perm,
                                               const int* __restrict__ pstart,
                                               float* __restrict__ poolP, int n) {
  const int tid = threadIdx.x;
  const int lane = tid & 63, w = tid >> 6;
  const int p = blockIdx.x >> 2, s = blockIdx.x & 3;
  const int g = s * 8 + w;
  const int c0 = lane * 2;

  float s0 = stats_red[c0], s1 = stats_red[c0 + 1];
  float qq0 = stats_red[128 + c0], qq1 = stats_red[128 + c0 + 1];
  float mu0 = s0 * (1.0f / 50000.0f), mu1 = s1 * (1.0f / 50000.0f);
  float scl0 = rsqrtf(qq0 * (1.0f / 50000.0f) - mu0 * mu0 + EPSV);
  float scl1 = rsqrtf(qq1 * (1.0f / 50000.0f) - mu1 * mu1 + EPSV);

  const int beg = pstart[p], end = pstart[p + 1];
  float cc0 = 0.f, cc1 = 0.f, cn0 = 0.f, cn1 = 0.f;

  int j = beg + g;
  for (; j + 32 < end; j += 64) {
    int rA = perm[j], rB = perm[j + 32];
    uint vA = *(const uint*)&hb[(size_t)rA * 128 + c0];
    uint vB = *(const uint*)&hb[(size_t)rB * 128 + c0];
    float cvA = cv[rA], cvB = cv[rB];
    float xA0 = (blo(vA) - mu0) * scl0; xA0 = xA0 > 0.f ? xA0 : 0.f;
    float xA1 = (bhi(vA) - mu1) * scl1; xA1 = xA1 > 0.f ? xA1 : 0.f;
    float xB0 = (blo(vB) - mu0) * scl0; xB0 = xB0 > 0.f ? xB0 : 0.f;
    float xB1 = (bhi(vB) - mu1) * scl1; xB1 = xB1 > 0.f ? xB1 : 0.f;
    cc0 += xA0 * cvA + xB0 * cvB;
    cc1 += xA1 * cvA + xB1 * cvB;
    cn0 += xA0 * (1.f - cvA) + xB0 * (1.f - cvB);
    cn1 += xA1 * (1.f - cvA) + xB1 * (1.f - cvB);
  }
  if (j < end) {
    int rA = perm[j];
    uint vA = *(const uint*)&hb[(size_t)rA * 128 + c0];
    float cvA = cv[rA];
    float xA0 = (blo(vA) - mu0) * scl0; xA0 = xA0 > 0.f ? xA0 : 0.f;
    float xA1 = (bhi(vA) - mu1) * scl1; xA1 = xA1 > 0.f ? xA1 : 0.f;
    cc0 += xA0 * cvA;
    cc1 += xA1 * cvA;
    cn0 += xA0 * (1.f - cvA);
    cn1 += xA1 * (1.f - cvA);
  }

  __shared__ float redC[8][128], redN[8][128];
  redC[w][c0] = cc0; redC[w][c0 + 1] = cc1;
  redN[w][c0] = cn0; redN[w][c0 + 1] = cn1;
  __syncthreads();
  if (tid < 128) {
    float a = 0.f;
    #pragma unroll
    for (int ww = 0; ww < 8; ++ww) a += redC[ww][tid];
    poolP[blockIdx.x * 256 + tid] = a;
  } else if (tid < 256) {
    int t = tid - 128;
    float a = 0.f;
    #pragma unroll
    for (int ww = 0; ww < 8; ++ww) a += redN[ww][t];
    poolP[blockIdx.x * 256 + tid] = a;
  }
}

// ---------------------------------------------------------------- final MLP: one block per partition
__global__ __launch_bounds__(128) void k_mlp(const ushort* __restrict__ hb,
                                             const float* __restrict__ stats_red,
                                             const float* __restrict__ poolP,
                                             const float* __restrict__ l1W,
                                             const float* __restrict__ l1b,
                                             const float* __restrict__ l2W,
                                             const float* __restrict__ l2b,
                                             const int* __restrict__ curr_ptr,
                                             float* __restrict__ out, int n) {
  const int p = blockIdx.x;
  const int t = threadIdx.x;
  __shared__ float z[384];
  int curr = *curr_ptr;
  float s = stats_red[t], q = stats_red[128 + t];
  float mu = s / (float)n;
  float scl = rsqrtf(q / (float)n - mu * mu + EPSV);
  float v = b2f(hb[(size_t)curr * 128 + t]);
  v = (v - mu) * scl;
  z[t] = v > 0.f ? v : 0.f;
  float ccore = 0.f, cnon = 0.f;
  #pragma unroll
  for (int sb = 0; sb < 4; ++sb) {
    ccore += poolP[(p * 4 + sb) * 256 + t];
    cnon  += poolP[(p * 4 + sb) * 256 + 128 + t];
  }
  z[128 + t] = ccore;
  z[256 + t] = cnon;
  __syncthreads();
  float a = l1b[t];
  for (int k = 0; k < 384; ++k) a += z[k] * l1W[k * 128 + t];
  a = a > 0.f ? a : 0.f;
  float pr = a * l2W[t];
  #pragma unroll
  for (int off = 32; off; off >>= 1) pr += __shfl_down(pr, off);
  __shared__ float rr[2];
  if ((t & 63) == 0) rr[t >> 6] = pr;
  __syncthreads();
  if (t == 0) out[p] = rr[0] + rr[1] + l2b[0];
}

// ================================================================ host
extern "C" void kernel_launch(void* const* d_in, const int* in_sizes, int n_in,
                              void* d_out, int out_size, void* d_ws, size_t ws_size,
                              hipStream_t stream) {
  const float* x    = (const float*)d_in[0];
  const float* cv   = (const float*)d_in[1];
  const float* W0   = (const float*)d_in[2];
  const float* b0   = (const float*)d_in[3];
  const float* W1   = (const float*)d_in[4];
  const float* b1   = (const float*)d_in[5];
  const float* l1W  = (const float*)d_in[6];
  const float* l1b  = (const float*)d_in[7];
  const float* l2W  = (const float*)d_in[8];
  const float* l2b  = (const float*)d_in[9];
  const int*   ei   = (const int*)d_in[10];
  const int*   part = (const int*)d_in[11];
  const int*   curr = (const int*)d_in[12];

  const int N = in_sizes[1];          // 50000
  const int E = in_sizes[10] / 2;     // 640000
  const int* src = ei;
  const int* dst = ei + E;

  const int GATHER_BLOCKS = 2048;

  char* w = (char*)d_ws;
  size_t off = 0;
  auto alloc = [&](size_t bytes) -> void* {
    void* p = (void*)(w + off);
    off = (off + bytes + 255) & ~(size_t)255;
    return p;
  };
  int*   hist      = (int*)alloc((size_t)N * 4);
  int*   cursor    = (int*)alloc((size_t)N * 4);
  int*   row_start = (int*)alloc((size_t)(N + 1) * 4);
  int*   csr       = (int*)alloc((size_t)E * 4);
  float* invs      = (float*)alloc((size_t)N * 4);
  int*   bsum      = (int*)alloc((size_t)SCAN_NB * 4);
  int*   boff      = (int*)alloc((size_t)SCAN_NB * 4);
  int*   blockHist = (int*)alloc((size_t)PSORT_NB * 64 * 4);
  int*   pbase     = (int*)alloc((size_t)PSORT_NB * 64 * 4);
  int*   ptot      = (int*)alloc(64 * 4);
  int*   pexcl     = (int*)alloc(64 * 4);
  int*   pstart    = (int*)alloc(65 * 4);
  int*   perm      = (int*)alloc((size_t)N * 4);
  float* stats_red0 = (float*)alloc(256 * 4);
  float* stats_red1 = (float*)alloc(256 * 4);
  float* statsP    = (float*)alloc((size_t)GATHER_BLOCKS * 256 * 4);
  float* poolP     = (float*)alloc((size_t)256 * 256 * 4);
  ushort* WT0      = (ushort*)alloc((size_t)16384 * 2);
  ushort* WT1      = (ushort*)alloc((size_t)16384 * 2);
  ushort* hsb      = (ushort*)alloc((size_t)N * 128 * 2);
  ushort* hb       = (ushort*)alloc((size_t)N * 128 * 2);
  (void)ws_size;

  int eb = (E + 255) / 256;
  int nb = (N + 255) / 256;
  // CSR build (edges) — multi-block scan
  k_zero<<<nb, 256, 0, stream>>>(hist, N);
  k_hist<<<eb, 256, 0, stream>>>(dst, hist, E);
  k_scan1<<<SCAN_NB, 256, 0, stream>>>(hist, row_start, invs, bsum, N);
  k_scan2<<<1, 64, 0, stream>>>(bsum, boff, row_start, N);
  k_scan3<<<SCAN_NB, 256, 0, stream>>>(row_start, cursor, boff, N);
  k_scatter<<<eb, 256, 0, stream>>>(src, dst, cursor, csr, E);
  // partition counting sort (nodes) — no global atomics, parallel base scan
  k_phist2<<<PSORT_NB, 256, 0, stream>>>(part, blockHist, N);
  k_pbaseA<<<64, 256, 0, stream>>>(blockHist, pbase, ptot);
  k_pbaseB<<<1, 64, 0, stream>>>(ptot, pexcl, pstart);
  k_pscatter2<<<PSORT_NB, 256, 0, stream>>>(part, pbase, pexcl, perm, N);
  // weights -> bf16 transposed
  k_castW<<<128, 256, 0, stream>>>(W0, W1, WT0, WT1);

  int gb = (N + 127) / 128;
  // layer 1
  k_gemm<false><<<gb, 256, 0, stream>>>(x, WT0, invs, nullptr, hsb, N);
  k_gather<<<GATHER_BLOCKS, 256, 0, stream>>>(hsb, row_start, csr, invs, b0, hb, statsP, N);
  k_finstats<<<16, 1024, 0, stream>>>(statsP, stats_red0, GATHER_BLOCKS);
  // layer 2 (BN+ReLU of layer1 fused into GEMM staging)
  k_gemm<true><<<gb, 256, 0, stream>>>(hb, WT1, invs, stats_red0, hsb, N);
  k_gather<<<GATHER_BLOCKS, 256, 0, stream>>>(hsb, row_start, csr, invs, b1, hb, statsP, N);
  k_finstats<<<16, 1024, 0, stream>>>(statsP, stats_red1, GATHER_BLOCKS);
  // pooling + head (BN+ReLU of layer2 fused into loads)
  k_pool2<<<256, 512, 0, stream>>>(hb, stats_red1, cv, perm, pstart, poolP, N);
  k_mlp<<<64, 128, 0, stream>>>(hb, stats_red1, poolP, l1W, l1b, l2W, l2b, curr, (float*)d_out, N);
}

// Round 7
// 189.654 us; speedup vs baseline: 3.2614x; 1.2005x over previous
//
#include <hip/hip_runtime.h>
#include <math.h>

#define EPSV 1e-5f
#define PSORT_NB 256
#define SCAN_NB 256

typedef __attribute__((ext_vector_type(8))) short bf16x8;
typedef __attribute__((ext_vector_type(4))) float f32x4;

__device__ __forceinline__ uint f2b(float f) {  // fp32 -> bf16 bits (RNE)
  uint u = __builtin_bit_cast(uint, f);
  return (u + 0x7FFFu + ((u >> 16) & 1u)) >> 16;
}
__device__ __forceinline__ float blo(uint v) { return __builtin_bit_cast(float, v << 16); }
__device__ __forceinline__ float bhi(uint v) { return __builtin_bit_cast(float, v & 0xFFFF0000u); }
__device__ __forceinline__ float b2f(ushort u) { return __builtin_bit_cast(float, ((uint)u) << 16); }

// ================================================================ PRE1: zero hist || partition per-block hist || castW
__global__ __launch_bounds__(256) void k_pre1(int* __restrict__ hist, int nbZero,
                                              const int* __restrict__ part,
                                              int* __restrict__ blockHist,
                                              const float* __restrict__ W0,
                                              const float* __restrict__ W1,
                                              ushort* __restrict__ WT0,
                                              ushort* __restrict__ WT1, int n) {
  const int b = blockIdx.x, tid = threadIdx.x;
  if (b < nbZero) {
    int i = b * 256 + tid;
    if (i < n) hist[i] = 0;
  } else if (b < nbZero + PSORT_NB) {
    __shared__ int lh[64];
    int pb = b - nbZero;
    if (tid < 64) lh[tid] = 0;
    __syncthreads();
    int chunk = (n + PSORT_NB - 1) / PSORT_NB;
    int beg = pb * chunk, end = min(n, beg + chunk);
    for (int i = beg + tid; i < end; i += 256) atomicAdd(&lh[part[i]], 1);
    __syncthreads();
    if (tid < 64) blockHist[pb * 64 + tid] = lh[tid];
  } else {
    int idx = (b - nbZero - PSORT_NB) * 256 + tid;  // 0..32767
    const float* W = (idx < 16384) ? W0 : W1;
    ushort* WT = (idx < 16384) ? WT0 : WT1;
    int j = idx & 16383;
    int c = j >> 7, k = j & 127;
    WT[j] = (ushort)f2b(W[k * 128 + c]);
  }
}

// ================================================================ PRE2: edge hist + rank || partition base scan
__global__ __launch_bounds__(256) void k_pre2(const int* __restrict__ dst,
                                              int* __restrict__ hist,
                                              int* __restrict__ rank, int e, int eb,
                                              const int* __restrict__ blockHist,
                                              int* __restrict__ base,
                                              int* __restrict__ ptot) {
  const int b = blockIdx.x, tid = threadIdx.x;
  if (b < eb) {
    int i = b * 256 + tid;
    if (i < e) rank[i] = atomicAdd(&hist[dst[i]], 1);
  } else {
    __shared__ int wtot[4];
    const int p = b - eb;  // 0..63
    const int lane = tid & 63, w = tid >> 6;
    int v = blockHist[tid * 64 + p];
    int x = v;
    #pragma unroll
    for (int off = 1; off < 64; off <<= 1) {
      int y = __shfl_up(x, off);
      if (lane >= off) x += y;
    }
    if (lane == 63) wtot[w] = x;
    __syncthreads();
    int woff = 0;
    if (w > 0) woff = wtot[0];
    if (w > 1) woff += wtot[1];
    if (w > 2) woff += wtot[2];
    base[tid * 64 + p] = woff + x - v;  // exclusive over blocks
    if (tid == 255) ptot[p] = woff + x;
  }
}

// ================================================================ PRE3: scan1 (deg->local excl scan + invs) || partition total scan
__global__ __launch_bounds__(256) void k_pre3(const int* __restrict__ hist,
                                              int* __restrict__ row_start,
                                              float* __restrict__ invs,
                                              int* __restrict__ bsum, int n,
                                              const int* __restrict__ ptot,
                                              int* __restrict__ pexcl,
                                              int* __restrict__ pstart) {
  const int b = blockIdx.x, tid = threadIdx.x;
  if (b < SCAN_NB) {
    __shared__ int wtot[4];
    __shared__ int tot;
    const int lane = tid & 63, w = tid >> 6;
    const int chunk = (n + SCAN_NB - 1) / SCAN_NB;
    const int beg = b * chunk, end = min(n, beg + chunk);
    int running = 0;
    for (int t0 = beg; t0 < end; t0 += 256) {
      int i = t0 + tid;
      int v = (i < end) ? hist[i] : 0;
      int x = v;
      #pragma unroll
      for (int off = 1; off < 64; off <<= 1) {
        int y = __shfl_up(x, off);
        if (lane >= off) x += y;
      }
      if (lane == 63) wtot[w] = x;
      __syncthreads();
      if (tid == 0) {
        int a0 = wtot[0], a1 = wtot[1], a2 = wtot[2], a3 = wtot[3];
        wtot[0] = 0; wtot[1] = a0; wtot[2] = a0 + a1; wtot[3] = a0 + a1 + a2;
        tot = a0 + a1 + a2 + a3;
      }
      __syncthreads();
      if (i < end) {
        row_start[i] = running + wtot[w] + x - v;
        invs[i] = rsqrtf((float)(v + 1));
      }
      running += tot;
      __syncthreads();
    }
    if (tid == 0) bsum[b] = running;
  } else if (tid < 64) {
    int v = ptot[tid];
    int x = v;
    #pragma unroll
    for (int off = 1; off < 64; off <<= 1) {
      int y = __shfl_up(x, off);
      if (tid >= off) x += y;
    }
    int excl = x - v;
    pexcl[tid] = excl;
    pstart[tid] = excl;
    if (tid == 63) pstart[64] = x;
  }
}

// ================================================================ PRE4: scan2 (block sums) || partition scatter
__global__ __launch_bounds__(256) void k_pre4(const int* __restrict__ bsum,
                                              int* __restrict__ boff,
                                              int* __restrict__ row_start, int n,
                                              const int* __restrict__ part,
                                              const int* __restrict__ base,
                                              const int* __restrict__ pexcl,
                                              int* __restrict__ perm) {
  const int b = blockIdx.x, tid = threadIdx.x;
  if (b == 0) {
    if (tid < 64) {
      int v0 = bsum[tid * 4], v1 = bsum[tid * 4 + 1], v2 = bsum[tid * 4 + 2], v3 = bsum[tid * 4 + 3];
      int s = v0 + v1 + v2 + v3;
      int x = s;
      #pragma unroll
      for (int off = 1; off < 64; off <<= 1) {
        int y = __shfl_up(x, off);
        if (tid >= off) x += y;
      }
      int run = x - s;
      boff[tid * 4] = run; run += v0;
      boff[tid * 4 + 1] = run; run += v1;
      boff[tid * 4 + 2] = run; run += v2;
      boff[tid * 4 + 3] = run;
      if (tid == 63) row_start[n] = x;
    }
  } else {
    __shared__ int cur[64];
    const int pb = b - 1;
    if (tid < 64) cur[tid] = base[pb * 64 + tid] + pexcl[tid];
    __syncthreads();
    int chunk = (n + PSORT_NB - 1) / PSORT_NB;
    int beg = pb * chunk, end = min(n, beg + chunk);
    for (int i = beg + tid; i < end; i += 256) {
      int pos = atomicAdd(&cur[part[i]], 1);
      perm[pos] = i;
    }
  }
}

// ================================================================ scan3: add block offsets, keep row_start final
__global__ __launch_bounds__(256) void k_scan3(int* __restrict__ row_start,
                                               const int* __restrict__ boff, int n) {
  const int b = blockIdx.x, tid = threadIdx.x;
  const int chunk = (n + SCAN_NB - 1) / SCAN_NB;
  const int beg = b * chunk, end = min(n, beg + chunk);
  const int off = boff[b];
  for (int i = beg + tid; i < end; i += 256) row_start[i] += off;
}

// ================================================================ scatter edges into CSR — atomic-free via rank
__global__ __launch_bounds__(256) void k_scatter(const int* __restrict__ src,
                                                 const int* __restrict__ dst,
                                                 const int* __restrict__ rank,
                                                 const int* __restrict__ row_start,
                                                 int* __restrict__ csr, int e) {
  int i = blockIdx.x * 256 + threadIdx.x;
  if (i < e) csr[row_start[dst[i]] + rank[i]] = src[i];
}

// ================================================================ MFMA GEMM
template <bool BN>
__global__ __launch_bounds__(256) void k_gemm(const void* __restrict__ inp,
                                              const ushort* __restrict__ WT,
                                              const float* __restrict__ invs,
                                              const float* __restrict__ stats_red,
                                              ushort* __restrict__ outb, int n) {
  __shared__ ushort As[16384];  // [row][k], XOR-swizzled
  __shared__ ushort Bs[16384];  // [col][k], XOR-swizzled
  __shared__ float muL[128], sclL[128];
  const int tid = threadIdx.x;
  const int l = tid & 63, w = tid >> 6;
  const int br0 = blockIdx.x * 128;

  if (BN) {
    if (tid < 128) {
      float s = stats_red[tid], q = stats_red[128 + tid];
      float m = s * (1.0f / 50000.0f);
      muL[tid] = m;
      sclL[tid] = rsqrtf(q * (1.0f / 50000.0f) - m * m + EPSV);
    }
    __syncthreads();
  }

  #pragma unroll
  for (int i = 0; i < 8; ++i) {
    int flat = i * 2048 + tid * 8;
    int c = flat >> 7;
    uint4 v = *(const uint4*)&WT[flat];
    *(uint4*)&Bs[flat ^ ((c & 7) << 3)] = v;
  }
  #pragma unroll
  for (int i = 0; i < 8; ++i) {
    int flat = i * 2048 + tid * 8;
    int row = flat >> 7, k0 = flat & 127;
    int grow = br0 + row;
    uint4 u;
    if (grow < n) {
      if (BN) {
        const ushort* inb = (const ushort*)inp;
        uint4 raw = *(const uint4*)&inb[(size_t)grow * 128 + k0];
        float f[8] = {blo(raw.x), bhi(raw.x), blo(raw.y), bhi(raw.y),
                      blo(raw.z), bhi(raw.z), blo(raw.w), bhi(raw.w)};
        #pragma unroll
        for (int j = 0; j < 8; ++j) {
          float v = (f[j] - muL[k0 + j]) * sclL[k0 + j];
          f[j] = v > 0.f ? v : 0.f;
        }
        u.x = f2b(f[0]) | (f2b(f[1]) << 16);
        u.y = f2b(f[2]) | (f2b(f[3]) << 16);
        u.z = f2b(f[4]) | (f2b(f[5]) << 16);
        u.w = f2b(f[6]) | (f2b(f[7]) << 16);
      } else {
        const float* inf = (const float*)inp;
        float4 v0 = *(const float4*)&inf[(size_t)grow * 128 + k0];
        float4 v1 = *(const float4*)&inf[(size_t)grow * 128 + k0 + 4];
        u.x = f2b(v0.x) | (f2b(v0.y) << 16);
        u.y = f2b(v0.z) | (f2b(v0.w) << 16);
        u.z = f2b(v1.x) | (f2b(v1.y) << 16);
        u.w = f2b(v1.z) | (f2b(v1.w) << 16);
      }
    } else {
      u.x = u.y = u.z = u.w = 0u;
    }
    *(uint4*)&As[flat ^ ((row & 7) << 3)] = u;
  }
  __syncthreads();

  const int wr = w >> 1, wc = w & 1;
  const int lr = l & 15, lk = (l >> 4) * 8;
  f32x4 acc[4][4];
  #pragma unroll
  for (int m = 0; m < 4; ++m)
    #pragma unroll
    for (int nn = 0; nn < 4; ++nn) acc[m][nn] = (f32x4){0.f, 0.f, 0.f, 0.f};

  #pragma unroll
  for (int ks = 0; ks < 4; ++ks) {
    bf16x8 af[4], bfr[4];
    #pragma unroll
    for (int m = 0; m < 4; ++m) {
      int row = wr * 64 + m * 16 + lr;
      af[m] = *(const bf16x8*)&As[(row * 128 + ks * 32 + lk) ^ ((row & 7) << 3)];
    }
    #pragma unroll
    for (int nn = 0; nn < 4; ++nn) {
      int c = wc * 64 + nn * 16 + lr;
      bfr[nn] = *(const bf16x8*)&Bs[(c * 128 + ks * 32 + lk) ^ ((c & 7) << 3)];
    }
    #pragma unroll
    for (int m = 0; m < 4; ++m)
      #pragma unroll
      for (int nn = 0; nn < 4; ++nn)
        acc[m][nn] = __builtin_amdgcn_mfma_f32_16x16x32_bf16(af[m], bfr[nn], acc[m][nn], 0, 0, 0);
  }

  #pragma unroll
  for (int m = 0; m < 4; ++m) {
    #pragma unroll
    for (int r = 0; r < 4; ++r) {
      int row = br0 + wr * 64 + m * 16 + (l >> 4) * 4 + r;
      if (row >= n) continue;
      float iv = invs[row];
      #pragma unroll
      for (int nn = 0; nn < 4; ++nn) {
        int col = wc * 64 + nn * 16 + lr;
        outb[(size_t)row * 128 + col] = (ushort)f2b(acc[m][nn][r] * iv);
      }
    }
  }
}

// ================================================================ gather: unroll 8/4/1
__global__ __launch_bounds__(256) void k_gather(const ushort* __restrict__ hsb,
                                                const int* __restrict__ row_start,
                                                const int* __restrict__ csr,
                                                const float* __restrict__ invs,
                                                const float* __restrict__ bias,
                                                ushort* __restrict__ outb,
                                                float* __restrict__ statsP, int n) {
  const int tid = threadIdx.x;
  const int lane = tid & 63, w = tid >> 6;
  const int c0 = lane * 2;
  const ushort* hc = hsb + c0;
  float s0 = 0.f, s1 = 0.f, q0 = 0.f, q1 = 0.f;
  const float bv0 = bias[c0], bv1 = bias[c0 + 1];
  const int stride = gridDim.x * 4;
  for (int node = blockIdx.x * 4 + w; node < n; node += stride) {
    uint vs = *(const uint*)&hc[(size_t)node * 128];  // self loop
    float accx = blo(vs), accy = bhi(vs);
    int beg = row_start[node], end = row_start[node + 1];
    int e = beg;
    for (; e + 7 < end; e += 8) {
      int sA = csr[e], sB = csr[e + 1], sC = csr[e + 2], sD = csr[e + 3];
      int sE = csr[e + 4], sF = csr[e + 5], sG = csr[e + 6], sH = csr[e + 7];
      uint vA = *(const uint*)&hc[(size_t)sA * 128];
      uint vB = *(const uint*)&hc[(size_t)sB * 128];
      uint vC = *(const uint*)&hc[(size_t)sC * 128];
      uint vD = *(const uint*)&hc[(size_t)sD * 128];
      uint vE = *(const uint*)&hc[(size_t)sE * 128];
      uint vF = *(const uint*)&hc[(size_t)sF * 128];
      uint vG = *(const uint*)&hc[(size_t)sG * 128];
      uint vH = *(const uint*)&hc[(size_t)sH * 128];
      accx += ((blo(vA) + blo(vB)) + (blo(vC) + blo(vD))) +
              ((blo(vE) + blo(vF)) + (blo(vG) + blo(vH)));
      accy += ((bhi(vA) + bhi(vB)) + (bhi(vC) + bhi(vD))) +
              ((bhi(vE) + bhi(vF)) + (bhi(vG) + bhi(vH)));
    }
    for (; e + 3 < end; e += 4) {
      int sA = csr[e], sB = csr[e + 1], sC = csr[e + 2], sD = csr[e + 3];
      uint vA = *(const uint*)&hc[(size_t)sA * 128];
      uint vB = *(const uint*)&hc[(size_t)sB * 128];
      uint vC = *(const uint*)&hc[(size_t)sC * 128];
      uint vD = *(const uint*)&hc[(size_t)sD * 128];
      accx += (blo(vA) + blo(vB)) + (blo(vC) + blo(vD));
      accy += (bhi(vA) + bhi(vB)) + (bhi(vC) + bhi(vD));
    }
    for (; e < end; ++e) {
      uint vA = *(const uint*)&hc[(size_t)csr[e] * 128];
      accx += blo(vA);
      accy += bhi(vA);
    }
    float iv = invs[node];
    float o0 = accx * iv + bv0, o1 = accy * iv + bv1;
    *(uint*)&outb[(size_t)node * 128 + c0] = f2b(o0) | (f2b(o1) << 16);
    s0 += o0; s1 += o1; q0 += o0 * o0; q1 += o1 * o1;
  }
  __shared__ float redS[4][128], redQ[4][128];
  redS[w][c0] = s0; redS[w][c0 + 1] = s1;
  redQ[w][c0] = q0; redQ[w][c0 + 1] = q1;
  __syncthreads();
  if (tid < 128) {
    float s = redS[0][tid] + redS[1][tid] + redS[2][tid] + redS[3][tid];
    statsP[blockIdx.x * 256 + tid] = s;
  } else {
    int t = tid - 128;
    float q = redQ[0][t] + redQ[1][t] + redQ[2][t] + redQ[3][t];
    statsP[blockIdx.x * 256 + tid] = q;
  }
}

// ================================================================ reduce stats partials -> stats_red[256]
__global__ __launch_bounds__(1024) void k_finstats(const float* __restrict__ statsP,
                                                   float* __restrict__ stats_red,
                                                   int nb) {
  int t = threadIdx.x;
  int c = blockIdx.x * 16 + (t & 15);
  int b0 = t >> 4;
  int per = nb >> 6;
  float s = 0.f;
  for (int j = 0; j < per; ++j) s += statsP[(b0 * per + j) * 256 + c];
  __shared__ float red[1024];
  red[t] = s;
  __syncthreads();
  for (int st = 512; st >= 16; st >>= 1) {
    if (t < st) red[t] += red[t + st];
    __syncthreads();
  }
  if (t < 16) stats_red[blockIdx.x * 16 + t] = red[t];
}

// ================================================================ pool over partition-sorted rows
__global__ __launch_bounds__(512) void k_pool2(const ushort* __restrict__ hb,
                                               const float* __restrict__ stats_red,
                                               const float* __restrict__ cv,
                                               const int* __restrict__ perm,
                                               const int* __restrict__ pstart,
                                               float* __restrict__ poolP, int n) {
  const int tid = threadIdx.x;
  const int lane = tid & 63, w = tid >> 6;
  const int p = blockIdx.x >> 2, s = blockIdx.x & 3;
  const int g = s * 8 + w;
  const int c0 = lane * 2;

  float s0 = stats_red[c0], s1 = stats_red[c0 + 1];
  float qq0 = stats_red[128 + c0], qq1 = stats_red[128 + c0 + 1];
  float mu0 = s0 * (1.0f / 50000.0f), mu1 = s1 * (1.0f / 50000.0f);
  float scl0 = rsqrtf(qq0 * (1.0f / 50000.0f) - mu0 * mu0 + EPSV);
  float scl1 = rsqrtf(qq1 * (1.0f / 50000.0f) - mu1 * mu1 + EPSV);

  const int beg = pstart[p], end = pstart[p + 1];
  float cc0 = 0.f, cc1 = 0.f, cn0 = 0.f, cn1 = 0.f;

  int j = beg + g;
  for (; j + 32 < end; j += 64) {
    int rA = perm[j], rB = perm[j + 32];
    uint vA = *(const uint*)&hb[(size_t)rA * 128 + c0];
    uint vB = *(const uint*)&hb[(size_t)rB * 128 + c0];
    float cvA = cv[rA], cvB = cv[rB];
    float xA0 = (blo(vA) - mu0) * scl0; xA0 = xA0 > 0.f ? xA0 : 0.f;
    float xA1 = (bhi(vA) - mu1) * scl1; xA1 = xA1 > 0.f ? xA1 : 0.f;
    float xB0 = (blo(vB) - mu0) * scl0; xB0 = xB0 > 0.f ? xB0 : 0.f;
    float xB1 = (bhi(vB) - mu1) * scl1; xB1 = xB1 > 0.f ? xB1 : 0.f;
    cc0 += xA0 * cvA + xB0 * cvB;
    cc1 += xA1 * cvA + xB1 * cvB;
    cn0 += xA0 * (1.f - cvA) + xB0 * (1.f - cvB);
    cn1 += xA1 * (1.f - cvA) + xB1 * (1.f - cvB);
  }
  if (j < end) {
    int rA = perm[j];
    uint vA = *(const uint*)&hb[(size_t)rA * 128 + c0];
    float cvA = cv[rA];
    float xA0 = (blo(vA) - mu0) * scl0; xA0 = xA0 > 0.f ? xA0 : 0.f;
    float xA1 = (bhi(vA) - mu1) * scl1; xA1 = xA1 > 0.f ? xA1 : 0.f;
    cc0 += xA0 * cvA;
    cc1 += xA1 * cvA;
    cn0 += xA0 * (1.f - cvA);
    cn1 += xA1 * (1.f - cvA);
  }

  __shared__ float redC[8][128], redN[8][128];
  redC[w][c0] = cc0; redC[w][c0 + 1] = cc1;
  redN[w][c0] = cn0; redN[w][c0 + 1] = cn1;
  __syncthreads();
  if (tid < 128) {
    float a = 0.f;
    #pragma unroll
    for (int ww = 0; ww < 8; ++ww) a += redC[ww][tid];
    poolP[blockIdx.x * 256 + tid] = a;
  } else if (tid < 256) {
    int t = tid - 128;
    float a = 0.f;
    #pragma unroll
    for (int ww = 0; ww < 8; ++ww) a += redN[ww][t];
    poolP[blockIdx.x * 256 + tid] = a;
  }
}

// ================================================================ final MLP: one block per partition
__global__ __launch_bounds__(128) void k_mlp(const ushort* __restrict__ hb,
                                             const float* __restrict__ stats_red,
                                             const float* __restrict__ poolP,
                                             const float* __restrict__ l1W,
                                             const float* __restrict__ l1b,
                                             const float* __restrict__ l2W,
                                             const float* __restrict__ l2b,
                                             const int* __restrict__ curr_ptr,
                                             float* __restrict__ out, int n) {
  const int p = blockIdx.x;
  const int t = threadIdx.x;
  __shared__ float z[384];
  int curr = *curr_ptr;
  float s = stats_red[t], q = stats_red[128 + t];
  float mu = s / (float)n;
  float scl = rsqrtf(q / (float)n - mu * mu + EPSV);
  float v = b2f(hb[(size_t)curr * 128 + t]);
  v = (v - mu) * scl;
  z[t] = v > 0.f ? v : 0.f;
  float ccore = 0.f, cnon = 0.f;
  #pragma unroll
  for (int sb = 0; sb < 4; ++sb) {
    ccore += poolP[(p * 4 + sb) * 256 + t];
    cnon  += poolP[(p * 4 + sb) * 256 + 128 + t];
  }
  z[128 + t] = ccore;
  z[256 + t] = cnon;
  __syncthreads();
  float a = l1b[t];
  for (int k = 0; k < 384; ++k) a += z[k] * l1W[k * 128 + t];
  a = a > 0.f ? a : 0.f;
  float pr = a * l2W[t];
  #pragma unroll
  for (int off = 32; off; off >>= 1) pr += __shfl_down(pr, off);
  __shared__ float rr[2];
  if ((t & 63) == 0) rr[t >> 6] = pr;
  __syncthreads();
  if (t == 0) out[p] = rr[0] + rr[1] + l2b[0];
}

// ================================================================ host
extern "C" void kernel_launch(void* const* d_in, const int* in_sizes, int n_in,
                              void* d_out, int out_size, void* d_ws, size_t ws_size,
                              hipStream_t stream) {
  const float* x    = (const float*)d_in[0];
  const float* cv   = (const float*)d_in[1];
  const float* W0   = (const float*)d_in[2];
  const float* b0   = (const float*)d_in[3];
  const float* W1   = (const float*)d_in[4];
  const float* b1   = (const float*)d_in[5];
  const float* l1W  = (const float*)d_in[6];
  const float* l1b  = (const float*)d_in[7];
  const float* l2W  = (const float*)d_in[8];
  const float* l2b  = (const float*)d_in[9];
  const int*   ei   = (const int*)d_in[10];
  const int*   part = (const int*)d_in[11];
  const int*   curr = (const int*)d_in[12];

  const int N = in_sizes[1];          // 50000
  const int E = in_sizes[10] / 2;     // 640000
  const int* src = ei;
  const int* dst = ei + E;

  const int GATHER_BLOCKS = 2048;

  char* w = (char*)d_ws;
  size_t off = 0;
  auto alloc = [&](size_t bytes) -> void* {
    void* p = (void*)(w + off);
    off = (off + bytes + 255) & ~(size_t)255;
    return p;
  };
  int*   hist      = (int*)alloc((size_t)N * 4);
  int*   row_start = (int*)alloc((size_t)(N + 1) * 4);
  int*   csr       = (int*)alloc((size_t)E * 4);
  int*   rank      = (int*)alloc((size_t)E * 4);
  float* invs      = (float*)alloc((size_t)N * 4);
  int*   bsum      = (int*)alloc((size_t)SCAN_NB * 4);
  int*   boff      = (int*)alloc((size_t)SCAN_NB * 4);
  int*   blockHist = (int*)alloc((size_t)PSORT_NB * 64 * 4);
  int*   pbase     = (int*)alloc((size_t)PSORT_NB * 64 * 4);
  int*   ptot      = (int*)alloc(64 * 4);
  int*   pexcl     = (int*)alloc(64 * 4);
  int*   pstart    = (int*)alloc(65 * 4);
  int*   perm      = (int*)alloc((size_t)N * 4);
  float* stats_red0 = (float*)alloc(256 * 4);
  float* stats_red1 = (float*)alloc(256 * 4);
  float* statsP    = (float*)alloc((size_t)GATHER_BLOCKS * 256 * 4);
  float* poolP     = (float*)alloc((size_t)256 * 256 * 4);
  ushort* WT0      = (ushort*)alloc((size_t)16384 * 2);
  ushort* WT1      = (ushort*)alloc((size_t)16384 * 2);
  ushort* hsb      = (ushort*)alloc((size_t)N * 128 * 2);
  ushort* hb       = (ushort*)alloc((size_t)N * 128 * 2);
  (void)ws_size;

  const int eb = (E + 255) / 256;
  const int nbZero = (N + 255) / 256;

  // PRE1: zero(hist) || partition per-block hist || castW
  k_pre1<<<nbZero + PSORT_NB + 128, 256, 0, stream>>>(hist, nbZero, part, blockHist,
                                                      W0, W1, WT0, WT1, N);
  // PRE2: edge hist + rank || partition base scan
  k_pre2<<<eb + 64, 256, 0, stream>>>(dst, hist, rank, E, eb, blockHist, pbase, ptot);
  // PRE3: degree scan phase 1 + invs || partition total scan
  k_pre3<<<SCAN_NB + 1, 256, 0, stream>>>(hist, row_start, invs, bsum, N, ptot, pexcl, pstart);
  // PRE4: degree scan phase 2 || partition scatter
  k_pre4<<<1 + PSORT_NB, 256, 0, stream>>>(bsum, boff, row_start, N, part, pbase, pexcl, perm);
  // scan phase 3 (finalize row_start)
  k_scan3<<<SCAN_NB, 256, 0, stream>>>(row_start, boff, N);
  // CSR scatter — atomic-free
  k_scatter<<<eb, 256, 0, stream>>>(src, dst, rank, row_start, csr, E);

  int gb = (N + 127) / 128;
  // layer 1
  k_gemm<false><<<gb, 256, 0, stream>>>(x, WT0, invs, nullptr, hsb, N);
  k_gather<<<GATHER_BLOCKS, 256, 0, stream>>>(hsb, row_start, csr, invs, b0, hb, statsP, N);
  k_finstats<<<16, 1024, 0, stream>>>(statsP, stats_red0, GATHER_BLOCKS);
  // layer 2
  k_gemm<true><<<gb, 256, 0, stream>>>(hb, WT1, invs, stats_red0, hsb, N);
  k_gather<<<GATHER_BLOCKS, 256, 0, stream>>>(hsb, row_start, csr, invs, b1, hb, statsP, N);
  k_finstats<<<16, 1024, 0, stream>>>(statsP, stats_red1, GATHER_BLOCKS);
  // pooling + head
  k_pool2<<<256, 512, 0, stream>>>(hb, stats_red1, cv, perm, pstart, poolP, N);
  k_mlp<<<64, 128, 0, stream>>>(hb, stats_red1, poolP, l1W, l1b, l2W, l2b, curr, (float*)d_out, N);
}

// Round 8
// 176.505 us; speedup vs baseline: 3.5044x; 1.0745x over previous
//
#include <hip/hip_runtime.h>
#include <math.h>

#define EPSV 1e-5f
#define PSORT_NB 256
#define SCAN_NB 256

typedef __attribute__((ext_vector_type(8))) short bf16x8;
typedef __attribute__((ext_vector_type(4))) float f32x4;

__device__ __forceinline__ uint f2b(float f) {  // fp32 -> bf16 bits (RNE)
  uint u = __builtin_bit_cast(uint, f);
  return (u + 0x7FFFu + ((u >> 16) & 1u)) >> 16;
}
__device__ __forceinline__ float blo(uint v) { return __builtin_bit_cast(float, v << 16); }
__device__ __forceinline__ float bhi(uint v) { return __builtin_bit_cast(float, v & 0xFFFF0000u); }
__device__ __forceinline__ float b2f(ushort u) { return __builtin_bit_cast(float, ((uint)u) << 16); }

// ================================================================ PRE1: zero hist || partition per-block hist || castW
__global__ __launch_bounds__(256) void k_pre1(int* __restrict__ hist, int nbZero,
                                              const int* __restrict__ part,
                                              int* __restrict__ blockHist,
                                              const float* __restrict__ W0,
                                              const float* __restrict__ W1,
                                              ushort* __restrict__ WT0,
                                              ushort* __restrict__ WT1, int n) {
  const int b = blockIdx.x, tid = threadIdx.x;
  if (b < nbZero) {
    int i = b * 256 + tid;
    if (i < n) hist[i] = 0;
  } else if (b < nbZero + PSORT_NB) {
    __shared__ int lh[64];
    int pb = b - nbZero;
    if (tid < 64) lh[tid] = 0;
    __syncthreads();
    int chunk = (n + PSORT_NB - 1) / PSORT_NB;
    int beg = pb * chunk, end = min(n, beg + chunk);
    for (int i = beg + tid; i < end; i += 256) atomicAdd(&lh[part[i]], 1);
    __syncthreads();
    if (tid < 64) blockHist[pb * 64 + tid] = lh[tid];
  } else {
    int idx = (b - nbZero - PSORT_NB) * 256 + tid;  // 0..32767
    const float* W = (idx < 16384) ? W0 : W1;
    ushort* WT = (idx < 16384) ? WT0 : WT1;
    int j = idx & 16383;
    int c = j >> 7, k = j & 127;
    WT[j] = (ushort)f2b(W[k * 128 + c]);
  }
}

// ================================================================ PRE2: edge hist + rank || partition base scan
__global__ __launch_bounds__(256) void k_pre2(const int* __restrict__ dst,
                                              int* __restrict__ hist,
                                              int* __restrict__ rank, int e, int eb,
                                              const int* __restrict__ blockHist,
                                              int* __restrict__ base,
                                              int* __restrict__ ptot) {
  const int b = blockIdx.x, tid = threadIdx.x;
  if (b < eb) {
    int i = b * 256 + tid;
    if (i < e) rank[i] = atomicAdd(&hist[dst[i]], 1);
  } else {
    __shared__ int wtot[4];
    const int p = b - eb;  // 0..63
    const int lane = tid & 63, w = tid >> 6;
    int v = blockHist[tid * 64 + p];
    int x = v;
    #pragma unroll
    for (int off = 1; off < 64; off <<= 1) {
      int y = __shfl_up(x, off);
      if (lane >= off) x += y;
    }
    if (lane == 63) wtot[w] = x;
    __syncthreads();
    int woff = 0;
    if (w > 0) woff = wtot[0];
    if (w > 1) woff += wtot[1];
    if (w > 2) woff += wtot[2];
    base[tid * 64 + p] = woff + x - v;  // exclusive over blocks
    if (tid == 255) ptot[p] = woff + x;
  }
}

// ================================================================ PRE3: scan1 (deg->local excl scan + invs) || partition total scan
__global__ __launch_bounds__(256) void k_pre3(const int* __restrict__ hist,
                                              int* __restrict__ row_start,
                                              float* __restrict__ invs,
                                              int* __restrict__ bsum, int n,
                                              const int* __restrict__ ptot,
                                              int* __restrict__ pexcl,
                                              int* __restrict__ pstart) {
  const int b = blockIdx.x, tid = threadIdx.x;
  if (b < SCAN_NB) {
    __shared__ int wtot[4];
    __shared__ int tot;
    const int lane = tid & 63, w = tid >> 6;
    const int chunk = (n + SCAN_NB - 1) / SCAN_NB;
    const int beg = b * chunk, end = min(n, beg + chunk);
    int running = 0;
    for (int t0 = beg; t0 < end; t0 += 256) {
      int i = t0 + tid;
      int v = (i < end) ? hist[i] : 0;
      int x = v;
      #pragma unroll
      for (int off = 1; off < 64; off <<= 1) {
        int y = __shfl_up(x, off);
        if (lane >= off) x += y;
      }
      if (lane == 63) wtot[w] = x;
      __syncthreads();
      if (tid == 0) {
        int a0 = wtot[0], a1 = wtot[1], a2 = wtot[2], a3 = wtot[3];
        wtot[0] = 0; wtot[1] = a0; wtot[2] = a0 + a1; wtot[3] = a0 + a1 + a2;
        tot = a0 + a1 + a2 + a3;
      }
      __syncthreads();
      if (i < end) {
        row_start[i] = running + wtot[w] + x - v;
        invs[i] = rsqrtf((float)(v + 1));
      }
      running += tot;
      __syncthreads();
    }
    if (tid == 0) bsum[b] = running;
  } else if (tid < 64) {
    int v = ptot[tid];
    int x = v;
    #pragma unroll
    for (int off = 1; off < 64; off <<= 1) {
      int y = __shfl_up(x, off);
      if (tid >= off) x += y;
    }
    int excl = x - v;
    pexcl[tid] = excl;
    pstart[tid] = excl;
    if (tid == 63) pstart[64] = x;
  }
}

// ================================================================ PRE4: scan2 (block sums -> boff) || partition scatter
__global__ __launch_bounds__(256) void k_pre4(const int* __restrict__ bsum,
                                              int* __restrict__ boff,
                                              int* __restrict__ row_fin, int n,
                                              const int* __restrict__ part,
                                              const int* __restrict__ base,
                                              const int* __restrict__ pexcl,
                                              int* __restrict__ perm) {
  const int b = blockIdx.x, tid = threadIdx.x;
  if (b == 0) {
    if (tid < 64) {
      int v0 = bsum[tid * 4], v1 = bsum[tid * 4 + 1], v2 = bsum[tid * 4 + 2], v3 = bsum[tid * 4 + 3];
      int s = v0 + v1 + v2 + v3;
      int x = s;
      #pragma unroll
      for (int off = 1; off < 64; off <<= 1) {
        int y = __shfl_up(x, off);
        if (tid >= off) x += y;
      }
      int run = x - s;
      boff[tid * 4] = run; run += v0;
      boff[tid * 4 + 1] = run; run += v1;
      boff[tid * 4 + 2] = run; run += v2;
      boff[tid * 4 + 3] = run;
      if (tid == 63) row_fin[n] = x;
    }
  } else {
    __shared__ int cur[64];
    const int pb = b - 1;
    if (tid < 64) cur[tid] = base[pb * 64 + tid] + pexcl[tid];
    __syncthreads();
    int chunk = (n + PSORT_NB - 1) / PSORT_NB;
    int beg = pb * chunk, end = min(n, beg + chunk);
    for (int i = beg + tid; i < end; i += 256) {
      int pos = atomicAdd(&cur[part[i]], 1);
      perm[pos] = i;
    }
  }
}

// ================================================================ GEMM body (shared by standalone + mega)
template <bool BN>
__device__ __forceinline__ void gemm_body(ushort* As, ushort* Bs, float* muL, float* sclL,
                                          const void* __restrict__ inp,
                                          const ushort* __restrict__ WT,
                                          const float* __restrict__ invs,
                                          const float* __restrict__ stats_red,
                                          ushort* __restrict__ outb, int n, int bb) {
  const int tid = threadIdx.x;
  const int l = tid & 63, w = tid >> 6;
  const int br0 = bb * 128;

  if (BN) {
    if (tid < 128) {
      float s = stats_red[tid], q = stats_red[128 + tid];
      float m = s * (1.0f / 50000.0f);
      muL[tid] = m;
      sclL[tid] = rsqrtf(q * (1.0f / 50000.0f) - m * m + EPSV);
    }
    __syncthreads();
  }

  #pragma unroll
  for (int i = 0; i < 8; ++i) {
    int flat = i * 2048 + tid * 8;
    int c = flat >> 7;
    uint4 v = *(const uint4*)&WT[flat];
    *(uint4*)&Bs[flat ^ ((c & 7) << 3)] = v;
  }
  #pragma unroll
  for (int i = 0; i < 8; ++i) {
    int flat = i * 2048 + tid * 8;
    int row = flat >> 7, k0 = flat & 127;
    int grow = br0 + row;
    uint4 u;
    if (grow < n) {
      if (BN) {
        const ushort* inb = (const ushort*)inp;
        uint4 raw = *(const uint4*)&inb[(size_t)grow * 128 + k0];
        float f[8] = {blo(raw.x), bhi(raw.x), blo(raw.y), bhi(raw.y),
                      blo(raw.z), bhi(raw.z), blo(raw.w), bhi(raw.w)};
        #pragma unroll
        for (int j = 0; j < 8; ++j) {
          float v = (f[j] - muL[k0 + j]) * sclL[k0 + j];
          f[j] = v > 0.f ? v : 0.f;
        }
        u.x = f2b(f[0]) | (f2b(f[1]) << 16);
        u.y = f2b(f[2]) | (f2b(f[3]) << 16);
        u.z = f2b(f[4]) | (f2b(f[5]) << 16);
        u.w = f2b(f[6]) | (f2b(f[7]) << 16);
      } else {
        const float* inf = (const float*)inp;
        float4 v0 = *(const float4*)&inf[(size_t)grow * 128 + k0];
        float4 v1 = *(const float4*)&inf[(size_t)grow * 128 + k0 + 4];
        u.x = f2b(v0.x) | (f2b(v0.y) << 16);
        u.y = f2b(v0.z) | (f2b(v0.w) << 16);
        u.z = f2b(v1.x) | (f2b(v1.y) << 16);
        u.w = f2b(v1.z) | (f2b(v1.w) << 16);
      }
    } else {
      u.x = u.y = u.z = u.w = 0u;
    }
    *(uint4*)&As[flat ^ ((row & 7) << 3)] = u;
  }
  __syncthreads();

  const int wr = w >> 1, wc = w & 1;
  const int lr = l & 15, lk = (l >> 4) * 8;
  f32x4 acc[4][4];
  #pragma unroll
  for (int m = 0; m < 4; ++m)
    #pragma unroll
    for (int nn = 0; nn < 4; ++nn) acc[m][nn] = (f32x4){0.f, 0.f, 0.f, 0.f};

  #pragma unroll
  for (int ks = 0; ks < 4; ++ks) {
    bf16x8 af[4], bfr[4];
    #pragma unroll
    for (int m = 0; m < 4; ++m) {
      int row = wr * 64 + m * 16 + lr;
      af[m] = *(const bf16x8*)&As[(row * 128 + ks * 32 + lk) ^ ((row & 7) << 3)];
    }
    #pragma unroll
    for (int nn = 0; nn < 4; ++nn) {
      int c = wc * 64 + nn * 16 + lr;
      bfr[nn] = *(const bf16x8*)&Bs[(c * 128 + ks * 32 + lk) ^ ((c & 7) << 3)];
    }
    #pragma unroll
    for (int m = 0; m < 4; ++m)
      #pragma unroll
      for (int nn = 0; nn < 4; ++nn)
        acc[m][nn] = __builtin_amdgcn_mfma_f32_16x16x32_bf16(af[m], bfr[nn], acc[m][nn], 0, 0, 0);
  }

  #pragma unroll
  for (int m = 0; m < 4; ++m) {
    #pragma unroll
    for (int r = 0; r < 4; ++r) {
      int row = br0 + wr * 64 + m * 16 + (l >> 4) * 4 + r;
      if (row >= n) continue;
      float iv = invs[row];
      #pragma unroll
      for (int nn = 0; nn < 4; ++nn) {
        int col = wc * 64 + nn * 16 + lr;
        outb[(size_t)row * 128 + col] = (ushort)f2b(acc[m][nn][r] * iv);
      }
    }
  }
}

// ================================================================ MEGA1: gemm1 || scan3(row_fin) || CSR scatter (atomic-free)
__global__ __launch_bounds__(256) void k_mega1(const float* __restrict__ x,
                                               const ushort* __restrict__ WT0,
                                               const float* __restrict__ invs,
                                               ushort* __restrict__ hsb, int n, int gb,
                                               const int* __restrict__ row_start,
                                               const int* __restrict__ boff,
                                               int* __restrict__ row_fin,
                                               const int* __restrict__ src,
                                               const int* __restrict__ dst,
                                               const int* __restrict__ rank,
                                               int* __restrict__ csr, int e) {
  __shared__ ushort As[16384];
  __shared__ ushort Bs[16384];
  const int b = blockIdx.x, tid = threadIdx.x;
  if (b < gb) {
    gemm_body<false>(As, Bs, nullptr, nullptr, x, WT0, invs, nullptr, hsb, n, b);
  } else if (b < gb + SCAN_NB) {
    const int sb = b - gb;
    const int chunk = (n + SCAN_NB - 1) / SCAN_NB;
    const int beg = sb * chunk, end = min(n, beg + chunk);
    const int off = boff[sb];
    for (int i = beg + tid; i < end; i += 256) row_fin[i] = row_start[i] + off;
  } else {
    const int chunkS = (n + SCAN_NB - 1) / SCAN_NB;
    int i = (b - gb - SCAN_NB) * 256 + tid;
    if (i < e) {
      int d = dst[i];
      csr[row_start[d] + boff[d / chunkS] + rank[i]] = src[i];
    }
  }
}

// ================================================================ standalone GEMM (layer 2)
template <bool BN>
__global__ __launch_bounds__(256) void k_gemm(const void* __restrict__ inp,
                                              const ushort* __restrict__ WT,
                                              const float* __restrict__ invs,
                                              const float* __restrict__ stats_red,
                                              ushort* __restrict__ outb, int n) {
  __shared__ ushort As[16384];
  __shared__ ushort Bs[16384];
  __shared__ float muL[128], sclL[128];
  gemm_body<BN>(As, Bs, muL, sclL, inp, WT, invs, stats_red, outb, n, blockIdx.x);
}

// ================================================================ gather: shfl-broadcast CSR, unroll 8
__global__ __launch_bounds__(256) void k_gather(const ushort* __restrict__ hsb,
                                                const int* __restrict__ row_fin,
                                                const int* __restrict__ csr,
                                                const float* __restrict__ invs,
                                                const float* __restrict__ bias,
                                                ushort* __restrict__ outb,
                                                float* __restrict__ statsP, int n) {
  const int tid = threadIdx.x;
  const int lane = tid & 63, w = tid >> 6;
  const int c0 = lane * 2;
  const ushort* hc = hsb + c0;
  float s0 = 0.f, s1 = 0.f, q0 = 0.f, q1 = 0.f;
  const float bv0 = bias[c0], bv1 = bias[c0 + 1];
  const int stride = gridDim.x * 4;
  for (int node = blockIdx.x * 4 + w; node < n; node += stride) {
    uint vs = *(const uint*)&hc[(size_t)node * 128];  // self loop
    float accx = blo(vs), accy = bhi(vs);
    int beg = row_fin[node], end = row_fin[node + 1];
    int deg = end - beg;
    int base = 0;
    while (base < deg) {
      int cnt = min(deg - base, 64);
      int sidx = 0;
      if (lane < cnt) sidx = csr[beg + base + lane];
      int j = 0;
      for (; j + 7 < cnt; j += 8) {
        int sA = __shfl(sidx, j + 0), sB = __shfl(sidx, j + 1);
        int sC = __shfl(sidx, j + 2), sD = __shfl(sidx, j + 3);
        int sE = __shfl(sidx, j + 4), sF = __shfl(sidx, j + 5);
        int sG = __shfl(sidx, j + 6), sH = __shfl(sidx, j + 7);
        uint vA = *(const uint*)&hc[(size_t)sA * 128];
        uint vB = *(const uint*)&hc[(size_t)sB * 128];
        uint vC = *(const uint*)&hc[(size_t)sC * 128];
        uint vD = *(const uint*)&hc[(size_t)sD * 128];
        uint vE = *(const uint*)&hc[(size_t)sE * 128];
        uint vF = *(const uint*)&hc[(size_t)sF * 128];
        uint vG = *(const uint*)&hc[(size_t)sG * 128];
        uint vH = *(const uint*)&hc[(size_t)sH * 128];
        accx += ((blo(vA) + blo(vB)) + (blo(vC) + blo(vD))) +
                ((blo(vE) + blo(vF)) + (blo(vG) + blo(vH)));
        accy += ((bhi(vA) + bhi(vB)) + (bhi(vC) + bhi(vD))) +
                ((bhi(vE) + bhi(vF)) + (bhi(vG) + bhi(vH)));
      }
      for (; j + 3 < cnt; j += 4) {
        int sA = __shfl(sidx, j + 0), sB = __shfl(sidx, j + 1);
        int sC = __shfl(sidx, j + 2), sD = __shfl(sidx, j + 3);
        uint vA = *(const uint*)&hc[(size_t)sA * 128];
        uint vB = *(const uint*)&hc[(size_t)sB * 128];
        uint vC = *(const uint*)&hc[(size_t)sC * 128];
        uint vD = *(const uint*)&hc[(size_t)sD * 128];
        accx += (blo(vA) + blo(vB)) + (blo(vC) + blo(vD));
        accy += (bhi(vA) + bhi(vB)) + (bhi(vC) + bhi(vD));
      }
      for (; j < cnt; ++j) {
        int sA = __shfl(sidx, j);
        uint vA = *(const uint*)&hc[(size_t)sA * 128];
        accx += blo(vA);
        accy += bhi(vA);
      }
      base += cnt;
    }
    float iv = invs[node];
    float o0 = accx * iv + bv0, o1 = accy * iv + bv1;
    *(uint*)&outb[(size_t)node * 128 + c0] = f2b(o0) | (f2b(o1) << 16);
    s0 += o0; s1 += o1; q0 += o0 * o0; q1 += o1 * o1;
  }
  __shared__ float redS[4][128], redQ[4][128];
  redS[w][c0] = s0; redS[w][c0 + 1] = s1;
  redQ[w][c0] = q0; redQ[w][c0 + 1] = q1;
  __syncthreads();
  if (tid < 128) {
    float s = redS[0][tid] + redS[1][tid] + redS[2][tid] + redS[3][tid];
    statsP[blockIdx.x * 256 + tid] = s;
  } else {
    int t = tid - 128;
    float q = redQ[0][t] + redQ[1][t] + redQ[2][t] + redQ[3][t];
    statsP[blockIdx.x * 256 + tid] = q;
  }
}

// ================================================================ reduce stats partials -> stats_red[256]
__global__ __launch_bounds__(1024) void k_finstats(const float* __restrict__ statsP,
                                                   float* __restrict__ stats_red,
                                                   int nb) {
  int t = threadIdx.x;
  int c = blockIdx.x * 16 + (t & 15);
  int b0 = t >> 4;
  int per = nb >> 6;
  float s = 0.f;
  for (int j = 0; j < per; ++j) s += statsP[(b0 * per + j) * 256 + c];
  __shared__ float red[1024];
  red[t] = s;
  __syncthreads();
  for (int st = 512; st >= 16; st >>= 1) {
    if (t < st) red[t] += red[t + st];
    __syncthreads();
  }
  if (t < 16) stats_red[blockIdx.x * 16 + t] = red[t];
}

// ================================================================ pool over partition-sorted rows
__global__ __launch_bounds__(512) void k_pool2(const ushort* __restrict__ hb,
                                               const float* __restrict__ stats_red,
                                               const float* __restrict__ cv,
                                               const int* __restrict__ perm,
                                               const int* __restrict__ pstart,
                                               float* __restrict__ poolP, int n) {
  const int tid = threadIdx.x;
  const int lane = tid & 63, w = tid >> 6;
  const int p = blockIdx.x >> 2, s = blockIdx.x & 3;
  const int g = s * 8 + w;
  const int c0 = lane * 2;

  float s0 = stats_red[c0], s1 = stats_red[c0 + 1];
  float qq0 = stats_red[128 + c0], qq1 = stats_red[128 + c0 + 1];
  float mu0 = s0 * (1.0f / 50000.0f), mu1 = s1 * (1.0f / 50000.0f);
  float scl0 = rsqrtf(qq0 * (1.0f / 50000.0f) - mu0 * mu0 + EPSV);
  float scl1 = rsqrtf(qq1 * (1.0f / 50000.0f) - mu1 * mu1 + EPSV);

  const int beg = pstart[p], end = pstart[p + 1];
  float cc0 = 0.f, cc1 = 0.f, cn0 = 0.f, cn1 = 0.f;

  int j = beg + g;
  for (; j + 32 < end; j += 64) {
    int rA = perm[j], rB = perm[j + 32];
    uint vA = *(const uint*)&hb[(size_t)rA * 128 + c0];
    uint vB = *(const uint*)&hb[(size_t)rB * 128 + c0];
    float cvA = cv[rA], cvB = cv[rB];
    float xA0 = (blo(vA) - mu0) * scl0; xA0 = xA0 > 0.f ? xA0 : 0.f;
    float xA1 = (bhi(vA) - mu1) * scl1; xA1 = xA1 > 0.f ? xA1 : 0.f;
    float xB0 = (blo(vB) - mu0) * scl0; xB0 = xB0 > 0.f ? xB0 : 0.f;
    float xB1 = (bhi(vB) - mu1) * scl1; xB1 = xB1 > 0.f ? xB1 : 0.f;
    cc0 += xA0 * cvA + xB0 * cvB;
    cc1 += xA1 * cvA + xB1 * cvB;
    cn0 += xA0 * (1.f - cvA) + xB0 * (1.f - cvB);
    cn1 += xA1 * (1.f - cvA) + xB1 * (1.f - cvB);
  }
  if (j < end) {
    int rA = perm[j];
    uint vA = *(const uint*)&hb[(size_t)rA * 128 + c0];
    float cvA = cv[rA];
    float xA0 = (blo(vA) - mu0) * scl0; xA0 = xA0 > 0.f ? xA0 : 0.f;
    float xA1 = (bhi(vA) - mu1) * scl1; xA1 = xA1 > 0.f ? xA1 : 0.f;
    cc0 += xA0 * cvA;
    cc1 += xA1 * cvA;
    cn0 += xA0 * (1.f - cvA);
    cn1 += xA1 * (1.f - cvA);
  }

  __shared__ float redC[8][128], redN[8][128];
  redC[w][c0] = cc0; redC[w][c0 + 1] = cc1;
  redN[w][c0] = cn0; redN[w][c0 + 1] = cn1;
  __syncthreads();
  if (tid < 128) {
    float a = 0.f;
    #pragma unroll
    for (int ww = 0; ww < 8; ++ww) a += redC[ww][tid];
    poolP[blockIdx.x * 256 + tid] = a;
  } else if (tid < 256) {
    int t = tid - 128;
    float a = 0.f;
    #pragma unroll
    for (int ww = 0; ww < 8; ++ww) a += redN[ww][t];
    poolP[blockIdx.x * 256 + tid] = a;
  }
}

// ================================================================ final MLP: one block per partition
__global__ __launch_bounds__(128) void k_mlp(const ushort* __restrict__ hb,
                                             const float* __restrict__ stats_red,
                                             const float* __restrict__ poolP,
                                             const float* __restrict__ l1W,
                                             const float* __restrict__ l1b,
                                             const float* __restrict__ l2W,
                                             const float* __restrict__ l2b,
                                             const int* __restrict__ curr_ptr,
                                             float* __restrict__ out, int n) {
  const int p = blockIdx.x;
  const int t = threadIdx.x;
  __shared__ float z[384];
  int curr = *curr_ptr;
  float s = stats_red[t], q = stats_red[128 + t];
  float mu = s / (float)n;
  float scl = rsqrtf(q / (float)n - mu * mu + EPSV);
  float v = b2f(hb[(size_t)curr * 128 + t]);
  v = (v - mu) * scl;
  z[t] = v > 0.f ? v : 0.f;
  float ccore = 0.f, cnon = 0.f;
  #pragma unroll
  for (int sb = 0; sb < 4; ++sb) {
    ccore += poolP[(p * 4 + sb) * 256 + t];
    cnon  += poolP[(p * 4 + sb) * 256 + 128 + t];
  }
  z[128 + t] = ccore;
  z[256 + t] = cnon;
  __syncthreads();
  float a = l1b[t];
  for (int k = 0; k < 384; ++k) a += z[k] * l1W[k * 128 + t];
  a = a > 0.f ? a : 0.f;
  float pr = a * l2W[t];
  #pragma unroll
  for (int off = 32; off; off >>= 1) pr += __shfl_down(pr, off);
  __shared__ float rr[2];
  if ((t & 63) == 0) rr[t >> 6] = pr;
  __syncthreads();
  if (t == 0) out[p] = rr[0] + rr[1] + l2b[0];
}

// ================================================================ host
extern "C" void kernel_launch(void* const* d_in, const int* in_sizes, int n_in,
                              void* d_out, int out_size, void* d_ws, size_t ws_size,
                              hipStream_t stream) {
  const float* x    = (const float*)d_in[0];
  const float* cv   = (const float*)d_in[1];
  const float* W0   = (const float*)d_in[2];
  const float* b0   = (const float*)d_in[3];
  const float* W1   = (const float*)d_in[4];
  const float* b1   = (const float*)d_in[5];
  const float* l1W  = (const float*)d_in[6];
  const float* l1b  = (const float*)d_in[7];
  const float* l2W  = (const float*)d_in[8];
  const float* l2b  = (const float*)d_in[9];
  const int*   ei   = (const int*)d_in[10];
  const int*   part = (const int*)d_in[11];
  const int*   curr = (const int*)d_in[12];

  const int N = in_sizes[1];          // 50000
  const int E = in_sizes[10] / 2;     // 640000
  const int* src = ei;
  const int* dst = ei + E;

  const int GATHER_BLOCKS = 2048;

  char* w = (char*)d_ws;
  size_t off = 0;
  auto alloc = [&](size_t bytes) -> void* {
    void* p = (void*)(w + off);
    off = (off + bytes + 255) & ~(size_t)255;
    return p;
  };
  int*   hist      = (int*)alloc((size_t)N * 4);
  int*   row_start = (int*)alloc((size_t)(N + 1) * 4);
  int*   row_fin   = (int*)alloc((size_t)(N + 1) * 4);
  int*   csr       = (int*)alloc((size_t)E * 4);
  int*   rank      = (int*)alloc((size_t)E * 4);
  float* invs      = (float*)alloc((size_t)N * 4);
  int*   bsum      = (int*)alloc((size_t)SCAN_NB * 4);
  int*   boff      = (int*)alloc((size_t)SCAN_NB * 4);
  int*   blockHist = (int*)alloc((size_t)PSORT_NB * 64 * 4);
  int*   pbase     = (int*)alloc((size_t)PSORT_NB * 64 * 4);
  int*   ptot      = (int*)alloc(64 * 4);
  int*   pexcl     = (int*)alloc(64 * 4);
  int*   pstart    = (int*)alloc(65 * 4);
  int*   perm      = (int*)alloc((size_t)N * 4);
  float* stats_red0 = (float*)alloc(256 * 4);
  float* stats_red1 = (float*)alloc(256 * 4);
  float* statsP    = (float*)alloc((size_t)GATHER_BLOCKS * 256 * 4);
  float* poolP     = (float*)alloc((size_t)256 * 256 * 4);
  ushort* WT0      = (ushort*)alloc((size_t)16384 * 2);
  ushort* WT1      = (ushort*)alloc((size_t)16384 * 2);
  ushort* hsb      = (ushort*)alloc((size_t)N * 128 * 2);
  ushort* hb       = (ushort*)alloc((size_t)N * 128 * 2);
  (void)ws_size;

  const int eb = (E + 255) / 256;
  const int nbZero = (N + 255) / 256;
  const int gb = (N + 127) / 128;

  // PRE1: zero(hist) || partition per-block hist || castW
  k_pre1<<<nbZero + PSORT_NB + 128, 256, 0, stream>>>(hist, nbZero, part, blockHist,
                                                      W0, W1, WT0, WT1, N);
  // PRE2: edge hist + rank || partition base scan
  k_pre2<<<eb + 64, 256, 0, stream>>>(dst, hist, rank, E, eb, blockHist, pbase, ptot);
  // PRE3: degree scan phase 1 + invs || partition total scan
  k_pre3<<<SCAN_NB + 1, 256, 0, stream>>>(hist, row_start, invs, bsum, N, ptot, pexcl, pstart);
  // PRE4: block-sum scan (-> boff, row_fin[n]) || partition scatter
  k_pre4<<<1 + PSORT_NB, 256, 0, stream>>>(bsum, boff, row_fin, N, part, pbase, pexcl, perm);
  // MEGA1: gemm layer1 || finalize row_fin || CSR scatter
  k_mega1<<<gb + SCAN_NB + eb, 256, 0, stream>>>(x, WT0, invs, hsb, N, gb,
                                                 row_start, boff, row_fin,
                                                 src, dst, rank, csr, E);
  // layer 1 aggregate
  k_gather<<<GATHER_BLOCKS, 256, 0, stream>>>(hsb, row_fin, csr, invs, b0, hb, statsP, N);
  k_finstats<<<16, 1024, 0, stream>>>(statsP, stats_red0, GATHER_BLOCKS);
  // layer 2
  k_gemm<true><<<gb, 256, 0, stream>>>(hb, WT1, invs, stats_red0, hsb, N);
  k_gather<<<GATHER_BLOCKS, 256, 0, stream>>>(hsb, row_fin, csr, invs, b1, hb, statsP, N);
  k_finstats<<<16, 1024, 0, stream>>>(statsP, stats_red1, GATHER_BLOCKS);
  // pooling + head
  k_pool2<<<256, 512, 0, stream>>>(hb, stats_red1, cv, perm, pstart, poolP, N);
  k_mlp<<<64, 128, 0, stream>>>(hb, stats_red1, poolP, l1W, l1b, l2W, l2b, curr, (float*)d_out, N);
}

// Round 9
// 175.116 us; speedup vs baseline: 3.5322x; 1.0079x over previous
//
#include <hip/hip_runtime.h>
#include <math.h>

#define EPSV 1e-5f
#define PSORT_NB 256
#define SCAN_NB 256

typedef __attribute__((ext_vector_type(8))) short bf16x8;
typedef __attribute__((ext_vector_type(4))) float f32x4;

__device__ __forceinline__ uint f2b(float f) {  // fp32 -> bf16 bits (RNE)
  uint u = __builtin_bit_cast(uint, f);
  return (u + 0x7FFFu + ((u >> 16) & 1u)) >> 16;
}
__device__ __forceinline__ float blo(uint v) { return __builtin_bit_cast(float, v << 16); }
__device__ __forceinline__ float bhi(uint v) { return __builtin_bit_cast(float, v & 0xFFFF0000u); }
__device__ __forceinline__ float b2f(ushort u) { return __builtin_bit_cast(float, ((uint)u) << 16); }

// ================================================================ PRE1: zero hist || partition per-block hist || castW
__global__ __launch_bounds__(256) void k_pre1(int* __restrict__ hist, int nbZero,
                                              const int* __restrict__ part,
                                              int* __restrict__ blockHist,
                                              const float* __restrict__ W0,
                                              const float* __restrict__ W1,
                                              ushort* __restrict__ WT0,
                                              ushort* __restrict__ WT1, int n) {
  const int b = blockIdx.x, tid = threadIdx.x;
  if (b < nbZero) {
    int i = b * 256 + tid;
    if (i < n) hist[i] = 0;
  } else if (b < nbZero + PSORT_NB) {
    __shared__ int lh[64];
    int pb = b - nbZero;
    if (tid < 64) lh[tid] = 0;
    __syncthreads();
    int chunk = (n + PSORT_NB - 1) / PSORT_NB;
    int beg = pb * chunk, end = min(n, beg + chunk);
    for (int i = beg + tid; i < end; i += 256) atomicAdd(&lh[part[i]], 1);
    __syncthreads();
    if (tid < 64) blockHist[pb * 64 + tid] = lh[tid];
  } else {
    int idx = (b - nbZero - PSORT_NB) * 256 + tid;  // 0..32767
    const float* W = (idx < 16384) ? W0 : W1;
    ushort* WT = (idx < 16384) ? WT0 : WT1;
    int j = idx & 16383;
    int c = j >> 7, k = j & 127;
    WT[j] = (ushort)f2b(W[k * 128 + c]);
  }
}

// ================================================================ GEMM body
// BN: apply batchnorm+relu to bf16 input; INV: scale output rows by invs
template <bool BN, bool INV>
__device__ __forceinline__ void gemm_body(ushort* As, ushort* Bs, float* muL, float* sclL,
                                          const void* __restrict__ inp,
                                          const ushort* __restrict__ WT,
                                          const float* __restrict__ invs,
                                          const float* __restrict__ stats_red,
                                          ushort* __restrict__ outb, int n, int bb) {
  const int tid = threadIdx.x;
  const int l = tid & 63, w = tid >> 6;
  const int br0 = bb * 128;

  if (BN) {
    if (tid < 128) {
      float s = stats_red[tid], q = stats_red[128 + tid];
      float m = s * (1.0f / 50000.0f);
      muL[tid] = m;
      sclL[tid] = rsqrtf(q * (1.0f / 50000.0f) - m * m + EPSV);
    }
    __syncthreads();
  }

  #pragma unroll
  for (int i = 0; i < 8; ++i) {
    int flat = i * 2048 + tid * 8;
    int c = flat >> 7;
    uint4 v = *(const uint4*)&WT[flat];
    *(uint4*)&Bs[flat ^ ((c & 7) << 3)] = v;
  }
  #pragma unroll
  for (int i = 0; i < 8; ++i) {
    int flat = i * 2048 + tid * 8;
    int row = flat >> 7, k0 = flat & 127;
    int grow = br0 + row;
    uint4 u;
    if (grow < n) {
      if (BN) {
        const ushort* inb = (const ushort*)inp;
        uint4 raw = *(const uint4*)&inb[(size_t)grow * 128 + k0];
        float f[8] = {blo(raw.x), bhi(raw.x), blo(raw.y), bhi(raw.y),
                      blo(raw.z), bhi(raw.z), blo(raw.w), bhi(raw.w)};
        #pragma unroll
        for (int j = 0; j < 8; ++j) {
          float v = (f[j] - muL[k0 + j]) * sclL[k0 + j];
          f[j] = v > 0.f ? v : 0.f;
        }
        u.x = f2b(f[0]) | (f2b(f[1]) << 16);
        u.y = f2b(f[2]) | (f2b(f[3]) << 16);
        u.z = f2b(f[4]) | (f2b(f[5]) << 16);
        u.w = f2b(f[6]) | (f2b(f[7]) << 16);
      } else {
        const float* inf = (const float*)inp;
        float4 v0 = *(const float4*)&inf[(size_t)grow * 128 + k0];
        float4 v1 = *(const float4*)&inf[(size_t)grow * 128 + k0 + 4];
        u.x = f2b(v0.x) | (f2b(v0.y) << 16);
        u.y = f2b(v0.z) | (f2b(v0.w) << 16);
        u.z = f2b(v1.x) | (f2b(v1.y) << 16);
        u.w = f2b(v1.z) | (f2b(v1.w) << 16);
      }
    } else {
      u.x = u.y = u.z = u.w = 0u;
    }
    *(uint4*)&As[flat ^ ((row & 7) << 3)] = u;
  }
  __syncthreads();

  const int wr = w >> 1, wc = w & 1;
  const int lr = l & 15, lk = (l >> 4) * 8;
  f32x4 acc[4][4];
  #pragma unroll
  for (int m = 0; m < 4; ++m)
    #pragma unroll
    for (int nn = 0; nn < 4; ++nn) acc[m][nn] = (f32x4){0.f, 0.f, 0.f, 0.f};

  #pragma unroll
  for (int ks = 0; ks < 4; ++ks) {
    bf16x8 af[4], bfr[4];
    #pragma unroll
    for (int m = 0; m < 4; ++m) {
      int row = wr * 64 + m * 16 + lr;
      af[m] = *(const bf16x8*)&As[(row * 128 + ks * 32 + lk) ^ ((row & 7) << 3)];
    }
    #pragma unroll
    for (int nn = 0; nn < 4; ++nn) {
      int c = wc * 64 + nn * 16 + lr;
      bfr[nn] = *(const bf16x8*)&Bs[(c * 128 + ks * 32 + lk) ^ ((c & 7) << 3)];
    }
    #pragma unroll
    for (int m = 0; m < 4; ++m)
      #pragma unroll
      for (int nn = 0; nn < 4; ++nn)
        acc[m][nn] = __builtin_amdgcn_mfma_f32_16x16x32_bf16(af[m], bfr[nn], acc[m][nn], 0, 0, 0);
  }

  #pragma unroll
  for (int m = 0; m < 4; ++m) {
    #pragma unroll
    for (int r = 0; r < 4; ++r) {
      int row = br0 + wr * 64 + m * 16 + (l >> 4) * 4 + r;
      if (row >= n) continue;
      float iv = INV ? invs[row] : 1.0f;
      #pragma unroll
      for (int nn = 0; nn < 4; ++nn) {
        int col = wc * 64 + nn * 16 + lr;
        float v = acc[m][nn][r];
        if (INV) v *= iv;
        outb[(size_t)row * 128 + col] = (ushort)f2b(v);
      }
    }
  }
}

// ================================================================ MEGA2: gemm1 (no invs) || edge hist+rank || pbaseA
__global__ __launch_bounds__(256) void k_mega2(const float* __restrict__ x,
                                               const ushort* __restrict__ WT0,
                                               ushort* __restrict__ hsb, int n, int gb,
                                               const int* __restrict__ dst,
                                               int* __restrict__ hist,
                                               int* __restrict__ rank, int e, int eb,
                                               const int* __restrict__ blockHist,
                                               int* __restrict__ base,
                                               int* __restrict__ ptot) {
  __shared__ ushort As[16384];
  __shared__ ushort Bs[16384];
  const int b = blockIdx.x, tid = threadIdx.x;
  if (b < gb) {
    gemm_body<false, false>(As, Bs, nullptr, nullptr, x, WT0, nullptr, nullptr, hsb, n, b);
  } else if (b < gb + eb) {
    int i = (b - gb) * 256 + tid;
    if (i < e) rank[i] = atomicAdd(&hist[dst[i]], 1);
  } else {
    __shared__ int wtot[4];
    const int p = b - gb - eb;  // 0..63
    const int lane = tid & 63, w = tid >> 6;
    int v = blockHist[tid * 64 + p];
    int x2 = v;
    #pragma unroll
    for (int off = 1; off < 64; off <<= 1) {
      int y = __shfl_up(x2, off);
      if (lane >= off) x2 += y;
    }
    if (lane == 63) wtot[w] = x2;
    __syncthreads();
    int woff = 0;
    if (w > 0) woff = wtot[0];
    if (w > 1) woff += wtot[1];
    if (w > 2) woff += wtot[2];
    base[tid * 64 + p] = woff + x2 - v;
    if (tid == 255) ptot[p] = woff + x2;
  }
}

// ================================================================ PRE3: scan1 (deg scan + invs) || partition total scan
__global__ __launch_bounds__(256) void k_pre3(const int* __restrict__ hist,
                                              int* __restrict__ row_start,
                                              float* __restrict__ invs,
                                              int* __restrict__ bsum, int n,
                                              const int* __restrict__ ptot,
                                              int* __restrict__ pexcl,
                                              int* __restrict__ pstart) {
  const int b = blockIdx.x, tid = threadIdx.x;
  if (b < SCAN_NB) {
    __shared__ int wtot[4];
    __shared__ int tot;
    const int lane = tid & 63, w = tid >> 6;
    const int chunk = (n + SCAN_NB - 1) / SCAN_NB;
    const int beg = b * chunk, end = min(n, beg + chunk);
    int running = 0;
    for (int t0 = beg; t0 < end; t0 += 256) {
      int i = t0 + tid;
      int v = (i < end) ? hist[i] : 0;
      int x = v;
      #pragma unroll
      for (int off = 1; off < 64; off <<= 1) {
        int y = __shfl_up(x, off);
        if (lane >= off) x += y;
      }
      if (lane == 63) wtot[w] = x;
      __syncthreads();
      if (tid == 0) {
        int a0 = wtot[0], a1 = wtot[1], a2 = wtot[2], a3 = wtot[3];
        wtot[0] = 0; wtot[1] = a0; wtot[2] = a0 + a1; wtot[3] = a0 + a1 + a2;
        tot = a0 + a1 + a2 + a3;
      }
      __syncthreads();
      if (i < end) {
        row_start[i] = running + wtot[w] + x - v;
        invs[i] = rsqrtf((float)(v + 1));
      }
      running += tot;
      __syncthreads();
    }
    if (tid == 0) bsum[b] = running;
  } else if (tid < 64) {
    int v = ptot[tid];
    int x = v;
    #pragma unroll
    for (int off = 1; off < 64; off <<= 1) {
      int y = __shfl_up(x, off);
      if (tid >= off) x += y;
    }
    int excl = x - v;
    pexcl[tid] = excl;
    pstart[tid] = excl;
    if (tid == 63) pstart[64] = x;
  }
}

// ================================================================ PRE4: scan2 (block sums -> boff) || partition scatter
__global__ __launch_bounds__(256) void k_pre4(const int* __restrict__ bsum,
                                              int* __restrict__ boff,
                                              int* __restrict__ row_fin, int n,
                                              const int* __restrict__ part,
                                              const int* __restrict__ base,
                                              const int* __restrict__ pexcl,
                                              int* __restrict__ perm) {
  const int b = blockIdx.x, tid = threadIdx.x;
  if (b == 0) {
    if (tid < 64) {
      int v0 = bsum[tid * 4], v1 = bsum[tid * 4 + 1], v2 = bsum[tid * 4 + 2], v3 = bsum[tid * 4 + 3];
      int s = v0 + v1 + v2 + v3;
      int x = s;
      #pragma unroll
      for (int off = 1; off < 64; off <<= 1) {
        int y = __shfl_up(x, off);
        if (tid >= off) x += y;
      }
      int run = x - s;
      boff[tid * 4] = run; run += v0;
      boff[tid * 4 + 1] = run; run += v1;
      boff[tid * 4 + 2] = run; run += v2;
      boff[tid * 4 + 3] = run;
      if (tid == 63) row_fin[n] = x;
    }
  } else {
    __shared__ int cur[64];
    const int pb = b - 1;
    if (tid < 64) cur[tid] = base[pb * 64 + tid] + pexcl[tid];
    __syncthreads();
    int chunk = (n + PSORT_NB - 1) / PSORT_NB;
    int beg = pb * chunk, end = min(n, beg + chunk);
    for (int i = beg + tid; i < end; i += 256) {
      int pos = atomicAdd(&cur[part[i]], 1);
      perm[pos] = i;
    }
  }
}

// ================================================================ MEGA5: row_fin finalize || CSR scatter (atomic-free)
__global__ __launch_bounds__(256) void k_mega5(const int* __restrict__ row_start,
                                               const int* __restrict__ boff,
                                               int* __restrict__ row_fin, int n,
                                               const int* __restrict__ src,
                                               const int* __restrict__ dst,
                                               const int* __restrict__ rank,
                                               int* __restrict__ csr, int e) {
  const int b = blockIdx.x, tid = threadIdx.x;
  const int chunk = (n + SCAN_NB - 1) / SCAN_NB;
  if (b < SCAN_NB) {
    const int beg = b * chunk, end = min(n, beg + chunk);
    const int off = boff[b];
    for (int i = beg + tid; i < end; i += 256) row_fin[i] = row_start[i] + off;
  } else {
    int i = (b - SCAN_NB) * 256 + tid;
    if (i < e) {
      int d = dst[i];
      csr[row_start[d] + boff[d / chunk] + rank[i]] = src[i];
    }
  }
}

// ================================================================ standalone GEMM (layer 2; BN + invs)
__global__ __launch_bounds__(256) void k_gemm2(const ushort* __restrict__ inp,
                                               const ushort* __restrict__ WT,
                                               const float* __restrict__ invs,
                                               const float* __restrict__ stats_red,
                                               ushort* __restrict__ outb, int n) {
  __shared__ ushort As[16384];
  __shared__ ushort Bs[16384];
  __shared__ float muL[128], sclL[128];
  gemm_body<true, true>(As, Bs, muL, sclL, inp, WT, invs, stats_red, outb, n, blockIdx.x);
}

// ================================================================ gather; EINV: per-edge invs[src] weighting (layer 1)
template <bool EINV>
__global__ __launch_bounds__(256) void k_gather(const ushort* __restrict__ hsb,
                                                const int* __restrict__ row_fin,
                                                const int* __restrict__ csr,
                                                const float* __restrict__ invs,
                                                const float* __restrict__ bias,
                                                ushort* __restrict__ outb,
                                                float* __restrict__ statsP, int n) {
  const int tid = threadIdx.x;
  const int lane = tid & 63, w = tid >> 6;
  const int c0 = lane * 2;
  const ushort* hc = hsb + c0;
  float s0 = 0.f, s1 = 0.f, q0 = 0.f, q1 = 0.f;
  const float bv0 = bias[c0], bv1 = bias[c0 + 1];
  const int stride = gridDim.x * 4;
  for (int node = blockIdx.x * 4 + w; node < n; node += stride) {
    uint vs = *(const uint*)&hc[(size_t)node * 128];  // self loop
    float iv_d = invs[node];
    float accx, accy;
    if (EINV) { accx = iv_d * blo(vs); accy = iv_d * bhi(vs); }
    else      { accx = blo(vs);        accy = bhi(vs); }
    int beg = row_fin[node], end = row_fin[node + 1];
    int deg = end - beg;
    int base = 0;
    while (base < deg) {
      int cnt = min(deg - base, 64);
      int sidx = 0;
      float siv = 0.f;
      if (lane < cnt) {
        sidx = csr[beg + base + lane];
        if (EINV) siv = invs[sidx];
      }
      int j = 0;
      for (; j + 7 < cnt; j += 8) {
        int sA = __shfl(sidx, j + 0), sB = __shfl(sidx, j + 1);
        int sC = __shfl(sidx, j + 2), sD = __shfl(sidx, j + 3);
        int sE = __shfl(sidx, j + 4), sF = __shfl(sidx, j + 5);
        int sG = __shfl(sidx, j + 6), sH = __shfl(sidx, j + 7);
        uint vA = *(const uint*)&hc[(size_t)sA * 128];
        uint vB = *(const uint*)&hc[(size_t)sB * 128];
        uint vC = *(const uint*)&hc[(size_t)sC * 128];
        uint vD = *(const uint*)&hc[(size_t)sD * 128];
        uint vE = *(const uint*)&hc[(size_t)sE * 128];
        uint vF = *(const uint*)&hc[(size_t)sF * 128];
        uint vG = *(const uint*)&hc[(size_t)sG * 128];
        uint vH = *(const uint*)&hc[(size_t)sH * 128];
        if (EINV) {
          float fA = __shfl(siv, j + 0), fB = __shfl(siv, j + 1);
          float fC = __shfl(siv, j + 2), fD = __shfl(siv, j + 3);
          float fE = __shfl(siv, j + 4), fF = __shfl(siv, j + 5);
          float fG = __shfl(siv, j + 6), fH = __shfl(siv, j + 7);
          accx += fA * blo(vA) + fB * blo(vB) + fC * blo(vC) + fD * blo(vD) +
                  fE * blo(vE) + fF * blo(vF) + fG * blo(vG) + fH * blo(vH);
          accy += fA * bhi(vA) + fB * bhi(vB) + fC * bhi(vC) + fD * bhi(vD) +
                  fE * bhi(vE) + fF * bhi(vF) + fG * bhi(vG) + fH * bhi(vH);
        } else {
          accx += ((blo(vA) + blo(vB)) + (blo(vC) + blo(vD))) +
                  ((blo(vE) + blo(vF)) + (blo(vG) + blo(vH)));
          accy += ((bhi(vA) + bhi(vB)) + (bhi(vC) + bhi(vD))) +
                  ((bhi(vE) + bhi(vF)) + (bhi(vG) + bhi(vH)));
        }
      }
      for (; j < cnt; ++j) {
        int sA = __shfl(sidx, j);
        uint vA = *(const uint*)&hc[(size_t)sA * 128];
        if (EINV) {
          float fA = __shfl(siv, j);
          accx += fA * blo(vA);
          accy += fA * bhi(vA);
        } else {
          accx += blo(vA);
          accy += bhi(vA);
        }
      }
      base += cnt;
    }
    float o0 = accx * iv_d + bv0, o1 = accy * iv_d + bv1;
    *(uint*)&outb[(size_t)node * 128 + c0] = f2b(o0) | (f2b(o1) << 16);
    s0 += o0; s1 += o1; q0 += o0 * o0; q1 += o1 * o1;
  }
  __shared__ float redS[4][128], redQ[4][128];
  redS[w][c0] = s0; redS[w][c0 + 1] = s1;
  redQ[w][c0] = q0; redQ[w][c0 + 1] = q1;
  __syncthreads();
  if (tid < 128) {
    float s = redS[0][tid] + redS[1][tid] + redS[2][tid] + redS[3][tid];
    statsP[blockIdx.x * 256 + tid] = s;
  } else {
    int t = tid - 128;
    float q = redQ[0][t] + redQ[1][t] + redQ[2][t] + redQ[3][t];
    statsP[blockIdx.x * 256 + tid] = q;
  }
}

// ================================================================ reduce stats partials -> stats_red[256]
__global__ __launch_bounds__(1024) void k_finstats(const float* __restrict__ statsP,
                                                   float* __restrict__ stats_red,
                                                   int nb) {
  int t = threadIdx.x;
  int c = blockIdx.x * 16 + (t & 15);
  int b0 = t >> 4;
  int per = nb >> 6;
  float s = 0.f;
  for (int j = 0; j < per; ++j) s += statsP[(b0 * per + j) * 256 + c];
  __shared__ float red[1024];
  red[t] = s;
  __syncthreads();
  for (int st = 512; st >= 16; st >>= 1) {
    if (t < st) red[t] += red[t + st];
    __syncthreads();
  }
  if (t < 16) stats_red[blockIdx.x * 16 + t] = red[t];
}

// ================================================================ pool over partition-sorted rows
__global__ __launch_bounds__(512) void k_pool2(const ushort* __restrict__ hb,
                                               const float* __restrict__ stats_red,
                                               const float* __restrict__ cv,
                                               const int* __restrict__ perm,
                                               const int* __restrict__ pstart,
                                               float* __restrict__ poolP, int n) {
  const int tid = threadIdx.x;
  const int lane = tid & 63, w = tid >> 6;
  const int p = blockIdx.x >> 2, s = blockIdx.x & 3;
  const int g = s * 8 + w;
  const int c0 = lane * 2;

  float s0 = stats_red[c0], s1 = stats_red[c0 + 1];
  float qq0 = stats_red[128 + c0], qq1 = stats_red[128 + c0 + 1];
  float mu0 = s0 * (1.0f / 50000.0f), mu1 = s1 * (1.0f / 50000.0f);
  float scl0 = rsqrtf(qq0 * (1.0f / 50000.0f) - mu0 * mu0 + EPSV);
  float scl1 = rsqrtf(qq1 * (1.0f / 50000.0f) - mu1 * mu1 + EPSV);

  const int beg = pstart[p], end = pstart[p + 1];
  float cc0 = 0.f, cc1 = 0.f, cn0 = 0.f, cn1 = 0.f;

  int j = beg + g;
  for (; j + 32 < end; j += 64) {
    int rA = perm[j], rB = perm[j + 32];
    uint vA = *(const uint*)&hb[(size_t)rA * 128 + c0];
    uint vB = *(const uint*)&hb[(size_t)rB * 128 + c0];
    float cvA = cv[rA], cvB = cv[rB];
    float xA0 = (blo(vA) - mu0) * scl0; xA0 = xA0 > 0.f ? xA0 : 0.f;
    float xA1 = (bhi(vA) - mu1) * scl1; xA1 = xA1 > 0.f ? xA1 : 0.f;
    float xB0 = (blo(vB) - mu0) * scl0; xB0 = xB0 > 0.f ? xB0 : 0.f;
    float xB1 = (bhi(vB) - mu1) * scl1; xB1 = xB1 > 0.f ? xB1 : 0.f;
    cc0 += xA0 * cvA + xB0 * cvB;
    cc1 += xA1 * cvA + xB1 * cvB;
    cn0 += xA0 * (1.f - cvA) + xB0 * (1.f - cvB);
    cn1 += xA1 * (1.f - cvA) + xB1 * (1.f - cvB);
  }
  if (j < end) {
    int rA = perm[j];
    uint vA = *(const uint*)&hb[(size_t)rA * 128 + c0];
    float cvA = cv[rA];
    float xA0 = (blo(vA) - mu0) * scl0; xA0 = xA0 > 0.f ? xA0 : 0.f;
    float xA1 = (bhi(vA) - mu1) * scl1; xA1 = xA1 > 0.f ? xA1 : 0.f;
    cc0 += xA0 * cvA;
    cc1 += xA1 * cvA;
    cn0 += xA0 * (1.f - cvA);
    cn1 += xA1 * (1.f - cvA);
  }

  __shared__ float redC[8][128], redN[8][128];
  redC[w][c0] = cc0; redC[w][c0 + 1] = cc1;
  redN[w][c0] = cn0; redN[w][c0 + 1] = cn1;
  __syncthreads();
  if (tid < 128) {
    float a = 0.f;
    #pragma unroll
    for (int ww = 0; ww < 8; ++ww) a += redC[ww][tid];
    poolP[blockIdx.x * 256 + tid] = a;
  } else if (tid < 256) {
    int t = tid - 128;
    float a = 0.f;
    #pragma unroll
    for (int ww = 0; ww < 8; ++ww) a += redN[ww][t];
    poolP[blockIdx.x * 256 + tid] = a;
  }
}

// ================================================================ final MLP: one block per partition
__global__ __launch_bounds__(128) void k_mlp(const ushort* __restrict__ hb,
                                             const float* __restrict__ stats_red,
                                             const float* __restrict__ poolP,
                                             const float* __restrict__ l1W,
                                             const float* __restrict__ l1b,
                                             const float* __restrict__ l2W,
                                             const float* __restrict__ l2b,
                                             const int* __restrict__ curr_ptr,
                                             float* __restrict__ out, int n) {
  const int p = blockIdx.x;
  const int t = threadIdx.x;
  __shared__ float z[384];
  int curr = *curr_ptr;
  float s = stats_red[t], q = stats_red[128 + t];
  float mu = s / (float)n;
  float scl = rsqrtf(q / (float)n - mu * mu + EPSV);
  float v = b2f(hb[(size_t)curr * 128 + t]);
  v = (v - mu) * scl;
  z[t] = v > 0.f ? v : 0.f;
  float ccore = 0.f, cnon = 0.f;
  #pragma unroll
  for (int sb = 0; sb < 4; ++sb) {
    ccore += poolP[(p * 4 + sb) * 256 + t];
    cnon  += poolP[(p * 4 + sb) * 256 + 128 + t];
  }
  z[128 + t] = ccore;
  z[256 + t] = cnon;
  __syncthreads();
  float a = l1b[t];
  for (int k = 0; k < 384; ++k) a += z[k] * l1W[k * 128 + t];
  a = a > 0.f ? a : 0.f;
  float pr = a * l2W[t];
  #pragma unroll
  for (int off = 32; off; off >>= 1) pr += __shfl_down(pr, off);
  __shared__ float rr[2];
  if ((t & 63) == 0) rr[t >> 6] = pr;
  __syncthreads();
  if (t == 0) out[p] = rr[0] + rr[1] + l2b[0];
}

// ================================================================ host
extern "C" void kernel_launch(void* const* d_in, const int* in_sizes, int n_in,
                              void* d_out, int out_size, void* d_ws, size_t ws_size,
                              hipStream_t stream) {
  const float* x    = (const float*)d_in[0];
  const float* cv   = (const float*)d_in[1];
  const float* W0   = (const float*)d_in[2];
  const float* b0   = (const float*)d_in[3];
  const float* W1   = (const float*)d_in[4];
  const float* b1   = (const float*)d_in[5];
  const float* l1W  = (const float*)d_in[6];
  const float* l1b  = (const float*)d_in[7];
  const float* l2W  = (const float*)d_in[8];
  const float* l2b  = (const float*)d_in[9];
  const int*   ei   = (const int*)d_in[10];
  const int*   part = (const int*)d_in[11];
  const int*   curr = (const int*)d_in[12];

  const int N = in_sizes[1];          // 50000
  const int E = in_sizes[10] / 2;     // 640000
  const int* src = ei;
  const int* dst = ei + E;

  const int GATHER_BLOCKS = 2048;

  char* w = (char*)d_ws;
  size_t off = 0;
  auto alloc = [&](size_t bytes) -> void* {
    void* p = (void*)(w + off);
    off = (off + bytes + 255) & ~(size_t)255;
    return p;
  };
  int*   hist      = (int*)alloc((size_t)N * 4);
  int*   row_start = (int*)alloc((size_t)(N + 1) * 4);
  int*   row_fin   = (int*)alloc((size_t)(N + 1) * 4);
  int*   csr       = (int*)alloc((size_t)E * 4);
  int*   rank      = (int*)alloc((size_t)E * 4);
  float* invs      = (float*)alloc((size_t)N * 4);
  int*   bsum      = (int*)alloc((size_t)SCAN_NB * 4);
  int*   boff      = (int*)alloc((size_t)SCAN_NB * 4);
  int*   blockHist = (int*)alloc((size_t)PSORT_NB * 64 * 4);
  int*   pbase     = (int*)alloc((size_t)PSORT_NB * 64 * 4);
  int*   ptot      = (int*)alloc(64 * 4);
  int*   pexcl     = (int*)alloc(64 * 4);
  int*   pstart    = (int*)alloc(65 * 4);
  int*   perm      = (int*)alloc((size_t)N * 4);
  float* stats_red0 = (float*)alloc(256 * 4);
  float* stats_red1 = (float*)alloc(256 * 4);
  float* statsP    = (float*)alloc((size_t)GATHER_BLOCKS * 256 * 4);
  float* poolP     = (float*)alloc((size_t)256 * 256 * 4);
  ushort* WT0      = (ushort*)alloc((size_t)16384 * 2);
  ushort* WT1      = (ushort*)alloc((size_t)16384 * 2);
  ushort* hsb      = (ushort*)alloc((size_t)N * 128 * 2);
  ushort* hb       = (ushort*)alloc((size_t)N * 128 * 2);
  (void)ws_size;

  const int eb = (E + 255) / 256;
  const int nbZero = (N + 255) / 256;
  const int gb = (N + 127) / 128;

  // L1: zero(hist) || partition per-block hist || castW
  k_pre1<<<nbZero + PSORT_NB + 128, 256, 0, stream>>>(hist, nbZero, part, blockHist,
                                                      W0, W1, WT0, WT1, N);
  // L2: gemm layer1 (unscaled) || edge hist+rank || partition base scan
  k_mega2<<<gb + eb + 64, 256, 0, stream>>>(x, WT0, hsb, N, gb,
                                            dst, hist, rank, E, eb,
                                            blockHist, pbase, ptot);
  // L3: degree scan + invs || partition total scan
  k_pre3<<<SCAN_NB + 1, 256, 0, stream>>>(hist, row_start, invs, bsum, N, ptot, pexcl, pstart);
  // L4: block-sum scan (boff, row_fin[n]) || partition scatter
  k_pre4<<<1 + PSORT_NB, 256, 0, stream>>>(bsum, boff, row_fin, N, part, pbase, pexcl, perm);
  // L5: finalize row_fin || CSR scatter
  k_mega5<<<SCAN_NB + eb, 256, 0, stream>>>(row_start, boff, row_fin, N, src, dst, rank, csr, E);
  // L6-7: layer-1 aggregate (per-edge invs) + stats reduce
  k_gather<true><<<GATHER_BLOCKS, 256, 0, stream>>>(hsb, row_fin, csr, invs, b0, hb, statsP, N);
  k_finstats<<<16, 1024, 0, stream>>>(statsP, stats_red0, GATHER_BLOCKS);
  // L8: layer-2 GEMM (BN+ReLU fused, invs applied)
  k_gemm2<<<gb, 256, 0, stream>>>(hb, WT1, invs, stats_red0, hsb, N);
  // L9-10: layer-2 aggregate + stats reduce
  k_gather<false><<<GATHER_BLOCKS, 256, 0, stream>>>(hsb, row_fin, csr, invs, b1, hb, statsP, N);
  k_finstats<<<16, 1024, 0, stream>>>(statsP, stats_red1, GATHER_BLOCKS);
  // L11-12: pooling + head
  k_pool2<<<256, 512, 0, stream>>>(hb, stats_red1, cv, perm, pstart, poolP, N);
  k_mlp<<<64, 128, 0, stream>>>(hb, stats_red1, poolP, l1W, l1b, l2W, l2b, curr, (float*)d_out, N);
}